// Round 7
// baseline (374.732 us; speedup 1.0000x reference)
//
#include <hip/hip_runtime.h>
#include <hip/hip_cooperative_groups.h>

namespace cg = cooperative_groups;

#define LEAF_SZ 32
#define MAXN 16384
#define MAXNODES 32768
#define MAXG 64
#define NQ 1024
#define PCAP 1024
#define BGRID 128

// Static device scratch (fully rewritten each call; no cross-call state relied on).
__device__ int    g_perm[MAXN];
__device__ int    g_ptmp[MAXN];
__device__ float4 g_p4[MAXN];    // x,y,z,charge in perm order
__device__ float4 g_t4[MAXN];
__device__ int    g_nstart[MAXNODES];
__device__ int    g_nend[MAXNODES];
__device__ int4   g_nmeta[MAXNODES];  // st, en, first_child, n_children(0=leaf)
__device__ float4 g_nc4[MAXNODES];    // bbox center + half (MAC)
__device__ float4 g_nm4[MAXNODES];    // mean center + total charge (monopole)
__device__ int    g_root[MAXG];
__device__ int    g_ncount;

struct NodeSh {
    float  mn[4][3], mx[4][3];
    double sx[4], sy[4], sz[4], sq[4];
    int    c8[4][8];
    int    cur[8];
    float  cc[3];
    int    info;
};

// Block-cooperative (256 threads) processing of one node (R2-proven verbatim):
// bbox+monopole, octant split at bbox center (>= rule), leaf if cnt<=32 or
// <=1 nonempty bin. Node point-segments are disjoint, so concurrent blocks
// scatter into disjoint ranges of g_ptmp/g_t4.
__device__ __forceinline__ void process_node(NodeSh& sh, int n)
{
    const int tid  = threadIdx.x;
    const int wid  = tid >> 6;
    const int lane = tid & 63;
    const int st = g_nstart[n], en = g_nend[n];
    const int cnt = en - st;

    // pass 1: bbox + mean-center + total charge
    float mnx = 3.402823466e38f, mny = mnx, mnz = mnx;
    float mxx = -mnx, mxy = -mnx, mxz = -mnx;
    double sx = 0.0, sy = 0.0, sz = 0.0, sq = 0.0;
    for (int j = st + tid; j < en; j += 256) {
        float4 p = g_p4[j];
        mnx = fminf(mnx, p.x); mny = fminf(mny, p.y); mnz = fminf(mnz, p.z);
        mxx = fmaxf(mxx, p.x); mxy = fmaxf(mxy, p.y); mxz = fmaxf(mxz, p.z);
        sx += (double)p.x; sy += (double)p.y; sz += (double)p.z; sq += (double)p.w;
    }
    for (int o = 1; o < 64; o <<= 1) {
        mnx = fminf(mnx, __shfl_xor(mnx, o));
        mny = fminf(mny, __shfl_xor(mny, o));
        mnz = fminf(mnz, __shfl_xor(mnz, o));
        mxx = fmaxf(mxx, __shfl_xor(mxx, o));
        mxy = fmaxf(mxy, __shfl_xor(mxy, o));
        mxz = fmaxf(mxz, __shfl_xor(mxz, o));
        sx += __shfl_xor(sx, o);
        sy += __shfl_xor(sy, o);
        sz += __shfl_xor(sz, o);
        sq += __shfl_xor(sq, o);
    }
    if (lane == 0) {
        sh.mn[wid][0] = mnx; sh.mn[wid][1] = mny; sh.mn[wid][2] = mnz;
        sh.mx[wid][0] = mxx; sh.mx[wid][1] = mxy; sh.mx[wid][2] = mxz;
        sh.sx[wid] = sx; sh.sy[wid] = sy; sh.sz[wid] = sz; sh.sq[wid] = sq;
    }
    __syncthreads();
    if (tid == 0) {
        float a0 = sh.mn[0][0], a1 = sh.mn[0][1], a2 = sh.mn[0][2];
        float b0 = sh.mx[0][0], b1 = sh.mx[0][1], b2 = sh.mx[0][2];
        double tx = sh.sx[0], ty = sh.sy[0], tz = sh.sz[0], tq = sh.sq[0];
        for (int w = 1; w < 4; ++w) {
            a0 = fminf(a0, sh.mn[w][0]); a1 = fminf(a1, sh.mn[w][1]); a2 = fminf(a2, sh.mn[w][2]);
            b0 = fmaxf(b0, sh.mx[w][0]); b1 = fmaxf(b1, sh.mx[w][1]); b2 = fmaxf(b2, sh.mx[w][2]);
            tx += sh.sx[w]; ty += sh.sy[w]; tz += sh.sz[w]; tq += sh.sq[w];
        }
        float cx = 0.5f * (a0 + b0), cy = 0.5f * (a1 + b1), cz = 0.5f * (a2 + b2);
        g_nc4[n] = make_float4(cx, cy, cz, 0.5f * fmaxf(fmaxf(b0 - a0, b1 - a1), b2 - a2));
        const float fc = (float)cnt;
        g_nm4[n] = make_float4((float)tx / fc, (float)ty / fc, (float)tz / fc, (float)tq);
        sh.cc[0] = cx; sh.cc[1] = cy; sh.cc[2] = cz;
        if (cnt <= LEAF_SZ) { g_nmeta[n] = make_int4(st, en, 0, 0); sh.info = -1; }
        else sh.info = 0;
    }
    __syncthreads();
    if (sh.info < 0) return;
    const float cx = sh.cc[0], cy = sh.cc[1], cz = sh.cc[2];

    // pass 2: octant counts
    int c8[8] = {0,0,0,0,0,0,0,0};
    for (int j = st + tid; j < en; j += 256) {
        float4 p = g_p4[j];
        int oct = (p.x >= cx ? 1 : 0) | (p.y >= cy ? 2 : 0) | (p.z >= cz ? 4 : 0);
        c8[oct]++;
    }
    #pragma unroll
    for (int k = 0; k < 8; ++k)
        for (int o = 1; o < 64; o <<= 1)
            c8[k] += __shfl_xor(c8[k], o);
    if (lane == 0)
        #pragma unroll
        for (int k = 0; k < 8; ++k) sh.c8[wid][k] = c8[k];
    __syncthreads();
    if (tid == 0) {
        int tot[8], nonempty = 0;
        #pragma unroll
        for (int k = 0; k < 8; ++k) {
            tot[k] = sh.c8[0][k] + sh.c8[1][k] + sh.c8[2][k] + sh.c8[3][k];
            nonempty += (tot[k] > 0) ? 1 : 0;
        }
        if (nonempty <= 1) { g_nmeta[n] = make_int4(st, en, 0, 0); sh.info = -1; }
        else {
            int base = atomicAdd(&g_ncount, nonempty);
            int acc = st, ci = base;
            #pragma unroll
            for (int k = 0; k < 8; ++k) {
                sh.cur[k] = acc;
                if (tot[k] > 0) { g_nstart[ci] = acc; g_nend[ci] = acc + tot[k]; ++ci; }
                acc += tot[k];
            }
            g_nmeta[n] = make_int4(st, en, base, nonempty);
            sh.info = 1;
        }
    }
    __syncthreads();
    if (sh.info < 0) return;

    // pass 3: scatter into child order
    for (int j = st + tid; j < en; j += 256) {
        float4 p = g_p4[j];
        int id = g_perm[j];
        int oct = (p.x >= cx ? 1 : 0) | (p.y >= cy ? 2 : 0) | (p.z >= cz ? 4 : 0);
        int pdst = atomicAdd(&sh.cur[oct], 1);
        g_ptmp[pdst] = id; g_t4[pdst] = p;
    }
    __syncthreads();
    for (int j = st + tid; j < en; j += 256) {
        g_perm[j] = g_ptmp[j];
        g_p4[j]   = g_t4[j];
    }
    __syncthreads();
}

// ---------------------------------------------------------------------------
// Cooperative single-launch build: init + graph ranges + level-synchronous
// octree with grid.sync() between levels (the sanctioned device-wide barrier;
// no hand-rolled spin anywhere -> hang-impossible by construction).
// Level ranges use the race-free two-sync read: sync -> tid0 reads ncount ->
// __syncthreads -> sync -> process. All grid.sync counts are grid-uniform.
// ---------------------------------------------------------------------------
__global__ __launch_bounds__(256)
void build_coop(const float* __restrict__ pos, const int* __restrict__ batch,
                const float* __restrict__ src, int N, int n_graphs)
{
    cg::grid_group grid = cg::this_grid();
    __shared__ NodeSh sh;
    __shared__ int s_first[MAXG], s_end[MAXG];
    __shared__ int s_le;

    const int tid  = threadIdx.x;
    const int gtid = blockIdx.x * 256 + tid;

    // phase 0: gather points into packed perm-order arrays
    for (int i = gtid; i < N; i += BGRID * 256) {
        g_perm[i] = i;
        g_p4[i] = make_float4(pos[3*i], pos[3*i+1], pos[3*i+2], src[i]);
    }
    __threadfence();
    grid.sync();                                  // #1: init visible

    // phase 1: block 0 computes per-graph contiguous ranges (batch sorted)
    if (blockIdx.x == 0) {
        for (int g = tid; g < MAXG; g += 256) { s_first[g] = -1; s_end[g] = 0; }
        __syncthreads();
        for (int i = tid; i < N; i += 256) {
            int b = batch[i];
            if (i == 0     || batch[i-1] != b) s_first[b] = i;
            if (i == N - 1 || batch[i+1] != b) s_end[b]   = i + 1;
        }
        __syncthreads();
        if (tid == 0) {
            int nc = 0;
            for (int g = 0; g < n_graphs && g < MAXG; ++g) {
                if (s_first[g] >= 0) {
                    g_root[g] = nc;
                    g_nstart[nc] = s_first[g];
                    g_nend[nc]   = s_end[g];
                    ++nc;
                } else g_root[g] = -1;
            }
            atomicExch(&g_ncount, nc);
        }
        __threadfence();
    }
    grid.sync();                                  // #2: ranges visible

    if (tid == 0) s_le = atomicAdd(&g_ncount, 0); // RMW read (coherent)
    __syncthreads();
    int lb = 0, le = s_le;
    grid.sync();                                  // #3: reads done before any alloc

    // level loop (capped; sync counts uniform since lb/le uniform)
    for (int lev = 0; lev < 64 && lb < le; ++lev) {
        for (int n = lb + blockIdx.x; n < le; n += BGRID)
            process_node(sh, n);
        __threadfence();
        grid.sync();                              // level done, writes visible
        if (tid == 0) s_le = atomicAdd(&g_ncount, 0);
        __syncthreads();
        lb = le; le = s_le;
        grid.sync();                              // reads done before next level
    }

    // mop-up for pathologically deep trees (normally zero work): block 0 alone,
    // bounded by total node count -> terminates.
    if (blockIdx.x == 0) {
        while (lb < le) {
            for (int n = lb; n < le; ++n) process_node(sh, n);
            __syncthreads();
            if (tid == 0) s_le = atomicAdd(&g_ncount, 0);
            __syncthreads();
            lb = le; le = s_le;
        }
    }
}

// ---------------------------------------------------------------------------
// One wave per target. Per batch: lanes classify nodes (monopole inline),
// leaf ranges prefix-summed into a flat LDS pair list, drained by all lanes.
// ---------------------------------------------------------------------------
__global__ __launch_bounds__(256)
void traverse_kernel(const int* __restrict__ batch,
                     const float* __restrict__ p_scr, const float* __restrict__ p_soft,
                     float* __restrict__ out, int N)
{
    __shared__ int s_q[4][NQ];
    __shared__ int s_pj[4][PCAP];
    __shared__ int s_qt[4];
    const int wid  = threadIdx.x >> 6;
    const int lane = threadIdx.x & 63;
    const int slot = blockIdx.x * 4 + wid;
    if (slot >= N) return;                 // wave-uniform; no __syncthreads used
    const int t = g_perm[slot];

    const float scr   = p_scr[0];
    const float soft  = p_soft[0];
    const float soft2 = soft * soft;
    const float cexp  = -scr * 1.4426950408889634f;  // exp(-scr*r) = exp2(cexp*r)
    const float4 tp = g_p4[slot];
    const float tx = tp.x, ty = tp.y, tz = tp.z;
    const int inv_t = slot;

    volatile int* q  = s_q[wid];
    volatile int* pj = s_pj[wid];
    if (lane == 0) { q[0] = g_root[batch[t]]; s_qt[wid] = 1; }
    __builtin_amdgcn_wave_barrier();

    float phi = 0.f;
    int qh = 0;
    while (true) {
        __builtin_amdgcn_wave_barrier();
        int qt = ((volatile int*)s_qt)[wid];
        if (qh >= qt) break;
        int take = qt - qh; if (take > 64) take = 64;
        int node = (lane < take) ? q[(qh + lane) & (NQ - 1)] : -1;
        qh += take;

        int leaf_st = 0, leaf_cnt = 0;
        if (node >= 0) {
            const int4 meta = g_nmeta[node];
            if (meta.w == 0) {
                leaf_st = meta.x; leaf_cnt = meta.y - meta.x;
            } else {
                float4 c4 = g_nc4[node];
                float dx = tx - c4.x, dy = ty - c4.y, dz = tz - c4.z;
                float dist = sqrtf(dx*dx + dy*dy + dz*dz + soft2);
                float diam = fmaxf(2.0f * c4.w, 1e-9f);
                bool inside = (inv_t >= meta.x) && (inv_t < meta.y);
                if (!inside && diam < 0.5f * dist) {
                    float4 m4 = g_nm4[node];
                    float ax = tx - m4.x, ay = ty - m4.y, az = tz - m4.z;
                    float s = ax*ax + ay*ay + az*az + soft2;
                    float rinv = rsqrtf(s);
                    phi += m4.w * exp2f(cexp * (s * rinv)) * rinv;
                } else {
                    int p = atomicAdd(&s_qt[wid], meta.w);
                    for (int c = 0; c < meta.w; ++c) q[(p + c) & (NQ - 1)] = meta.z + c;
                }
            }
        }

        // wave prefix-sum of (leaf size minus self) -> flat pair list
        bool hasself = (inv_t >= leaf_st) && (inv_t < leaf_st + leaf_cnt);
        int cnt_adj = leaf_cnt - (hasself ? 1 : 0);
        int x = cnt_adj;
        #pragma unroll
        for (int o = 1; o < 64; o <<= 1) { int y = __shfl_up(x, o); if (lane >= o) x += y; }
        int total = __shfl(x, 63);
        int off = x - cnt_adj;

        if (total > 0) {
            if (total <= PCAP) {
                int w = off;
                for (int k = 0; k < leaf_cnt; ++k) {
                    int j = leaf_st + k;
                    if (j != inv_t) pj[w++] = j;
                }
                __builtin_amdgcn_wave_barrier();
                for (int p = lane; p < total; p += 64) {
                    int j = pj[p];
                    float4 pp = g_p4[j];
                    float dx = tx - pp.x, dy = ty - pp.y, dz = tz - pp.z;
                    float s = dx*dx + dy*dy + dz*dz + soft2;
                    float rinv = rsqrtf(s);
                    phi += pp.w * exp2f(cexp * (s * rinv)) * rinv;
                }
                __builtin_amdgcn_wave_barrier();
            } else {
                // pathological huge-leaf fallback: serial per lane (never in practice)
                for (int k = 0; k < leaf_cnt; ++k) {
                    int j = leaf_st + k;
                    if (j == inv_t) continue;
                    float4 pp = g_p4[j];
                    float dx = tx - pp.x, dy = ty - pp.y, dz = tz - pp.z;
                    float s = dx*dx + dy*dy + dz*dz + soft2;
                    float rinv = rsqrtf(s);
                    phi += pp.w * exp2f(cexp * (s * rinv)) * rinv;
                }
            }
        }
    }

    #pragma unroll
    for (int o = 1; o < 64; o <<= 1) phi += __shfl_xor(phi, o);
    if (lane == 0) out[t] = 0.5f * (tp.w * phi);
}

extern "C" void kernel_launch(void* const* d_in, const int* in_sizes, int n_in,
                              void* d_out, int out_size, void* d_ws, size_t ws_size,
                              hipStream_t stream) {
    const float* pos    = (const float*)d_in[0];
    const int*   batch  = (const int*)  d_in[1];
    const float* source = (const float*)d_in[3];
    const float* p_scr  = (const float*)d_in[4];
    const float* p_soft = (const float*)d_in[5];

    int N        = in_sizes[0] / 3;
    int n_graphs = in_sizes[2] / 9;

    void* args[] = { (void*)&pos, (void*)&batch, (void*)&source, (void*)&N, (void*)&n_graphs };
    hipLaunchCooperativeKernel((void*)build_coop, dim3(BGRID), dim3(256), args, 0, stream);

    const int blocks = (N + 3) / 4;  // 4 waves (targets) per 256-thread block
    traverse_kernel<<<blocks, 256, 0, stream>>>(batch, p_scr, p_soft, (float*)d_out, N);
}

// Round 8
// 300.365 us; speedup vs baseline: 1.2476x; 1.2476x over previous
//
#include <hip/hip_runtime.h>

#define LEAF_SZ 32
#define MAXN 16384
#define MAXNODES 32768
#define MAXG 64
#define NQ 1024
#define PCAP 1024
#define BGRID 128
#define STK 1024

// Static device scratch (fully rewritten each call; no cross-call state relied on).
__device__ int    g_perm[MAXN];
__device__ int    g_ptmp[MAXN];
__device__ float4 g_p4[MAXN];    // x,y,z,charge in perm order
__device__ float4 g_t4[MAXN];
__device__ int    g_nstart[MAXNODES];
__device__ int    g_nend[MAXNODES];
__device__ int4   g_nmeta[MAXNODES];  // st, en, first_child, n_children(0=leaf)
__device__ float4 g_nc4[MAXNODES];    // bbox center + half (MAC)
__device__ float4 g_nm4[MAXNODES];    // mean center + total charge (monopole)
__device__ int    g_root[MAXG];
__device__ int    g_ncount;
__device__ int    g_lrange[8];
__device__ int    g_done[4];
__device__ int    g_claim;

struct NodeSh {
    float  mn[4][3], mx[4][3];
    double sx[4], sy[4], sz[4], sq[4];
    int    c8[4][8];
    int    cur[8];
    float  cc[3];
    int    info;    // -1 leaf/degenerate, 1 split
    int    base, num;
};

// Block-cooperative (256 threads) processing of one node (R2-proven):
// bbox+monopole, octant split at bbox center (>= rule), leaf if cnt<=32 or
// <=1 nonempty bin. Concurrent blocks only ever touch disjoint [st,en)
// segments, so the shared g_ptmp/g_t4 scratch is race-free.
__device__ __forceinline__ void process_node(NodeSh& sh, int n)
{
    const int tid  = threadIdx.x;
    const int wid  = tid >> 6;
    const int lane = tid & 63;
    const int st = g_nstart[n], en = g_nend[n];
    const int cnt = en - st;

    // pass 1: bbox + mean-center + total charge
    float mnx = 3.402823466e38f, mny = mnx, mnz = mnx;
    float mxx = -mnx, mxy = -mnx, mxz = -mnx;
    double sx = 0.0, sy = 0.0, sz = 0.0, sq = 0.0;
    for (int j = st + tid; j < en; j += 256) {
        float4 p = g_p4[j];
        mnx = fminf(mnx, p.x); mny = fminf(mny, p.y); mnz = fminf(mnz, p.z);
        mxx = fmaxf(mxx, p.x); mxy = fmaxf(mxy, p.y); mxz = fmaxf(mxz, p.z);
        sx += (double)p.x; sy += (double)p.y; sz += (double)p.z; sq += (double)p.w;
    }
    for (int o = 1; o < 64; o <<= 1) {
        mnx = fminf(mnx, __shfl_xor(mnx, o));
        mny = fminf(mny, __shfl_xor(mny, o));
        mnz = fminf(mnz, __shfl_xor(mnz, o));
        mxx = fmaxf(mxx, __shfl_xor(mxx, o));
        mxy = fmaxf(mxy, __shfl_xor(mxy, o));
        mxz = fmaxf(mxz, __shfl_xor(mxz, o));
        sx += __shfl_xor(sx, o);
        sy += __shfl_xor(sy, o);
        sz += __shfl_xor(sz, o);
        sq += __shfl_xor(sq, o);
    }
    if (lane == 0) {
        sh.mn[wid][0] = mnx; sh.mn[wid][1] = mny; sh.mn[wid][2] = mnz;
        sh.mx[wid][0] = mxx; sh.mx[wid][1] = mxy; sh.mx[wid][2] = mxz;
        sh.sx[wid] = sx; sh.sy[wid] = sy; sh.sz[wid] = sz; sh.sq[wid] = sq;
    }
    __syncthreads();
    if (tid == 0) {
        float a0 = sh.mn[0][0], a1 = sh.mn[0][1], a2 = sh.mn[0][2];
        float b0 = sh.mx[0][0], b1 = sh.mx[0][1], b2 = sh.mx[0][2];
        double tx = sh.sx[0], ty = sh.sy[0], tz = sh.sz[0], tq = sh.sq[0];
        for (int w = 1; w < 4; ++w) {
            a0 = fminf(a0, sh.mn[w][0]); a1 = fminf(a1, sh.mn[w][1]); a2 = fminf(a2, sh.mn[w][2]);
            b0 = fmaxf(b0, sh.mx[w][0]); b1 = fmaxf(b1, sh.mx[w][1]); b2 = fmaxf(b2, sh.mx[w][2]);
            tx += sh.sx[w]; ty += sh.sy[w]; tz += sh.sz[w]; tq += sh.sq[w];
        }
        float cx = 0.5f * (a0 + b0), cy = 0.5f * (a1 + b1), cz = 0.5f * (a2 + b2);
        g_nc4[n] = make_float4(cx, cy, cz, 0.5f * fmaxf(fmaxf(b0 - a0, b1 - a1), b2 - a2));
        const float fc = (float)cnt;
        g_nm4[n] = make_float4((float)tx / fc, (float)ty / fc, (float)tz / fc, (float)tq);
        sh.cc[0] = cx; sh.cc[1] = cy; sh.cc[2] = cz;
        if (cnt <= LEAF_SZ) { g_nmeta[n] = make_int4(st, en, 0, 0); sh.info = -1; }
        else sh.info = 0;
    }
    __syncthreads();
    if (sh.info < 0) return;
    const float cx = sh.cc[0], cy = sh.cc[1], cz = sh.cc[2];

    // pass 2: octant counts
    int c8[8] = {0,0,0,0,0,0,0,0};
    for (int j = st + tid; j < en; j += 256) {
        float4 p = g_p4[j];
        int oct = (p.x >= cx ? 1 : 0) | (p.y >= cy ? 2 : 0) | (p.z >= cz ? 4 : 0);
        c8[oct]++;
    }
    #pragma unroll
    for (int k = 0; k < 8; ++k)
        for (int o = 1; o < 64; o <<= 1)
            c8[k] += __shfl_xor(c8[k], o);
    if (lane == 0)
        #pragma unroll
        for (int k = 0; k < 8; ++k) sh.c8[wid][k] = c8[k];
    __syncthreads();
    if (tid == 0) {
        int tot[8], nonempty = 0;
        #pragma unroll
        for (int k = 0; k < 8; ++k) {
            tot[k] = sh.c8[0][k] + sh.c8[1][k] + sh.c8[2][k] + sh.c8[3][k];
            nonempty += (tot[k] > 0) ? 1 : 0;
        }
        if (nonempty <= 1) { g_nmeta[n] = make_int4(st, en, 0, 0); sh.info = -1; }
        else {
            int base = atomicAdd(&g_ncount, nonempty);   // allocation RMW (no polling)
            int acc = st, ci = base;
            #pragma unroll
            for (int k = 0; k < 8; ++k) {
                sh.cur[k] = acc;
                if (tot[k] > 0) { g_nstart[ci] = acc; g_nend[ci] = acc + tot[k]; ++ci; }
                acc += tot[k];
            }
            g_nmeta[n] = make_int4(st, en, base, nonempty);
            sh.base = base; sh.num = nonempty; sh.info = 1;
        }
    }
    __syncthreads();
    if (sh.info < 0) return;

    // pass 3: scatter into child order
    for (int j = st + tid; j < en; j += 256) {
        float4 p = g_p4[j];
        int id = g_perm[j];
        int oct = (p.x >= cx ? 1 : 0) | (p.y >= cy ? 2 : 0) | (p.z >= cz ? 4 : 0);
        int pdst = atomicAdd(&sh.cur[oct], 1);
        g_ptmp[pdst] = id; g_t4[pdst] = p;
    }
    __syncthreads();
    for (int j = st + tid; j < en; j += 256) {
        g_perm[j] = g_ptmp[j];
        g_p4[j]   = g_t4[j];
    }
    __syncthreads();
}

__global__ void init_kernel(const float* __restrict__ pos, const float* __restrict__ src, int N)
{
    int i = blockIdx.x * blockDim.x + threadIdx.x;
    if (i < N) {
        g_perm[i] = i;
        g_p4[i] = make_float4(pos[3*i], pos[3*i+1], pos[3*i+2], src[i]);
    }
}

__global__ __launch_bounds__(256) void roots_kernel(const int* __restrict__ batch, int N, int n_graphs)
{
    __shared__ int s_first[MAXG], s_end[MAXG];
    const int tid = threadIdx.x;
    for (int g = tid; g < MAXG; g += 256) { s_first[g] = -1; s_end[g] = 0; }
    __syncthreads();
    for (int i = tid; i < N; i += 256) {
        int b = batch[i];
        if (i == 0     || batch[i-1] != b) s_first[b] = i;
        if (i == N - 1 || batch[i+1] != b) s_end[b]   = i + 1;
    }
    __syncthreads();
    if (tid == 0) {
        int nc = 0;
        for (int g = 0; g < n_graphs && g < MAXG; ++g) {
            if (s_first[g] >= 0) {
                g_root[g] = nc;
                g_nstart[nc] = s_first[g];
                g_nend[nc]   = s_end[g];
                ++nc;
            } else g_root[g] = -1;
        }
        g_ncount = nc;
        g_lrange[0] = 0; g_lrange[1] = nc;
        g_done[0] = g_done[1] = g_done[2] = g_done[3] = 0;
        g_claim = 0;
    }
}

// One launch per level (2 levels): kernel boundary = free device-wide barrier.
// R2-proven publication: per-level done counter; last block snapshots ncount.
__global__ __launch_bounds__(256) void level_kernel(int lev)
{
    __shared__ NodeSh sh;
    const int lb = g_lrange[lev], le = g_lrange[lev + 1];
    for (int n = lb + blockIdx.x; n < le; n += BGRID) {
        __syncthreads();
        process_node(sh, n);
    }
    __syncthreads();
    if (threadIdx.x == 0) {
        __threadfence();
        int d = atomicAdd(&g_done[lev], 1);
        if (d == BGRID - 1)
            g_lrange[lev + 2] = atomicAdd(&g_ncount, 0);
    }
}

// Each block claims frontier nodes (single atomicAdd ticket — allocation, not
// polling) and builds the whole subtree DFS with an LDS stack. Subtrees are
// independent: zero cross-block communication, hang-impossible.
__global__ __launch_bounds__(256) void subtree_kernel()
{
    __shared__ NodeSh sh;
    __shared__ int s_stk[STK];
    __shared__ int s_sp, s_task, s_node;
    const int tid = threadIdx.x;
    const int lb = g_lrange[2], le = g_lrange[3];

    while (true) {
        if (tid == 0) s_task = atomicAdd(&g_claim, 1);
        __syncthreads();
        const int root = lb + s_task;
        if (root >= le) break;
        if (tid == 0) { s_sp = 1; s_stk[0] = root; }
        while (true) {
            __syncthreads();
            const int sp = s_sp;
            if (sp == 0) break;
            __syncthreads();                 // all read sp before tid0 pops
            if (tid == 0) { s_sp = sp - 1; s_node = s_stk[sp - 1]; }
            __syncthreads();
            process_node(sh, s_node);
            if (tid == 0 && sh.info == 1) {
                for (int c = 0; c < sh.num; ++c) s_stk[s_sp + c] = sh.base + c;
                s_sp += sh.num;
            }
        }
        __syncthreads();
    }
}

// ---------------------------------------------------------------------------
// One wave per target. Per batch: lanes classify nodes (monopole inline),
// leaf ranges prefix-summed into a flat LDS pair list, drained by all lanes.
// ---------------------------------------------------------------------------
__global__ __launch_bounds__(256)
void traverse_kernel(const int* __restrict__ batch,
                     const float* __restrict__ p_scr, const float* __restrict__ p_soft,
                     float* __restrict__ out, int N)
{
    __shared__ int s_q[4][NQ];
    __shared__ int s_pj[4][PCAP];
    __shared__ int s_qt[4];
    const int wid  = threadIdx.x >> 6;
    const int lane = threadIdx.x & 63;
    const int slot = blockIdx.x * 4 + wid;
    if (slot >= N) return;                 // wave-uniform; no __syncthreads used
    const int t = g_perm[slot];

    const float scr   = p_scr[0];
    const float soft  = p_soft[0];
    const float soft2 = soft * soft;
    const float cexp  = -scr * 1.4426950408889634f;  // exp(-scr*r) = exp2(cexp*r)
    const float4 tp = g_p4[slot];
    const float tx = tp.x, ty = tp.y, tz = tp.z;
    const int inv_t = slot;

    volatile int* q  = s_q[wid];
    volatile int* pj = s_pj[wid];
    if (lane == 0) { q[0] = g_root[batch[t]]; s_qt[wid] = 1; }
    __builtin_amdgcn_wave_barrier();

    float phi = 0.f;
    int qh = 0;
    while (true) {
        __builtin_amdgcn_wave_barrier();
        int qt = ((volatile int*)s_qt)[wid];
        if (qh >= qt) break;
        int take = qt - qh; if (take > 64) take = 64;
        int node = (lane < take) ? q[(qh + lane) & (NQ - 1)] : -1;
        qh += take;

        int leaf_st = 0, leaf_cnt = 0;
        if (node >= 0) {
            const int4 meta = g_nmeta[node];
            if (meta.w == 0) {
                leaf_st = meta.x; leaf_cnt = meta.y - meta.x;
            } else {
                float4 c4 = g_nc4[node];
                float dx = tx - c4.x, dy = ty - c4.y, dz = tz - c4.z;
                float dist = sqrtf(dx*dx + dy*dy + dz*dz + soft2);
                float diam = fmaxf(2.0f * c4.w, 1e-9f);
                bool inside = (inv_t >= meta.x) && (inv_t < meta.y);
                if (!inside && diam < 0.5f * dist) {
                    float4 m4 = g_nm4[node];
                    float ax = tx - m4.x, ay = ty - m4.y, az = tz - m4.z;
                    float s = ax*ax + ay*ay + az*az + soft2;
                    float rinv = rsqrtf(s);
                    phi += m4.w * exp2f(cexp * (s * rinv)) * rinv;
                } else {
                    int p = atomicAdd(&s_qt[wid], meta.w);
                    for (int c = 0; c < meta.w; ++c) q[(p + c) & (NQ - 1)] = meta.z + c;
                }
            }
        }

        // wave prefix-sum of (leaf size minus self) -> flat pair list
        bool hasself = (inv_t >= leaf_st) && (inv_t < leaf_st + leaf_cnt);
        int cnt_adj = leaf_cnt - (hasself ? 1 : 0);
        int x = cnt_adj;
        #pragma unroll
        for (int o = 1; o < 64; o <<= 1) { int y = __shfl_up(x, o); if (lane >= o) x += y; }
        int total = __shfl(x, 63);
        int off = x - cnt_adj;

        if (total > 0) {
            if (total <= PCAP) {
                int w = off;
                for (int k = 0; k < leaf_cnt; ++k) {
                    int j = leaf_st + k;
                    if (j != inv_t) pj[w++] = j;
                }
                __builtin_amdgcn_wave_barrier();
                for (int p = lane; p < total; p += 64) {
                    int j = pj[p];
                    float4 pp = g_p4[j];
                    float dx = tx - pp.x, dy = ty - pp.y, dz = tz - pp.z;
                    float s = dx*dx + dy*dy + dz*dz + soft2;
                    float rinv = rsqrtf(s);
                    phi += pp.w * exp2f(cexp * (s * rinv)) * rinv;
                }
                __builtin_amdgcn_wave_barrier();
            } else {
                for (int k = 0; k < leaf_cnt; ++k) {
                    int j = leaf_st + k;
                    if (j == inv_t) continue;
                    float4 pp = g_p4[j];
                    float dx = tx - pp.x, dy = ty - pp.y, dz = tz - pp.z;
                    float s = dx*dx + dy*dy + dz*dz + soft2;
                    float rinv = rsqrtf(s);
                    phi += pp.w * exp2f(cexp * (s * rinv)) * rinv;
                }
            }
        }
    }

    #pragma unroll
    for (int o = 1; o < 64; o <<= 1) phi += __shfl_xor(phi, o);
    if (lane == 0) out[t] = 0.5f * (tp.w * phi);
}

extern "C" void kernel_launch(void* const* d_in, const int* in_sizes, int n_in,
                              void* d_out, int out_size, void* d_ws, size_t ws_size,
                              hipStream_t stream) {
    const float* pos    = (const float*)d_in[0];
    const int*   batch  = (const int*)  d_in[1];
    const float* source = (const float*)d_in[3];
    const float* p_scr  = (const float*)d_in[4];
    const float* p_soft = (const float*)d_in[5];

    const int N        = in_sizes[0] / 3;
    const int n_graphs = in_sizes[2] / 9;

    init_kernel<<<(N + 255) / 256, 256, 0, stream>>>(pos, source, N);
    roots_kernel<<<1, 256, 0, stream>>>(batch, N, n_graphs);
    level_kernel<<<BGRID, 256, 0, stream>>>(0);
    level_kernel<<<BGRID, 256, 0, stream>>>(1);
    subtree_kernel<<<BGRID, 256, 0, stream>>>();

    const int blocks = (N + 3) / 4;  // 4 waves (targets) per 256-thread block
    traverse_kernel<<<blocks, 256, 0, stream>>>(batch, p_scr, p_soft, (float*)d_out, N);
}

// Round 9
// 259.275 us; speedup vs baseline: 1.4453x; 1.1585x over previous
//
#include <hip/hip_runtime.h>

#define LEAF_SZ 32
#define MAXN 16384
#define MAXNODES 32768
#define MAXG 64
#define NQ 1024
#define PCAP 1024
#define BGRID 128
#define STKW 512

// Static device scratch (fully rewritten each call; no cross-call state relied on).
__device__ int    g_perm[MAXN];
__device__ int    g_ptmp[MAXN];
__device__ float4 g_p4[MAXN];    // x,y,z,charge in perm order
__device__ float4 g_t4[MAXN];
__device__ int    g_nstart[MAXNODES];
__device__ int    g_nend[MAXNODES];
__device__ int4   g_nmeta[MAXNODES];  // st, en, first_child, n_children(0=leaf)
__device__ float4 g_nc4[MAXNODES];    // bbox center + half (MAC)
__device__ float4 g_nm4[MAXNODES];    // mean center + total charge (monopole)
__device__ int    g_root[MAXG];
__device__ int    g_ncount;
__device__ int    g_lrange[8];
__device__ int    g_done[4];
__device__ int    g_claim;

struct NodeSh {
    float  mn[4][3], mx[4][3];
    double sx[4], sy[4], sz[4], sq[4];
    int    c8[4][8];
    int    cur[8];
    float  cc[3];
    int    info;    // -1 leaf/degenerate, 1 split
    int    base, num;
};

// Block-cooperative (256 threads) processing of one node (R2-proven) — used
// for the big top-level nodes only.
__device__ __forceinline__ void process_node(NodeSh& sh, int n)
{
    const int tid  = threadIdx.x;
    const int wid  = tid >> 6;
    const int lane = tid & 63;
    const int st = g_nstart[n], en = g_nend[n];
    const int cnt = en - st;

    float mnx = 3.402823466e38f, mny = mnx, mnz = mnx;
    float mxx = -mnx, mxy = -mnx, mxz = -mnx;
    double sx = 0.0, sy = 0.0, sz = 0.0, sq = 0.0;
    for (int j = st + tid; j < en; j += 256) {
        float4 p = g_p4[j];
        mnx = fminf(mnx, p.x); mny = fminf(mny, p.y); mnz = fminf(mnz, p.z);
        mxx = fmaxf(mxx, p.x); mxy = fmaxf(mxy, p.y); mxz = fmaxf(mxz, p.z);
        sx += (double)p.x; sy += (double)p.y; sz += (double)p.z; sq += (double)p.w;
    }
    for (int o = 1; o < 64; o <<= 1) {
        mnx = fminf(mnx, __shfl_xor(mnx, o));
        mny = fminf(mny, __shfl_xor(mny, o));
        mnz = fminf(mnz, __shfl_xor(mnz, o));
        mxx = fmaxf(mxx, __shfl_xor(mxx, o));
        mxy = fmaxf(mxy, __shfl_xor(mxy, o));
        mxz = fmaxf(mxz, __shfl_xor(mxz, o));
        sx += __shfl_xor(sx, o);
        sy += __shfl_xor(sy, o);
        sz += __shfl_xor(sz, o);
        sq += __shfl_xor(sq, o);
    }
    if (lane == 0) {
        sh.mn[wid][0] = mnx; sh.mn[wid][1] = mny; sh.mn[wid][2] = mnz;
        sh.mx[wid][0] = mxx; sh.mx[wid][1] = mxy; sh.mx[wid][2] = mxz;
        sh.sx[wid] = sx; sh.sy[wid] = sy; sh.sz[wid] = sz; sh.sq[wid] = sq;
    }
    __syncthreads();
    if (tid == 0) {
        float a0 = sh.mn[0][0], a1 = sh.mn[0][1], a2 = sh.mn[0][2];
        float b0 = sh.mx[0][0], b1 = sh.mx[0][1], b2 = sh.mx[0][2];
        double tx = sh.sx[0], ty = sh.sy[0], tz = sh.sz[0], tq = sh.sq[0];
        for (int w = 1; w < 4; ++w) {
            a0 = fminf(a0, sh.mn[w][0]); a1 = fminf(a1, sh.mn[w][1]); a2 = fminf(a2, sh.mn[w][2]);
            b0 = fmaxf(b0, sh.mx[w][0]); b1 = fmaxf(b1, sh.mx[w][1]); b2 = fmaxf(b2, sh.mx[w][2]);
            tx += sh.sx[w]; ty += sh.sy[w]; tz += sh.sz[w]; tq += sh.sq[w];
        }
        float cx = 0.5f * (a0 + b0), cy = 0.5f * (a1 + b1), cz = 0.5f * (a2 + b2);
        g_nc4[n] = make_float4(cx, cy, cz, 0.5f * fmaxf(fmaxf(b0 - a0, b1 - a1), b2 - a2));
        const float fc = (float)cnt;
        g_nm4[n] = make_float4((float)tx / fc, (float)ty / fc, (float)tz / fc, (float)tq);
        sh.cc[0] = cx; sh.cc[1] = cy; sh.cc[2] = cz;
        if (cnt <= LEAF_SZ) { g_nmeta[n] = make_int4(st, en, 0, 0); sh.info = -1; }
        else sh.info = 0;
    }
    __syncthreads();
    if (sh.info < 0) return;
    const float cx = sh.cc[0], cy = sh.cc[1], cz = sh.cc[2];

    int c8[8] = {0,0,0,0,0,0,0,0};
    for (int j = st + tid; j < en; j += 256) {
        float4 p = g_p4[j];
        int oct = (p.x >= cx ? 1 : 0) | (p.y >= cy ? 2 : 0) | (p.z >= cz ? 4 : 0);
        c8[oct]++;
    }
    #pragma unroll
    for (int k = 0; k < 8; ++k)
        for (int o = 1; o < 64; o <<= 1)
            c8[k] += __shfl_xor(c8[k], o);
    if (lane == 0)
        #pragma unroll
        for (int k = 0; k < 8; ++k) sh.c8[wid][k] = c8[k];
    __syncthreads();
    if (tid == 0) {
        int tot[8], nonempty = 0;
        #pragma unroll
        for (int k = 0; k < 8; ++k) {
            tot[k] = sh.c8[0][k] + sh.c8[1][k] + sh.c8[2][k] + sh.c8[3][k];
            nonempty += (tot[k] > 0) ? 1 : 0;
        }
        if (nonempty <= 1) { g_nmeta[n] = make_int4(st, en, 0, 0); sh.info = -1; }
        else {
            int base = atomicAdd(&g_ncount, nonempty);
            int acc = st, ci = base;
            #pragma unroll
            for (int k = 0; k < 8; ++k) {
                sh.cur[k] = acc;
                if (tot[k] > 0) { g_nstart[ci] = acc; g_nend[ci] = acc + tot[k]; ++ci; }
                acc += tot[k];
            }
            g_nmeta[n] = make_int4(st, en, base, nonempty);
            sh.base = base; sh.num = nonempty; sh.info = 1;
        }
    }
    __syncthreads();
    if (sh.info < 0) return;

    for (int j = st + tid; j < en; j += 256) {
        float4 p = g_p4[j];
        int id = g_perm[j];
        int oct = (p.x >= cx ? 1 : 0) | (p.y >= cy ? 2 : 0) | (p.z >= cz ? 4 : 0);
        int pdst = atomicAdd(&sh.cur[oct], 1);
        g_ptmp[pdst] = id; g_t4[pdst] = p;
    }
    __syncthreads();
    for (int j = st + tid; j < en; j += 256) {
        g_perm[j] = g_ptmp[j];
        g_p4[j]   = g_t4[j];
    }
    __syncthreads();
}

__global__ void init_kernel(const float* __restrict__ pos, const float* __restrict__ src, int N)
{
    int i = blockIdx.x * blockDim.x + threadIdx.x;
    if (i < N) {
        g_perm[i] = i;
        g_p4[i] = make_float4(pos[3*i], pos[3*i+1], pos[3*i+2], src[i]);
    }
}

__global__ __launch_bounds__(256) void roots_kernel(const int* __restrict__ batch, int N, int n_graphs)
{
    __shared__ int s_first[MAXG], s_end[MAXG];
    const int tid = threadIdx.x;
    for (int g = tid; g < MAXG; g += 256) { s_first[g] = -1; s_end[g] = 0; }
    __syncthreads();
    for (int i = tid; i < N; i += 256) {
        int b = batch[i];
        if (i == 0     || batch[i-1] != b) s_first[b] = i;
        if (i == N - 1 || batch[i+1] != b) s_end[b]   = i + 1;
    }
    __syncthreads();
    if (tid == 0) {
        int nc = 0;
        for (int g = 0; g < n_graphs && g < MAXG; ++g) {
            if (s_first[g] >= 0) {
                g_root[g] = nc;
                g_nstart[nc] = s_first[g];
                g_nend[nc]   = s_end[g];
                ++nc;
            } else g_root[g] = -1;
        }
        g_ncount = nc;
        g_lrange[0] = 0; g_lrange[1] = nc;
        g_done[0] = g_done[1] = g_done[2] = g_done[3] = 0;
        g_claim = 0;
    }
}

// One launch per level (2 levels): kernel boundary = free device-wide barrier.
__global__ __launch_bounds__(256) void level_kernel(int lev)
{
    __shared__ NodeSh sh;
    const int lb = g_lrange[lev], le = g_lrange[lev + 1];
    for (int n = lb + blockIdx.x; n < le; n += BGRID) {
        __syncthreads();
        process_node(sh, n);
    }
    __syncthreads();
    if (threadIdx.x == 0) {
        __threadfence();
        int d = atomicAdd(&g_done[lev], 1);
        if (d == BGRID - 1)
            g_lrange[lev + 2] = atomicAdd(&g_ncount, 0);
    }
}

// ---------------------------------------------------------------------------
// Wave-granular node processing: 64-lane shfl butterflies, per-wave LDS
// scatter cursors, vmcnt waits for same-wave store->load hazards. No block
// barriers at all. Returns {n_children, base} ({0,0} = leaf).
// ---------------------------------------------------------------------------
__device__ __forceinline__ int2 process_node_wave(int n, int* s_cur)
{
    const int lane = threadIdx.x & 63;
    const int st = g_nstart[n], en = g_nend[n];
    const int cnt = en - st;

    float mnx = 3.402823466e38f, mny = mnx, mnz = mnx;
    float mxx = -mnx, mxy = -mnx, mxz = -mnx;
    double sx = 0.0, sy = 0.0, sz = 0.0, sq = 0.0;
    for (int j = st + lane; j < en; j += 64) {
        float4 p = g_p4[j];
        mnx = fminf(mnx, p.x); mny = fminf(mny, p.y); mnz = fminf(mnz, p.z);
        mxx = fmaxf(mxx, p.x); mxy = fmaxf(mxy, p.y); mxz = fmaxf(mxz, p.z);
        sx += (double)p.x; sy += (double)p.y; sz += (double)p.z; sq += (double)p.w;
    }
    for (int o = 1; o < 64; o <<= 1) {
        mnx = fminf(mnx, __shfl_xor(mnx, o));
        mny = fminf(mny, __shfl_xor(mny, o));
        mnz = fminf(mnz, __shfl_xor(mnz, o));
        mxx = fmaxf(mxx, __shfl_xor(mxx, o));
        mxy = fmaxf(mxy, __shfl_xor(mxy, o));
        mxz = fmaxf(mxz, __shfl_xor(mxz, o));
        sx += __shfl_xor(sx, o);
        sy += __shfl_xor(sy, o);
        sz += __shfl_xor(sz, o);
        sq += __shfl_xor(sq, o);
    }
    const float cx = 0.5f * (mnx + mxx);
    const float cy = 0.5f * (mny + mxy);
    const float cz = 0.5f * (mnz + mxz);
    if (lane == 0) {
        g_nc4[n] = make_float4(cx, cy, cz, 0.5f * fmaxf(fmaxf(mxx - mnx, mxy - mny), mxz - mnz));
        const float fc = (float)cnt;
        g_nm4[n] = make_float4((float)sx / fc, (float)sy / fc, (float)sz / fc, (float)sq);
    }
    if (cnt <= LEAF_SZ) {
        if (lane == 0) g_nmeta[n] = make_int4(st, en, 0, 0);
        return make_int2(0, 0);
    }

    int c8[8] = {0,0,0,0,0,0,0,0};
    for (int j = st + lane; j < en; j += 64) {
        float4 p = g_p4[j];
        int oct = (p.x >= cx ? 1 : 0) | (p.y >= cy ? 2 : 0) | (p.z >= cz ? 4 : 0);
        c8[oct]++;
    }
    #pragma unroll
    for (int k = 0; k < 8; ++k)
        for (int o = 1; o < 64; o <<= 1)
            c8[k] += __shfl_xor(c8[k], o);
    int nonempty = 0;
    #pragma unroll
    for (int k = 0; k < 8; ++k) nonempty += (c8[k] > 0) ? 1 : 0;
    if (nonempty <= 1) {
        if (lane == 0) g_nmeta[n] = make_int4(st, en, 0, 0);
        return make_int2(0, 0);
    }

    int base = 0;
    if (lane == 0) base = atomicAdd(&g_ncount, nonempty);
    base = __shfl(base, 0);
    int acc = st, ci = base;
    int off[8];
    #pragma unroll
    for (int k = 0; k < 8; ++k) {
        off[k] = acc;
        if (c8[k] > 0) {
            if (lane == 0) { g_nstart[ci] = acc; g_nend[ci] = acc + c8[k]; }
            ++ci;
        }
        acc += c8[k];
    }
    if (lane == 0) g_nmeta[n] = make_int4(st, en, base, nonempty);

    if (lane < 8) s_cur[lane] = off[lane];
    __builtin_amdgcn_wave_barrier();
    for (int j = st + lane; j < en; j += 64) {
        float4 p = g_p4[j];
        int id = g_perm[j];
        int oct = (p.x >= cx ? 1 : 0) | (p.y >= cy ? 2 : 0) | (p.z >= cz ? 4 : 0);
        int pdst = atomicAdd(&s_cur[oct], 1);
        g_ptmp[pdst] = id; g_t4[pdst] = p;
    }
    asm volatile("s_waitcnt vmcnt(0)" ::: "memory");   // scatter stores done
    __builtin_amdgcn_wave_barrier();
    for (int j = st + lane; j < en; j += 64) {
        g_perm[j] = g_ptmp[j];
        g_p4[j]   = g_t4[j];
    }
    asm volatile("s_waitcnt vmcnt(0)" ::: "memory");   // copy-back done before children read
    return make_int2(nonempty, base);
}

// Each WAVE claims frontier subtrees (one atomicAdd ticket each — allocation,
// not polling) and builds its subtree DFS with a per-wave LDS stack. Subtrees
// are independent; zero cross-wave communication; hang-impossible.
__global__ __launch_bounds__(256) void subtree_kernel()
{
    __shared__ int s_stk[4][STKW];
    __shared__ int s_cur[4][8];
    const int wid  = threadIdx.x >> 6;
    const int lane = threadIdx.x & 63;
    const int lb = g_lrange[2], le = g_lrange[3];
    int* stk = s_stk[wid];
    int* cur = s_cur[wid];

    while (true) {
        int task = 0;
        if (lane == 0) task = atomicAdd(&g_claim, 1);
        task = __shfl(task, 0);
        const int root = lb + task;
        if (root >= le) break;                    // wave-uniform
        int sp = 1;
        int node = root;
        while (true) {
            int2 r = process_node_wave(node, cur);
            --sp;                                  // current node retired
            if (r.x > 0) {
                if (lane < r.x && sp + lane < STKW) stk[sp + lane] = r.y + lane;
                __builtin_amdgcn_wave_barrier();
                sp += r.x;
                if (sp > STKW) sp = STKW;          // safety clamp (never in practice)
            }
            if (sp <= 0) break;
            node = stk[sp - 1];                    // uniform LDS broadcast read
            __builtin_amdgcn_wave_barrier();
        }
    }
}

// ---------------------------------------------------------------------------
// One wave per target. Per batch: lanes classify nodes (monopole inline),
// leaf ranges prefix-summed into a flat LDS pair list, drained by all lanes.
// ---------------------------------------------------------------------------
__global__ __launch_bounds__(256)
void traverse_kernel(const int* __restrict__ batch,
                     const float* __restrict__ p_scr, const float* __restrict__ p_soft,
                     float* __restrict__ out, int N)
{
    __shared__ int s_q[4][NQ];
    __shared__ int s_pj[4][PCAP];
    __shared__ int s_qt[4];
    const int wid  = threadIdx.x >> 6;
    const int lane = threadIdx.x & 63;
    const int slot = blockIdx.x * 4 + wid;
    if (slot >= N) return;                 // wave-uniform; no __syncthreads used
    const int t = g_perm[slot];

    const float scr   = p_scr[0];
    const float soft  = p_soft[0];
    const float soft2 = soft * soft;
    const float cexp  = -scr * 1.4426950408889634f;  // exp(-scr*r) = exp2(cexp*r)
    const float4 tp = g_p4[slot];
    const float tx = tp.x, ty = tp.y, tz = tp.z;
    const int inv_t = slot;

    volatile int* q  = s_q[wid];
    volatile int* pj = s_pj[wid];
    if (lane == 0) { q[0] = g_root[batch[t]]; s_qt[wid] = 1; }
    __builtin_amdgcn_wave_barrier();

    float phi = 0.f;
    int qh = 0;
    while (true) {
        __builtin_amdgcn_wave_barrier();
        int qt = ((volatile int*)s_qt)[wid];
        if (qh >= qt) break;
        int take = qt - qh; if (take > 64) take = 64;
        int node = (lane < take) ? q[(qh + lane) & (NQ - 1)] : -1;
        qh += take;

        int leaf_st = 0, leaf_cnt = 0;
        if (node >= 0) {
            const int4 meta = g_nmeta[node];
            if (meta.w == 0) {
                leaf_st = meta.x; leaf_cnt = meta.y - meta.x;
            } else {
                float4 c4 = g_nc4[node];
                float dx = tx - c4.x, dy = ty - c4.y, dz = tz - c4.z;
                float dist = sqrtf(dx*dx + dy*dy + dz*dz + soft2);
                float diam = fmaxf(2.0f * c4.w, 1e-9f);
                bool inside = (inv_t >= meta.x) && (inv_t < meta.y);
                if (!inside && diam < 0.5f * dist) {
                    float4 m4 = g_nm4[node];
                    float ax = tx - m4.x, ay = ty - m4.y, az = tz - m4.z;
                    float s = ax*ax + ay*ay + az*az + soft2;
                    float rinv = rsqrtf(s);
                    phi += m4.w * exp2f(cexp * (s * rinv)) * rinv;
                } else {
                    int p = atomicAdd(&s_qt[wid], meta.w);
                    for (int c = 0; c < meta.w; ++c) q[(p + c) & (NQ - 1)] = meta.z + c;
                }
            }
        }

        // wave prefix-sum of (leaf size minus self) -> flat pair list
        bool hasself = (inv_t >= leaf_st) && (inv_t < leaf_st + leaf_cnt);
        int cnt_adj = leaf_cnt - (hasself ? 1 : 0);
        int x = cnt_adj;
        #pragma unroll
        for (int o = 1; o < 64; o <<= 1) { int y = __shfl_up(x, o); if (lane >= o) x += y; }
        int total = __shfl(x, 63);
        int off = x - cnt_adj;

        if (total > 0) {
            if (total <= PCAP) {
                int w = off;
                for (int k = 0; k < leaf_cnt; ++k) {
                    int j = leaf_st + k;
                    if (j != inv_t) pj[w++] = j;
                }
                __builtin_amdgcn_wave_barrier();
                for (int p = lane; p < total; p += 64) {
                    int j = pj[p];
                    float4 pp = g_p4[j];
                    float dx = tx - pp.x, dy = ty - pp.y, dz = tz - pp.z;
                    float s = dx*dx + dy*dy + dz*dz + soft2;
                    float rinv = rsqrtf(s);
                    phi += pp.w * exp2f(cexp * (s * rinv)) * rinv;
                }
                __builtin_amdgcn_wave_barrier();
            } else {
                for (int k = 0; k < leaf_cnt; ++k) {
                    int j = leaf_st + k;
                    if (j == inv_t) continue;
                    float4 pp = g_p4[j];
                    float dx = tx - pp.x, dy = ty - pp.y, dz = tz - pp.z;
                    float s = dx*dx + dy*dy + dz*dz + soft2;
                    float rinv = rsqrtf(s);
                    phi += pp.w * exp2f(cexp * (s * rinv)) * rinv;
                }
            }
        }
    }

    #pragma unroll
    for (int o = 1; o < 64; o <<= 1) phi += __shfl_xor(phi, o);
    if (lane == 0) out[t] = 0.5f * (tp.w * phi);
}

extern "C" void kernel_launch(void* const* d_in, const int* in_sizes, int n_in,
                              void* d_out, int out_size, void* d_ws, size_t ws_size,
                              hipStream_t stream) {
    const float* pos    = (const float*)d_in[0];
    const int*   batch  = (const int*)  d_in[1];
    const float* source = (const float*)d_in[3];
    const float* p_scr  = (const float*)d_in[4];
    const float* p_soft = (const float*)d_in[5];

    const int N        = in_sizes[0] / 3;
    const int n_graphs = in_sizes[2] / 9;

    init_kernel<<<(N + 255) / 256, 256, 0, stream>>>(pos, source, N);
    roots_kernel<<<1, 256, 0, stream>>>(batch, N, n_graphs);
    level_kernel<<<BGRID, 256, 0, stream>>>(0);
    level_kernel<<<BGRID, 256, 0, stream>>>(1);
    subtree_kernel<<<BGRID, 256, 0, stream>>>();

    const int blocks = (N + 3) / 4;  // 4 waves (targets) per 256-thread block
    traverse_kernel<<<blocks, 256, 0, stream>>>(batch, p_scr, p_soft, (float*)d_out, N);
}

// Round 10
// 251.580 us; speedup vs baseline: 1.4895x; 1.0306x over previous
//
#include <hip/hip_runtime.h>

#define LEAF_SZ 32
#define MAXN 16384
#define MAXNODES 65536
#define MAXG 64
#define NQ 1024
#define PCAP 1024
#define BGRID 128
#define STKW 512
#define MAXFRONT 4096

// Static device scratch (fully rewritten each call; no cross-call state relied on).
__device__ int    g_perm[MAXN];
__device__ int    g_ptmp[MAXN];
__device__ float4 g_p4[MAXN];    // x,y,z,charge in perm order
__device__ float4 g_t4[MAXN];
__device__ int    g_nstart[MAXNODES];
__device__ int    g_nend[MAXNODES];
__device__ int4   g_nmeta[MAXNODES];  // st, en, first_child, n_children(0=leaf)
__device__ float4 g_nc4[MAXNODES];    // bbox center + half (MAC)
__device__ float4 g_nm4[MAXNODES];    // mean center + total charge (monopole)
__device__ int    g_arena[MAXFRONT];  // per-frontier-subtree node-id arena base
__device__ int    g_root[MAXG];
__device__ int    g_ncount;
__device__ int    g_lrange[8];
__device__ int    g_done[4];

struct NodeSh {
    float  mn[4][3], mx[4][3];
    double sx[4], sy[4], sz[4], sq[4];
    int    c8[4][8];
    int    cur[8];
    float  cc[3];
    int    info;
    int    base, num;
};

// Block-cooperative node processing — top levels only (R2-proven).
__device__ __forceinline__ void process_node(NodeSh& sh, int n)
{
    const int tid  = threadIdx.x;
    const int wid  = tid >> 6;
    const int lane = tid & 63;
    const int st = g_nstart[n], en = g_nend[n];
    const int cnt = en - st;

    float mnx = 3.402823466e38f, mny = mnx, mnz = mnx;
    float mxx = -mnx, mxy = -mnx, mxz = -mnx;
    double sx = 0.0, sy = 0.0, sz = 0.0, sq = 0.0;
    for (int j = st + tid; j < en; j += 256) {
        float4 p = g_p4[j];
        mnx = fminf(mnx, p.x); mny = fminf(mny, p.y); mnz = fminf(mnz, p.z);
        mxx = fmaxf(mxx, p.x); mxy = fmaxf(mxy, p.y); mxz = fmaxf(mxz, p.z);
        sx += (double)p.x; sy += (double)p.y; sz += (double)p.z; sq += (double)p.w;
    }
    for (int o = 1; o < 64; o <<= 1) {
        mnx = fminf(mnx, __shfl_xor(mnx, o));
        mny = fminf(mny, __shfl_xor(mny, o));
        mnz = fminf(mnz, __shfl_xor(mnz, o));
        mxx = fmaxf(mxx, __shfl_xor(mxx, o));
        mxy = fmaxf(mxy, __shfl_xor(mxy, o));
        mxz = fmaxf(mxz, __shfl_xor(mxz, o));
        sx += __shfl_xor(sx, o);
        sy += __shfl_xor(sy, o);
        sz += __shfl_xor(sz, o);
        sq += __shfl_xor(sq, o);
    }
    if (lane == 0) {
        sh.mn[wid][0] = mnx; sh.mn[wid][1] = mny; sh.mn[wid][2] = mnz;
        sh.mx[wid][0] = mxx; sh.mx[wid][1] = mxy; sh.mx[wid][2] = mxz;
        sh.sx[wid] = sx; sh.sy[wid] = sy; sh.sz[wid] = sz; sh.sq[wid] = sq;
    }
    __syncthreads();
    if (tid == 0) {
        float a0 = sh.mn[0][0], a1 = sh.mn[0][1], a2 = sh.mn[0][2];
        float b0 = sh.mx[0][0], b1 = sh.mx[0][1], b2 = sh.mx[0][2];
        double tx = sh.sx[0], ty = sh.sy[0], tz = sh.sz[0], tq = sh.sq[0];
        for (int w = 1; w < 4; ++w) {
            a0 = fminf(a0, sh.mn[w][0]); a1 = fminf(a1, sh.mn[w][1]); a2 = fminf(a2, sh.mn[w][2]);
            b0 = fmaxf(b0, sh.mx[w][0]); b1 = fmaxf(b1, sh.mx[w][1]); b2 = fmaxf(b2, sh.mx[w][2]);
            tx += sh.sx[w]; ty += sh.sy[w]; tz += sh.sz[w]; tq += sh.sq[w];
        }
        float cx = 0.5f * (a0 + b0), cy = 0.5f * (a1 + b1), cz = 0.5f * (a2 + b2);
        g_nc4[n] = make_float4(cx, cy, cz, 0.5f * fmaxf(fmaxf(b0 - a0, b1 - a1), b2 - a2));
        const float fc = (float)cnt;
        g_nm4[n] = make_float4((float)tx / fc, (float)ty / fc, (float)tz / fc, (float)tq);
        sh.cc[0] = cx; sh.cc[1] = cy; sh.cc[2] = cz;
        if (cnt <= LEAF_SZ) { g_nmeta[n] = make_int4(st, en, 0, 0); sh.info = -1; }
        else sh.info = 0;
    }
    __syncthreads();
    if (sh.info < 0) return;
    const float cx = sh.cc[0], cy = sh.cc[1], cz = sh.cc[2];

    int c8[8] = {0,0,0,0,0,0,0,0};
    for (int j = st + tid; j < en; j += 256) {
        float4 p = g_p4[j];
        int oct = (p.x >= cx ? 1 : 0) | (p.y >= cy ? 2 : 0) | (p.z >= cz ? 4 : 0);
        c8[oct]++;
    }
    #pragma unroll
    for (int k = 0; k < 8; ++k)
        for (int o = 1; o < 64; o <<= 1)
            c8[k] += __shfl_xor(c8[k], o);
    if (lane == 0)
        #pragma unroll
        for (int k = 0; k < 8; ++k) sh.c8[wid][k] = c8[k];
    __syncthreads();
    if (tid == 0) {
        int tot[8], nonempty = 0;
        #pragma unroll
        for (int k = 0; k < 8; ++k) {
            tot[k] = sh.c8[0][k] + sh.c8[1][k] + sh.c8[2][k] + sh.c8[3][k];
            nonempty += (tot[k] > 0) ? 1 : 0;
        }
        if (nonempty <= 1) { g_nmeta[n] = make_int4(st, en, 0, 0); sh.info = -1; }
        else {
            int base = atomicAdd(&g_ncount, nonempty);
            int acc = st, ci = base;
            #pragma unroll
            for (int k = 0; k < 8; ++k) {
                sh.cur[k] = acc;
                if (tot[k] > 0) { g_nstart[ci] = acc; g_nend[ci] = acc + tot[k]; ++ci; }
                acc += tot[k];
            }
            g_nmeta[n] = make_int4(st, en, base, nonempty);
            sh.base = base; sh.num = nonempty; sh.info = 1;
        }
    }
    __syncthreads();
    if (sh.info < 0) return;

    for (int j = st + tid; j < en; j += 256) {
        float4 p = g_p4[j];
        int id = g_perm[j];
        int oct = (p.x >= cx ? 1 : 0) | (p.y >= cy ? 2 : 0) | (p.z >= cz ? 4 : 0);
        int pdst = atomicAdd(&sh.cur[oct], 1);
        g_ptmp[pdst] = id; g_t4[pdst] = p;
    }
    __syncthreads();
    for (int j = st + tid; j < en; j += 256) {
        g_perm[j] = g_ptmp[j];
        g_p4[j]   = g_t4[j];
    }
    __syncthreads();
}

__global__ void init_kernel(const float* __restrict__ pos, const float* __restrict__ src, int N)
{
    int i = blockIdx.x * blockDim.x + threadIdx.x;
    if (i < N) {
        g_perm[i] = i;
        g_p4[i] = make_float4(pos[3*i], pos[3*i+1], pos[3*i+2], src[i]);
    }
}

__global__ __launch_bounds__(256) void roots_kernel(const int* __restrict__ batch, int N, int n_graphs)
{
    __shared__ int s_first[MAXG], s_end[MAXG];
    const int tid = threadIdx.x;
    for (int g = tid; g < MAXG; g += 256) { s_first[g] = -1; s_end[g] = 0; }
    __syncthreads();
    for (int i = tid; i < N; i += 256) {
        int b = batch[i];
        if (i == 0     || batch[i-1] != b) s_first[b] = i;
        if (i == N - 1 || batch[i+1] != b) s_end[b]   = i + 1;
    }
    __syncthreads();
    if (tid == 0) {
        int nc = 0;
        for (int g = 0; g < n_graphs && g < MAXG; ++g) {
            if (s_first[g] >= 0) {
                g_root[g] = nc;
                g_nstart[nc] = s_first[g];
                g_nend[nc]   = s_end[g];
                ++nc;
            } else g_root[g] = -1;
        }
        g_ncount = nc;
        g_lrange[0] = 0; g_lrange[1] = nc;
        g_done[0] = g_done[1] = g_done[2] = g_done[3] = 0;
    }
}

// One launch per level (2 levels): kernel boundary = free device-wide barrier.
__global__ __launch_bounds__(256) void level_kernel(int lev)
{
    __shared__ NodeSh sh;
    const int lb = g_lrange[lev], le = g_lrange[lev + 1];
    for (int n = lb + blockIdx.x; n < le; n += BGRID) {
        __syncthreads();
        process_node(sh, n);
    }
    __syncthreads();
    if (threadIdx.x == 0) {
        __threadfence();
        int d = atomicAdd(&g_done[lev], 1);
        if (d == BGRID - 1)
            g_lrange[lev + 2] = atomicAdd(&g_ncount, 0);
    }
}

// One wave: exclusive prefix-scan of per-subtree arena sizes (2*cnt bound:
// a tree on A atoms has <= 2A-1 nodes; root pre-exists -> children <= 2A-2).
__global__ void arena_kernel()
{
    const int lane = threadIdx.x;
    const int lb = g_lrange[2], le = g_lrange[3];
    const int n = le - lb;
    int base = le;
    for (int c = 0; c < n; c += 64) {
        int i = c + lane;
        int v = (i < n) ? 2 * (g_nend[lb + i] - g_nstart[lb + i]) : 0;
        int x = v;
        for (int o = 1; o < 64; o <<= 1) { int y = __shfl_up(x, o); if (lane >= o) x += y; }
        if (i < n) g_arena[i] = base + x - v;
        base += __shfl(x, 63);
    }
}

// ---------------------------------------------------------------------------
// Wave-granular subtree build, zero device atomics.
// small path (cnt<=64): everything in registers — one load, shfl reduce,
// ballot counts, ballot-prefix in-place scatter, stack push of child ranges.
// big path (cnt>64): R9's multi-pass with tmp scatter, arena alloc.
// Both push (id,st,en) onto the per-wave LDS stack; return #children.
// ---------------------------------------------------------------------------
__device__ __forceinline__ int proc_small(int n, int st, int en, int abase,
                                          int* sid, int* sst, int* sen, int sp)
{
    const int lane = threadIdx.x & 63;
    const int cnt = en - st;
    const bool act = lane < cnt;

    float4 p = act ? g_p4[st + lane] : make_float4(0.f, 0.f, 0.f, 0.f);
    int    id = act ? g_perm[st + lane] : 0;

    float mnx = act ? p.x : 3.402823466e38f;
    float mny = act ? p.y : 3.402823466e38f;
    float mnz = act ? p.z : 3.402823466e38f;
    float mxx = act ? p.x : -3.402823466e38f;
    float mxy = act ? p.y : -3.402823466e38f;
    float mxz = act ? p.z : -3.402823466e38f;
    double sx = act ? (double)p.x : 0.0;
    double sy = act ? (double)p.y : 0.0;
    double sz = act ? (double)p.z : 0.0;
    double sq = act ? (double)p.w : 0.0;
    for (int o = 1; o < 64; o <<= 1) {
        mnx = fminf(mnx, __shfl_xor(mnx, o));
        mny = fminf(mny, __shfl_xor(mny, o));
        mnz = fminf(mnz, __shfl_xor(mnz, o));
        mxx = fmaxf(mxx, __shfl_xor(mxx, o));
        mxy = fmaxf(mxy, __shfl_xor(mxy, o));
        mxz = fmaxf(mxz, __shfl_xor(mxz, o));
        sx += __shfl_xor(sx, o);
        sy += __shfl_xor(sy, o);
        sz += __shfl_xor(sz, o);
        sq += __shfl_xor(sq, o);
    }
    const float cx = 0.5f * (mnx + mxx);
    const float cy = 0.5f * (mny + mxy);
    const float cz = 0.5f * (mnz + mxz);
    if (lane == 0) {
        g_nc4[n] = make_float4(cx, cy, cz, 0.5f * fmaxf(fmaxf(mxx - mnx, mxy - mny), mxz - mnz));
        const float fc = (float)cnt;
        g_nm4[n] = make_float4((float)sx / fc, (float)sy / fc, (float)sz / fc, (float)sq);
    }
    if (cnt <= LEAF_SZ) {
        if (lane == 0) g_nmeta[n] = make_int4(st, en, 0, 0);
        return 0;
    }

    const int oct = (p.x >= cx ? 1 : 0) | (p.y >= cy ? 2 : 0) | (p.z >= cz ? 4 : 0);
    unsigned long long bal[8];
    #pragma unroll
    for (int k = 0; k < 8; ++k) bal[k] = __ballot(act && oct == k);
    int c8[8], nonempty = 0;
    #pragma unroll
    for (int k = 0; k < 8; ++k) { c8[k] = (int)__popcll(bal[k]); nonempty += (c8[k] > 0) ? 1 : 0; }
    if (nonempty <= 1) {
        if (lane == 0) g_nmeta[n] = make_int4(st, en, 0, 0);
        return 0;
    }

    int off[8], acc = 0;
    #pragma unroll
    for (int k = 0; k < 8; ++k) { off[k] = acc; acc += c8[k]; }
    if (lane == 0) {
        g_nmeta[n] = make_int4(st, en, abase, nonempty);
        int ci = 0;
        #pragma unroll
        for (int k = 0; k < 8; ++k) {
            if (c8[k] > 0) {
                sid[sp + ci] = abase + ci;
                sst[sp + ci] = st + off[k];
                sen[sp + ci] = st + off[k] + c8[k];
                ++ci;
            }
        }
    }
    // in-place scatter: values already in registers, ballot-prefix rank
    if (act) {
        int npos = st + off[oct] + (int)__popcll(bal[oct] & ((1ull << lane) - 1ull));
        g_p4[npos] = p;
        g_perm[npos] = id;
    }
    asm volatile("s_waitcnt vmcnt(0)" ::: "memory");   // children reload this region
    return nonempty;
}

__device__ __forceinline__ int proc_big(int n, int st, int en, int abase, int* cur,
                                        int* sid, int* sst, int* sen, int sp)
{
    const int lane = threadIdx.x & 63;
    const int cnt = en - st;

    float mnx = 3.402823466e38f, mny = mnx, mnz = mnx;
    float mxx = -mnx, mxy = -mnx, mxz = -mnx;
    double sx = 0.0, sy = 0.0, sz = 0.0, sq = 0.0;
    for (int j = st + lane; j < en; j += 64) {
        float4 p = g_p4[j];
        mnx = fminf(mnx, p.x); mny = fminf(mny, p.y); mnz = fminf(mnz, p.z);
        mxx = fmaxf(mxx, p.x); mxy = fmaxf(mxy, p.y); mxz = fmaxf(mxz, p.z);
        sx += (double)p.x; sy += (double)p.y; sz += (double)p.z; sq += (double)p.w;
    }
    for (int o = 1; o < 64; o <<= 1) {
        mnx = fminf(mnx, __shfl_xor(mnx, o));
        mny = fminf(mny, __shfl_xor(mny, o));
        mnz = fminf(mnz, __shfl_xor(mnz, o));
        mxx = fmaxf(mxx, __shfl_xor(mxx, o));
        mxy = fmaxf(mxy, __shfl_xor(mxy, o));
        mxz = fmaxf(mxz, __shfl_xor(mxz, o));
        sx += __shfl_xor(sx, o);
        sy += __shfl_xor(sy, o);
        sz += __shfl_xor(sz, o);
        sq += __shfl_xor(sq, o);
    }
    const float cx = 0.5f * (mnx + mxx);
    const float cy = 0.5f * (mny + mxy);
    const float cz = 0.5f * (mnz + mxz);
    if (lane == 0) {
        g_nc4[n] = make_float4(cx, cy, cz, 0.5f * fmaxf(fmaxf(mxx - mnx, mxy - mny), mxz - mnz));
        const float fc = (float)cnt;
        g_nm4[n] = make_float4((float)sx / fc, (float)sy / fc, (float)sz / fc, (float)sq);
    }
    // cnt > 64 > LEAF_SZ: never a size-leaf

    int c8[8] = {0,0,0,0,0,0,0,0};
    for (int j = st + lane; j < en; j += 64) {
        float4 p = g_p4[j];
        int oct = (p.x >= cx ? 1 : 0) | (p.y >= cy ? 2 : 0) | (p.z >= cz ? 4 : 0);
        c8[oct]++;
    }
    #pragma unroll
    for (int k = 0; k < 8; ++k)
        for (int o = 1; o < 64; o <<= 1)
            c8[k] += __shfl_xor(c8[k], o);
    int nonempty = 0;
    #pragma unroll
    for (int k = 0; k < 8; ++k) nonempty += (c8[k] > 0) ? 1 : 0;
    if (nonempty <= 1) {
        if (lane == 0) g_nmeta[n] = make_int4(st, en, 0, 0);
        return 0;
    }

    int off[8], acc = 0;
    #pragma unroll
    for (int k = 0; k < 8; ++k) { off[k] = acc; acc += c8[k]; }
    if (lane == 0) {
        g_nmeta[n] = make_int4(st, en, abase, nonempty);
        int ci = 0;
        #pragma unroll
        for (int k = 0; k < 8; ++k) {
            if (c8[k] > 0) {
                sid[sp + ci] = abase + ci;
                sst[sp + ci] = st + off[k];
                sen[sp + ci] = st + off[k] + c8[k];
                ++ci;
            }
        }
    }
    if (lane < 8) cur[lane] = st + off[lane];
    __builtin_amdgcn_wave_barrier();
    for (int j = st + lane; j < en; j += 64) {
        float4 p = g_p4[j];
        int id = g_perm[j];
        int oct = (p.x >= cx ? 1 : 0) | (p.y >= cy ? 2 : 0) | (p.z >= cz ? 4 : 0);
        int pdst = atomicAdd(&cur[oct], 1);
        g_ptmp[pdst] = id; g_t4[pdst] = p;
    }
    asm volatile("s_waitcnt vmcnt(0)" ::: "memory");
    __builtin_amdgcn_wave_barrier();
    for (int j = st + lane; j < en; j += 64) {
        g_perm[j] = g_ptmp[j];
        g_p4[j]   = g_t4[j];
    }
    asm volatile("s_waitcnt vmcnt(0)" ::: "memory");
    return nonempty;
}

// Static task->wave mapping (no claim atomics); per-subtree arena (no alloc
// atomics); DFS with (id,st,en) LDS stack (no meta reloads).
__global__ __launch_bounds__(256) void subtree_kernel()
{
    __shared__ int s_id[4][STKW], s_st[4][STKW], s_en[4][STKW];
    __shared__ int s_cur[4][8];
    const int wid  = threadIdx.x >> 6;
    const int gw   = blockIdx.x * 4 + wid;     // global wave id
    const int lb = g_lrange[2], le = g_lrange[3];
    const int ntasks = le - lb;
    int* sid = s_id[wid];
    int* sst = s_st[wid];
    int* sen = s_en[wid];
    int* cur = s_cur[wid];

    for (int task = gw; task < ntasks; task += BGRID * 4) {
        int cn  = lb + task;
        int cst = g_nstart[cn], cen = g_nend[cn];
        int abase = g_arena[task];
        int sp = 0;
        while (true) {
            int num;
            if (cen - cst <= 64) num = proc_small(cn, cst, cen, abase, sid, sst, sen, sp);
            else                 num = proc_big(cn, cst, cen, abase, cur, sid, sst, sen, sp);
            abase += num;
            sp += num;
            if (sp > STKW) sp = STKW;          // safety clamp (never in practice)
            if (sp <= 0) break;
            --sp;
            __builtin_amdgcn_wave_barrier();
            cn = sid[sp]; cst = sst[sp]; cen = sen[sp];   // uniform LDS broadcast
            __builtin_amdgcn_wave_barrier();
        }
    }
}

// ---------------------------------------------------------------------------
// One wave per target. Per batch: lanes classify nodes (monopole inline),
// leaf ranges prefix-summed into a flat LDS pair list, drained by all lanes.
// ---------------------------------------------------------------------------
__global__ __launch_bounds__(256)
void traverse_kernel(const int* __restrict__ batch,
                     const float* __restrict__ p_scr, const float* __restrict__ p_soft,
                     float* __restrict__ out, int N)
{
    __shared__ int s_q[4][NQ];
    __shared__ int s_pj[4][PCAP];
    __shared__ int s_qt[4];
    const int wid  = threadIdx.x >> 6;
    const int lane = threadIdx.x & 63;
    const int slot = blockIdx.x * 4 + wid;
    if (slot >= N) return;                 // wave-uniform; no __syncthreads used
    const int t = g_perm[slot];

    const float scr   = p_scr[0];
    const float soft  = p_soft[0];
    const float soft2 = soft * soft;
    const float cexp  = -scr * 1.4426950408889634f;  // exp(-scr*r) = exp2(cexp*r)
    const float4 tp = g_p4[slot];
    const float tx = tp.x, ty = tp.y, tz = tp.z;
    const int inv_t = slot;

    volatile int* q  = s_q[wid];
    volatile int* pj = s_pj[wid];
    if (lane == 0) { q[0] = g_root[batch[t]]; s_qt[wid] = 1; }
    __builtin_amdgcn_wave_barrier();

    float phi = 0.f;
    int qh = 0;
    while (true) {
        __builtin_amdgcn_wave_barrier();
        int qt = ((volatile int*)s_qt)[wid];
        if (qh >= qt) break;
        int take = qt - qh; if (take > 64) take = 64;
        int node = (lane < take) ? q[(qh + lane) & (NQ - 1)] : -1;
        qh += take;

        int leaf_st = 0, leaf_cnt = 0;
        if (node >= 0) {
            const int4 meta = g_nmeta[node];
            if (meta.w == 0) {
                leaf_st = meta.x; leaf_cnt = meta.y - meta.x;
            } else {
                float4 c4 = g_nc4[node];
                float dx = tx - c4.x, dy = ty - c4.y, dz = tz - c4.z;
                float dist = sqrtf(dx*dx + dy*dy + dz*dz + soft2);
                float diam = fmaxf(2.0f * c4.w, 1e-9f);
                bool inside = (inv_t >= meta.x) && (inv_t < meta.y);
                if (!inside && diam < 0.5f * dist) {
                    float4 m4 = g_nm4[node];
                    float ax = tx - m4.x, ay = ty - m4.y, az = tz - m4.z;
                    float s = ax*ax + ay*ay + az*az + soft2;
                    float rinv = rsqrtf(s);
                    phi += m4.w * exp2f(cexp * (s * rinv)) * rinv;
                } else {
                    int p = atomicAdd(&s_qt[wid], meta.w);
                    for (int c = 0; c < meta.w; ++c) q[(p + c) & (NQ - 1)] = meta.z + c;
                }
            }
        }

        // wave prefix-sum of (leaf size minus self) -> flat pair list
        bool hasself = (inv_t >= leaf_st) && (inv_t < leaf_st + leaf_cnt);
        int cnt_adj = leaf_cnt - (hasself ? 1 : 0);
        int x = cnt_adj;
        #pragma unroll
        for (int o = 1; o < 64; o <<= 1) { int y = __shfl_up(x, o); if (lane >= o) x += y; }
        int total = __shfl(x, 63);
        int off = x - cnt_adj;

        if (total > 0) {
            if (total <= PCAP) {
                int w = off;
                for (int k = 0; k < leaf_cnt; ++k) {
                    int j = leaf_st + k;
                    if (j != inv_t) pj[w++] = j;
                }
                __builtin_amdgcn_wave_barrier();
                for (int p = lane; p < total; p += 64) {
                    int j = pj[p];
                    float4 pp = g_p4[j];
                    float dx = tx - pp.x, dy = ty - pp.y, dz = tz - pp.z;
                    float s = dx*dx + dy*dy + dz*dz + soft2;
                    float rinv = rsqrtf(s);
                    phi += pp.w * exp2f(cexp * (s * rinv)) * rinv;
                }
                __builtin_amdgcn_wave_barrier();
            } else {
                for (int k = 0; k < leaf_cnt; ++k) {
                    int j = leaf_st + k;
                    if (j == inv_t) continue;
                    float4 pp = g_p4[j];
                    float dx = tx - pp.x, dy = ty - pp.y, dz = tz - pp.z;
                    float s = dx*dx + dy*dy + dz*dz + soft2;
                    float rinv = rsqrtf(s);
                    phi += pp.w * exp2f(cexp * (s * rinv)) * rinv;
                }
            }
        }
    }

    #pragma unroll
    for (int o = 1; o < 64; o <<= 1) phi += __shfl_xor(phi, o);
    if (lane == 0) out[t] = 0.5f * (tp.w * phi);
}

extern "C" void kernel_launch(void* const* d_in, const int* in_sizes, int n_in,
                              void* d_out, int out_size, void* d_ws, size_t ws_size,
                              hipStream_t stream) {
    const float* pos    = (const float*)d_in[0];
    const int*   batch  = (const int*)  d_in[1];
    const float* source = (const float*)d_in[3];
    const float* p_scr  = (const float*)d_in[4];
    const float* p_soft = (const float*)d_in[5];

    const int N        = in_sizes[0] / 3;
    const int n_graphs = in_sizes[2] / 9;

    init_kernel<<<(N + 255) / 256, 256, 0, stream>>>(pos, source, N);
    roots_kernel<<<1, 256, 0, stream>>>(batch, N, n_graphs);
    level_kernel<<<BGRID, 256, 0, stream>>>(0);
    level_kernel<<<BGRID, 256, 0, stream>>>(1);
    arena_kernel<<<1, 64, 0, stream>>>();
    subtree_kernel<<<BGRID, 256, 0, stream>>>();

    const int blocks = (N + 3) / 4;  // 4 waves (targets) per 256-thread block
    traverse_kernel<<<blocks, 256, 0, stream>>>(batch, p_scr, p_soft, (float*)d_out, N);
}

// Round 11
// 243.742 us; speedup vs baseline: 1.5374x; 1.0322x over previous
//
#include <hip/hip_runtime.h>

#define LEAF_SZ 32
#define MAXN 16384
#define MAXNODES 65536
#define MAXG 64
#define NQ 1024
#define PCAP 1024
#define BGRID 128
#define LCAP 256
#define LSTK 192
#define GSTK 64

// Static device scratch (fully rewritten each call; no cross-call state relied on).
__device__ int    g_perm[MAXN];
__device__ int    g_ptmp[MAXN];
__device__ float4 g_p4[MAXN];    // x,y,z,charge in perm order
__device__ float4 g_t4[MAXN];
__device__ int    g_nstart[MAXNODES];
__device__ int    g_nend[MAXNODES];
__device__ int4   g_nmeta[MAXNODES];  // st, en, first_child, n_children(0=leaf)
__device__ float4 g_nc4[MAXNODES];    // bbox center + half (MAC)
__device__ float4 g_nm4[MAXNODES];    // mean center + total charge (monopole)
__device__ int    g_root[MAXG];
__device__ int    g_ncount;
__device__ int    g_lrange[8];
__device__ int    g_done[4];

struct NodeSh {
    float  mn[4][3], mx[4][3];
    double sx[4], sy[4], sz[4], sq[4];
    int    c8[4][8];
    int    cur[8];
    float  cc[3];
    int    info;
    int    base, num;
};

// Block-cooperative node processing — top levels only (R2-proven).
__device__ __forceinline__ void process_node(NodeSh& sh, int n)
{
    const int tid  = threadIdx.x;
    const int wid  = tid >> 6;
    const int lane = tid & 63;
    const int st = g_nstart[n], en = g_nend[n];
    const int cnt = en - st;

    float mnx = 3.402823466e38f, mny = mnx, mnz = mnx;
    float mxx = -mnx, mxy = -mnx, mxz = -mnx;
    double sx = 0.0, sy = 0.0, sz = 0.0, sq = 0.0;
    for (int j = st + tid; j < en; j += 256) {
        float4 p = g_p4[j];
        mnx = fminf(mnx, p.x); mny = fminf(mny, p.y); mnz = fminf(mnz, p.z);
        mxx = fmaxf(mxx, p.x); mxy = fmaxf(mxy, p.y); mxz = fmaxf(mxz, p.z);
        sx += (double)p.x; sy += (double)p.y; sz += (double)p.z; sq += (double)p.w;
    }
    for (int o = 1; o < 64; o <<= 1) {
        mnx = fminf(mnx, __shfl_xor(mnx, o));
        mny = fminf(mny, __shfl_xor(mny, o));
        mnz = fminf(mnz, __shfl_xor(mnz, o));
        mxx = fmaxf(mxx, __shfl_xor(mxx, o));
        mxy = fmaxf(mxy, __shfl_xor(mxy, o));
        mxz = fmaxf(mxz, __shfl_xor(mxz, o));
        sx += __shfl_xor(sx, o);
        sy += __shfl_xor(sy, o);
        sz += __shfl_xor(sz, o);
        sq += __shfl_xor(sq, o);
    }
    if (lane == 0) {
        sh.mn[wid][0] = mnx; sh.mn[wid][1] = mny; sh.mn[wid][2] = mnz;
        sh.mx[wid][0] = mxx; sh.mx[wid][1] = mxy; sh.mx[wid][2] = mxz;
        sh.sx[wid] = sx; sh.sy[wid] = sy; sh.sz[wid] = sz; sh.sq[wid] = sq;
    }
    __syncthreads();
    if (tid == 0) {
        float a0 = sh.mn[0][0], a1 = sh.mn[0][1], a2 = sh.mn[0][2];
        float b0 = sh.mx[0][0], b1 = sh.mx[0][1], b2 = sh.mx[0][2];
        double tx = sh.sx[0], ty = sh.sy[0], tz = sh.sz[0], tq = sh.sq[0];
        for (int w = 1; w < 4; ++w) {
            a0 = fminf(a0, sh.mn[w][0]); a1 = fminf(a1, sh.mn[w][1]); a2 = fminf(a2, sh.mn[w][2]);
            b0 = fmaxf(b0, sh.mx[w][0]); b1 = fmaxf(b1, sh.mx[w][1]); b2 = fmaxf(b2, sh.mx[w][2]);
            tx += sh.sx[w]; ty += sh.sy[w]; tz += sh.sz[w]; tq += sh.sq[w];
        }
        float cx = 0.5f * (a0 + b0), cy = 0.5f * (a1 + b1), cz = 0.5f * (a2 + b2);
        g_nc4[n] = make_float4(cx, cy, cz, 0.5f * fmaxf(fmaxf(b0 - a0, b1 - a1), b2 - a2));
        const float fc = (float)cnt;
        g_nm4[n] = make_float4((float)tx / fc, (float)ty / fc, (float)tz / fc, (float)tq);
        sh.cc[0] = cx; sh.cc[1] = cy; sh.cc[2] = cz;
        if (cnt <= LEAF_SZ) { g_nmeta[n] = make_int4(st, en, 0, 0); sh.info = -1; }
        else sh.info = 0;
    }
    __syncthreads();
    if (sh.info < 0) return;
    const float cx = sh.cc[0], cy = sh.cc[1], cz = sh.cc[2];

    int c8[8] = {0,0,0,0,0,0,0,0};
    for (int j = st + tid; j < en; j += 256) {
        float4 p = g_p4[j];
        int oct = (p.x >= cx ? 1 : 0) | (p.y >= cy ? 2 : 0) | (p.z >= cz ? 4 : 0);
        c8[oct]++;
    }
    #pragma unroll
    for (int k = 0; k < 8; ++k)
        for (int o = 1; o < 64; o <<= 1)
            c8[k] += __shfl_xor(c8[k], o);
    if (lane == 0)
        #pragma unroll
        for (int k = 0; k < 8; ++k) sh.c8[wid][k] = c8[k];
    __syncthreads();
    if (tid == 0) {
        int tot[8], nonempty = 0;
        #pragma unroll
        for (int k = 0; k < 8; ++k) {
            tot[k] = sh.c8[0][k] + sh.c8[1][k] + sh.c8[2][k] + sh.c8[3][k];
            nonempty += (tot[k] > 0) ? 1 : 0;
        }
        if (nonempty <= 1) { g_nmeta[n] = make_int4(st, en, 0, 0); sh.info = -1; }
        else {
            int base = atomicAdd(&g_ncount, nonempty);
            int acc = st, ci = base;
            #pragma unroll
            for (int k = 0; k < 8; ++k) {
                sh.cur[k] = acc;
                if (tot[k] > 0) { g_nstart[ci] = acc; g_nend[ci] = acc + tot[k]; ++ci; }
                acc += tot[k];
            }
            g_nmeta[n] = make_int4(st, en, base, nonempty);
            sh.base = base; sh.num = nonempty; sh.info = 1;
        }
    }
    __syncthreads();
    if (sh.info < 0) return;

    for (int j = st + tid; j < en; j += 256) {
        float4 p = g_p4[j];
        int id = g_perm[j];
        int oct = (p.x >= cx ? 1 : 0) | (p.y >= cy ? 2 : 0) | (p.z >= cz ? 4 : 0);
        int pdst = atomicAdd(&sh.cur[oct], 1);
        g_ptmp[pdst] = id; g_t4[pdst] = p;
    }
    __syncthreads();
    for (int j = st + tid; j < en; j += 256) {
        g_perm[j] = g_ptmp[j];
        g_p4[j]   = g_t4[j];
    }
    __syncthreads();
}

__global__ void init_kernel(const float* __restrict__ pos, const float* __restrict__ src, int N)
{
    int i = blockIdx.x * blockDim.x + threadIdx.x;
    if (i < N) {
        g_perm[i] = i;
        g_p4[i] = make_float4(pos[3*i], pos[3*i+1], pos[3*i+2], src[i]);
    }
}

__global__ __launch_bounds__(256) void roots_kernel(const int* __restrict__ batch, int N, int n_graphs)
{
    __shared__ int s_first[MAXG], s_end[MAXG];
    const int tid = threadIdx.x;
    for (int g = tid; g < MAXG; g += 256) { s_first[g] = -1; s_end[g] = 0; }
    __syncthreads();
    for (int i = tid; i < N; i += 256) {
        int b = batch[i];
        if (i == 0     || batch[i-1] != b) s_first[b] = i;
        if (i == N - 1 || batch[i+1] != b) s_end[b]   = i + 1;
    }
    __syncthreads();
    if (tid == 0) {
        int nc = 0;
        for (int g = 0; g < n_graphs && g < MAXG; ++g) {
            if (s_first[g] >= 0) {
                g_root[g] = nc;
                g_nstart[nc] = s_first[g];
                g_nend[nc]   = s_end[g];
                ++nc;
            } else g_root[g] = -1;
        }
        g_ncount = nc;
        g_lrange[0] = 0; g_lrange[1] = nc;
        g_done[0] = g_done[1] = 0;
    }
}

// One launch per level (2 levels): kernel boundary = free device-wide barrier.
__global__ __launch_bounds__(256) void level_kernel(int lev)
{
    __shared__ NodeSh sh;
    const int lb = g_lrange[lev], le = g_lrange[lev + 1];
    for (int n = lb + blockIdx.x; n < le; n += BGRID) {
        __syncthreads();
        process_node(sh, n);
    }
    __syncthreads();
    if (threadIdx.x == 0) {
        __threadfence();
        int d = atomicAdd(&g_done[lev], 1);
        if (d == BGRID - 1)
            g_lrange[lev + 2] = atomicAdd(&g_ncount, 0);
    }
}

// ---------------------------------------------------------------------------
// LDS-resident subtree DFS (cnt <= LCAP): load segment once, whole DFS out of
// LDS/registers, in-place ballot-rank scatter (DS pipe is in-order per wave),
// fire-and-forget node-output stores, one write-back at the end.
// ---------------------------------------------------------------------------
__device__ __forceinline__ void lds_subtree(int rootn, int st, int en, int& abase,
                                            float4* a4, int* aid,
                                            int* lid, int* la, int* lbb)
{
    const int lane = threadIdx.x & 63;
    const int cnt = en - st;
    const unsigned long long mlt = (1ull << lane) - 1ull;

    for (int j = lane; j < cnt; j += 64) {
        a4[j]  = g_p4[st + j];
        aid[j] = g_perm[st + j];
    }
    asm volatile("s_waitcnt vmcnt(0) lgkmcnt(0)" ::: "memory");
    __builtin_amdgcn_wave_barrier();

    int sp = 0;
    int cn = rootn, ca = 0, cb = cnt;
    while (true) {
        const int c = cb - ca;
        float4 pv[4]; int idv[4]; int oc[4];
        float mnx = 3.402823466e38f, mny = mnx, mnz = mnx;
        float mxx = -mnx, mxy = -mnx, mxz = -mnx;
        float sx = 0.f, sy = 0.f, sz = 0.f, sq = 0.f;
        #pragma unroll
        for (int i = 0; i < 4; ++i) {
            bool act = (i*64 + lane) < c;
            int j = act ? (ca + i*64 + lane) : ca;   // clamped addr: always in-bounds
            float4 p = a4[j];
            pv[i] = p; idv[i] = aid[j];
            if (act) {
                mnx = fminf(mnx, p.x); mny = fminf(mny, p.y); mnz = fminf(mnz, p.z);
                mxx = fmaxf(mxx, p.x); mxy = fmaxf(mxy, p.y); mxz = fmaxf(mxz, p.z);
                sx += p.x; sy += p.y; sz += p.z; sq += p.w;
            }
        }
        for (int o = 1; o < 64; o <<= 1) {
            mnx = fminf(mnx, __shfl_xor(mnx, o));
            mny = fminf(mny, __shfl_xor(mny, o));
            mnz = fminf(mnz, __shfl_xor(mnz, o));
            mxx = fmaxf(mxx, __shfl_xor(mxx, o));
            mxy = fmaxf(mxy, __shfl_xor(mxy, o));
            mxz = fmaxf(mxz, __shfl_xor(mxz, o));
            sx += __shfl_xor(sx, o);
            sy += __shfl_xor(sy, o);
            sz += __shfl_xor(sz, o);
            sq += __shfl_xor(sq, o);
        }
        const float cx = 0.5f * (mnx + mxx);
        const float cy = 0.5f * (mny + mxy);
        const float cz = 0.5f * (mnz + mxz);
        if (lane == 0) {
            g_nc4[cn] = make_float4(cx, cy, cz, 0.5f * fmaxf(fmaxf(mxx - mnx, mxy - mny), mxz - mnz));
            const float fc = (float)c;
            g_nm4[cn] = make_float4(sx / fc, sy / fc, sz / fc, sq);
        }

        int nonempty = 0;
        int c8[8] = {0,0,0,0,0,0,0,0};
        if (c > LEAF_SZ) {
            #pragma unroll
            for (int i = 0; i < 4; ++i) {
                bool act = (i*64 + lane) < c;
                int o = act ? ((pv[i].x >= cx ? 1 : 0) | (pv[i].y >= cy ? 2 : 0) | (pv[i].z >= cz ? 4 : 0)) : 8;
                oc[i] = o;
                #pragma unroll
                for (int k = 0; k < 8; ++k)
                    c8[k] += (int)__popcll(__ballot(o == k));
            }
            #pragma unroll
            for (int k = 0; k < 8; ++k) nonempty += (c8[k] > 0) ? 1 : 0;
        }

        if (c <= LEAF_SZ || nonempty <= 1) {
            if (lane == 0) g_nmeta[cn] = make_int4(st + ca, st + cb, 0, 0);
        } else {
            int off[8], acc = 0;
            #pragma unroll
            for (int k = 0; k < 8; ++k) { off[k] = acc; acc += c8[k]; }
            if (lane == 0) g_nmeta[cn] = make_int4(st + ca, st + cb, abase, nonempty);
            // in-place scatter: all values already in registers; stable rank via ballots
            int cum[8] = {0,0,0,0,0,0,0,0};
            #pragma unroll
            for (int i = 0; i < 4; ++i) {
                int o = oc[i];
                int pdst = 0;
                #pragma unroll
                for (int k = 0; k < 8; ++k) {
                    unsigned long long b = __ballot(o == k);
                    if (o == k) pdst = ca + off[k] + cum[k] + (int)__popcll(b & mlt);
                    cum[k] += (int)__popcll(b);
                }
                if (o < 8) { a4[pdst] = pv[i]; aid[pdst] = idv[i]; }
            }
            asm volatile("s_waitcnt lgkmcnt(0)" ::: "memory");
            __builtin_amdgcn_wave_barrier();
            if (lane == 0) {
                int ci = 0;
                #pragma unroll
                for (int k = 0; k < 8; ++k) {
                    if (c8[k] > 0) {
                        lid[sp + ci] = abase + ci;
                        la [sp + ci] = ca + off[k];
                        lbb[sp + ci] = ca + off[k] + c8[k];
                        ++ci;
                    }
                }
            }
            abase += nonempty; sp += nonempty;
            if (sp > LSTK) sp = LSTK;              // safety clamp (never in practice)
        }
        if (sp <= 0) break;
        --sp;
        __builtin_amdgcn_wave_barrier();
        asm volatile("s_waitcnt lgkmcnt(0)" ::: "memory");
        cn = lid[sp]; ca = la[sp]; cb = lbb[sp];
        __builtin_amdgcn_wave_barrier();
    }

    for (int j = lane; j < cnt; j += 64) {
        g_p4[st + j]  = a4[j];
        g_perm[st + j] = aid[j];
    }
    asm volatile("s_waitcnt vmcnt(0)" ::: "memory");
}

// Global-memory wave path for rare cnt > LCAP nodes (R10-proven).
__device__ __forceinline__ int proc_big(int n, int st, int en, int abase, int* cur,
                                        int* gid, int* gst, int* gen, int sp)
{
    const int lane = threadIdx.x & 63;
    const int cnt = en - st;

    float mnx = 3.402823466e38f, mny = mnx, mnz = mnx;
    float mxx = -mnx, mxy = -mnx, mxz = -mnx;
    double sx = 0.0, sy = 0.0, sz = 0.0, sq = 0.0;
    for (int j = st + lane; j < en; j += 64) {
        float4 p = g_p4[j];
        mnx = fminf(mnx, p.x); mny = fminf(mny, p.y); mnz = fminf(mnz, p.z);
        mxx = fmaxf(mxx, p.x); mxy = fmaxf(mxy, p.y); mxz = fmaxf(mxz, p.z);
        sx += (double)p.x; sy += (double)p.y; sz += (double)p.z; sq += (double)p.w;
    }
    for (int o = 1; o < 64; o <<= 1) {
        mnx = fminf(mnx, __shfl_xor(mnx, o));
        mny = fminf(mny, __shfl_xor(mny, o));
        mnz = fminf(mnz, __shfl_xor(mnz, o));
        mxx = fmaxf(mxx, __shfl_xor(mxx, o));
        mxy = fmaxf(mxy, __shfl_xor(mxy, o));
        mxz = fmaxf(mxz, __shfl_xor(mxz, o));
        sx += __shfl_xor(sx, o);
        sy += __shfl_xor(sy, o);
        sz += __shfl_xor(sz, o);
        sq += __shfl_xor(sq, o);
    }
    const float cx = 0.5f * (mnx + mxx);
    const float cy = 0.5f * (mny + mxy);
    const float cz = 0.5f * (mnz + mxz);
    if (lane == 0) {
        g_nc4[n] = make_float4(cx, cy, cz, 0.5f * fmaxf(fmaxf(mxx - mnx, mxy - mny), mxz - mnz));
        const float fc = (float)cnt;
        g_nm4[n] = make_float4((float)sx / fc, (float)sy / fc, (float)sz / fc, (float)sq);
    }
    // cnt > LCAP > LEAF_SZ: never a size-leaf

    int c8[8] = {0,0,0,0,0,0,0,0};
    for (int j = st + lane; j < en; j += 64) {
        float4 p = g_p4[j];
        int oct = (p.x >= cx ? 1 : 0) | (p.y >= cy ? 2 : 0) | (p.z >= cz ? 4 : 0);
        c8[oct]++;
    }
    #pragma unroll
    for (int k = 0; k < 8; ++k)
        for (int o = 1; o < 64; o <<= 1)
            c8[k] += __shfl_xor(c8[k], o);
    int nonempty = 0;
    #pragma unroll
    for (int k = 0; k < 8; ++k) nonempty += (c8[k] > 0) ? 1 : 0;
    if (nonempty <= 1) {
        if (lane == 0) g_nmeta[n] = make_int4(st, en, 0, 0);
        return 0;
    }

    int off[8], acc = 0;
    #pragma unroll
    for (int k = 0; k < 8; ++k) { off[k] = acc; acc += c8[k]; }
    if (lane == 0) {
        g_nmeta[n] = make_int4(st, en, abase, nonempty);
        int ci = 0;
        #pragma unroll
        for (int k = 0; k < 8; ++k) {
            if (c8[k] > 0) {
                gid[sp + ci] = abase + ci;
                gst[sp + ci] = st + off[k];
                gen[sp + ci] = st + off[k] + c8[k];
                ++ci;
            }
        }
    }
    if (lane < 8) cur[lane] = st + off[lane];
    __builtin_amdgcn_wave_barrier();
    for (int j = st + lane; j < en; j += 64) {
        float4 p = g_p4[j];
        int id = g_perm[j];
        int oct = (p.x >= cx ? 1 : 0) | (p.y >= cy ? 2 : 0) | (p.z >= cz ? 4 : 0);
        int pdst = atomicAdd(&cur[oct], 1);
        g_ptmp[pdst] = id; g_t4[pdst] = p;
    }
    asm volatile("s_waitcnt vmcnt(0)" ::: "memory");
    __builtin_amdgcn_wave_barrier();
    for (int j = st + lane; j < en; j += 64) {
        g_perm[j] = g_ptmp[j];
        g_p4[j]   = g_t4[j];
    }
    asm volatile("s_waitcnt vmcnt(0)" ::: "memory");
    return nonempty;
}

// Static task->wave mapping; arena = [le + 2*st, le + 2*en) per task (ranges
// tile the atom array -> disjoint); zero device atomics; hang-impossible.
__global__ __launch_bounds__(256) void subtree_kernel()
{
    __shared__ float4 s_a4[4][LCAP];
    __shared__ int    s_aid[4][LCAP];
    __shared__ int    s_lid[4][LSTK], s_la[4][LSTK], s_lb[4][LSTK];
    __shared__ int    s_gid[4][GSTK], s_gst[4][GSTK], s_gen[4][GSTK];
    __shared__ int    s_cur[4][8];

    const int wid = threadIdx.x >> 6;
    const int gw  = blockIdx.x * 4 + wid;
    const int lb = g_lrange[2], le = g_lrange[3];
    const int ntasks = le - lb;

    float4* a4 = s_a4[wid];  int* aid = s_aid[wid];
    int* lid = s_lid[wid];   int* la = s_la[wid];  int* lbb = s_lb[wid];
    int* gid = s_gid[wid];   int* gst = s_gst[wid]; int* gen = s_gen[wid];
    int* cur = s_cur[wid];

    for (int task = gw; task < ntasks; task += BGRID * 4) {
        int cn  = lb + task;
        int cst = g_nstart[cn], cen = g_nend[cn];
        int abase = le + 2 * cst;
        int gsp = 0;
        while (true) {
            if (cen - cst <= LCAP) {
                lds_subtree(cn, cst, cen, abase, a4, aid, lid, la, lbb);
            } else {
                int num = proc_big(cn, cst, cen, abase, cur, gid, gst, gen, gsp);
                abase += num; gsp += num;
                if (gsp > GSTK) gsp = GSTK;        // safety clamp (never in practice)
            }
            if (gsp <= 0) break;
            --gsp;
            __builtin_amdgcn_wave_barrier();
            asm volatile("s_waitcnt lgkmcnt(0)" ::: "memory");
            cn = gid[gsp]; cst = gst[gsp]; cen = gen[gsp];
            __builtin_amdgcn_wave_barrier();
        }
    }
}

// ---------------------------------------------------------------------------
// One wave per target. Per batch: lanes classify nodes (monopole inline),
// leaf ranges prefix-summed into a flat LDS pair list, drained by all lanes.
// ---------------------------------------------------------------------------
__global__ __launch_bounds__(256)
void traverse_kernel(const int* __restrict__ batch,
                     const float* __restrict__ p_scr, const float* __restrict__ p_soft,
                     float* __restrict__ out, int N)
{
    __shared__ int s_q[4][NQ];
    __shared__ int s_pj[4][PCAP];
    __shared__ int s_qt[4];
    const int wid  = threadIdx.x >> 6;
    const int lane = threadIdx.x & 63;
    const int slot = blockIdx.x * 4 + wid;
    if (slot >= N) return;                 // wave-uniform; no __syncthreads used
    const int t = g_perm[slot];

    const float scr   = p_scr[0];
    const float soft  = p_soft[0];
    const float soft2 = soft * soft;
    const float cexp  = -scr * 1.4426950408889634f;  // exp(-scr*r) = exp2(cexp*r)
    const float4 tp = g_p4[slot];
    const float tx = tp.x, ty = tp.y, tz = tp.z;
    const int inv_t = slot;

    volatile int* q  = s_q[wid];
    volatile int* pj = s_pj[wid];
    if (lane == 0) { q[0] = g_root[batch[t]]; s_qt[wid] = 1; }
    __builtin_amdgcn_wave_barrier();

    float phi = 0.f;
    int qh = 0;
    while (true) {
        __builtin_amdgcn_wave_barrier();
        int qt = ((volatile int*)s_qt)[wid];
        if (qh >= qt) break;
        int take = qt - qh; if (take > 64) take = 64;
        int node = (lane < take) ? q[(qh + lane) & (NQ - 1)] : -1;
        qh += take;

        int leaf_st = 0, leaf_cnt = 0;
        if (node >= 0) {
            const int4 meta = g_nmeta[node];
            if (meta.w == 0) {
                leaf_st = meta.x; leaf_cnt = meta.y - meta.x;
            } else {
                float4 c4 = g_nc4[node];
                float dx = tx - c4.x, dy = ty - c4.y, dz = tz - c4.z;
                float dist = sqrtf(dx*dx + dy*dy + dz*dz + soft2);
                float diam = fmaxf(2.0f * c4.w, 1e-9f);
                bool inside = (inv_t >= meta.x) && (inv_t < meta.y);
                if (!inside && diam < 0.5f * dist) {
                    float4 m4 = g_nm4[node];
                    float ax = tx - m4.x, ay = ty - m4.y, az = tz - m4.z;
                    float s = ax*ax + ay*ay + az*az + soft2;
                    float rinv = rsqrtf(s);
                    phi += m4.w * exp2f(cexp * (s * rinv)) * rinv;
                } else {
                    int p = atomicAdd(&s_qt[wid], meta.w);
                    for (int c = 0; c < meta.w; ++c) q[(p + c) & (NQ - 1)] = meta.z + c;
                }
            }
        }

        // wave prefix-sum of (leaf size minus self) -> flat pair list
        bool hasself = (inv_t >= leaf_st) && (inv_t < leaf_st + leaf_cnt);
        int cnt_adj = leaf_cnt - (hasself ? 1 : 0);
        int x = cnt_adj;
        #pragma unroll
        for (int o = 1; o < 64; o <<= 1) { int y = __shfl_up(x, o); if (lane >= o) x += y; }
        int total = __shfl(x, 63);
        int off = x - cnt_adj;

        if (total > 0) {
            if (total <= PCAP) {
                int w = off;
                for (int k = 0; k < leaf_cnt; ++k) {
                    int j = leaf_st + k;
                    if (j != inv_t) pj[w++] = j;
                }
                __builtin_amdgcn_wave_barrier();
                for (int p = lane; p < total; p += 64) {
                    int j = pj[p];
                    float4 pp = g_p4[j];
                    float dx = tx - pp.x, dy = ty - pp.y, dz = tz - pp.z;
                    float s = dx*dx + dy*dy + dz*dz + soft2;
                    float rinv = rsqrtf(s);
                    phi += pp.w * exp2f(cexp * (s * rinv)) * rinv;
                }
                __builtin_amdgcn_wave_barrier();
            } else {
                for (int k = 0; k < leaf_cnt; ++k) {
                    int j = leaf_st + k;
                    if (j == inv_t) continue;
                    float4 pp = g_p4[j];
                    float dx = tx - pp.x, dy = ty - pp.y, dz = tz - pp.z;
                    float s = dx*dx + dy*dy + dz*dz + soft2;
                    float rinv = rsqrtf(s);
                    phi += pp.w * exp2f(cexp * (s * rinv)) * rinv;
                }
            }
        }
    }

    #pragma unroll
    for (int o = 1; o < 64; o <<= 1) phi += __shfl_xor(phi, o);
    if (lane == 0) out[t] = 0.5f * (tp.w * phi);
}

extern "C" void kernel_launch(void* const* d_in, const int* in_sizes, int n_in,
                              void* d_out, int out_size, void* d_ws, size_t ws_size,
                              hipStream_t stream) {
    const float* pos    = (const float*)d_in[0];
    const int*   batch  = (const int*)  d_in[1];
    const float* source = (const float*)d_in[3];
    const float* p_scr  = (const float*)d_in[4];
    const float* p_soft = (const float*)d_in[5];

    const int N        = in_sizes[0] / 3;
    const int n_graphs = in_sizes[2] / 9;

    init_kernel<<<(N + 255) / 256, 256, 0, stream>>>(pos, source, N);
    roots_kernel<<<1, 256, 0, stream>>>(batch, N, n_graphs);
    level_kernel<<<BGRID, 256, 0, stream>>>(0);
    level_kernel<<<BGRID, 256, 0, stream>>>(1);
    subtree_kernel<<<BGRID, 256, 0, stream>>>();

    const int blocks = (N + 3) / 4;  // 4 waves (targets) per 256-thread block
    traverse_kernel<<<blocks, 256, 0, stream>>>(batch, p_scr, p_soft, (float*)d_out, N);
}

// Round 12
// 205.771 us; speedup vs baseline: 1.8211x; 1.1845x over previous
//
#include <hip/hip_runtime.h>

#define LEAF_SZ 32
#define MAXN 16384
#define MAXNODES 65536
#define MAXG 64
#define NQ 1024
#define PCAP 1024
#define BGRID 128
#define LCAP 256
#define LSTK 192
#define GSTK 64

// Static device scratch (fully rewritten each call; no cross-call state relied on).
__device__ int    g_perm[MAXN];
__device__ int    g_ptmp[MAXN];
__device__ float4 g_p4[MAXN];    // x,y,z,charge in perm order
__device__ float4 g_t4[MAXN];
__device__ int    g_nstart[MAXNODES];
__device__ int    g_nend[MAXNODES];
__device__ int4   g_nmeta[MAXNODES];  // st, en, first_child, n_children(0=leaf)
__device__ float4 g_nc4[MAXNODES];    // bbox center + half (MAC)
__device__ float4 g_nm4[MAXNODES];    // mean center + total charge (monopole)
__device__ int    g_root[MAXG];
__device__ int    g_ncount;
__device__ int    g_lrange[8];
__device__ int    g_done[4];

struct NodeSh {
    float  mn[4][3], mx[4][3];
    double sx[4], sy[4], sz[4], sq[4];
    int    c8[4][8];
    int    cur[8];
    float  cc[3];
    int    info;
    int    base, num;
};

// Block-cooperative node processing — top levels only (R2-proven).
__device__ __forceinline__ void process_node(NodeSh& sh, int n)
{
    const int tid  = threadIdx.x;
    const int wid  = tid >> 6;
    const int lane = tid & 63;
    const int st = g_nstart[n], en = g_nend[n];
    const int cnt = en - st;

    float mnx = 3.402823466e38f, mny = mnx, mnz = mnx;
    float mxx = -mnx, mxy = -mnx, mxz = -mnx;
    double sx = 0.0, sy = 0.0, sz = 0.0, sq = 0.0;
    for (int j = st + tid; j < en; j += 256) {
        float4 p = g_p4[j];
        mnx = fminf(mnx, p.x); mny = fminf(mny, p.y); mnz = fminf(mnz, p.z);
        mxx = fmaxf(mxx, p.x); mxy = fmaxf(mxy, p.y); mxz = fmaxf(mxz, p.z);
        sx += (double)p.x; sy += (double)p.y; sz += (double)p.z; sq += (double)p.w;
    }
    for (int o = 1; o < 64; o <<= 1) {
        mnx = fminf(mnx, __shfl_xor(mnx, o));
        mny = fminf(mny, __shfl_xor(mny, o));
        mnz = fminf(mnz, __shfl_xor(mnz, o));
        mxx = fmaxf(mxx, __shfl_xor(mxx, o));
        mxy = fmaxf(mxy, __shfl_xor(mxy, o));
        mxz = fmaxf(mxz, __shfl_xor(mxz, o));
        sx += __shfl_xor(sx, o);
        sy += __shfl_xor(sy, o);
        sz += __shfl_xor(sz, o);
        sq += __shfl_xor(sq, o);
    }
    if (lane == 0) {
        sh.mn[wid][0] = mnx; sh.mn[wid][1] = mny; sh.mn[wid][2] = mnz;
        sh.mx[wid][0] = mxx; sh.mx[wid][1] = mxy; sh.mx[wid][2] = mxz;
        sh.sx[wid] = sx; sh.sy[wid] = sy; sh.sz[wid] = sz; sh.sq[wid] = sq;
    }
    __syncthreads();
    if (tid == 0) {
        float a0 = sh.mn[0][0], a1 = sh.mn[0][1], a2 = sh.mn[0][2];
        float b0 = sh.mx[0][0], b1 = sh.mx[0][1], b2 = sh.mx[0][2];
        double tx = sh.sx[0], ty = sh.sy[0], tz = sh.sz[0], tq = sh.sq[0];
        for (int w = 1; w < 4; ++w) {
            a0 = fminf(a0, sh.mn[w][0]); a1 = fminf(a1, sh.mn[w][1]); a2 = fminf(a2, sh.mn[w][2]);
            b0 = fmaxf(b0, sh.mx[w][0]); b1 = fmaxf(b1, sh.mx[w][1]); b2 = fmaxf(b2, sh.mx[w][2]);
            tx += sh.sx[w]; ty += sh.sy[w]; tz += sh.sz[w]; tq += sh.sq[w];
        }
        float cx = 0.5f * (a0 + b0), cy = 0.5f * (a1 + b1), cz = 0.5f * (a2 + b2);
        g_nc4[n] = make_float4(cx, cy, cz, 0.5f * fmaxf(fmaxf(b0 - a0, b1 - a1), b2 - a2));
        const float fc = (float)cnt;
        g_nm4[n] = make_float4((float)tx / fc, (float)ty / fc, (float)tz / fc, (float)tq);
        sh.cc[0] = cx; sh.cc[1] = cy; sh.cc[2] = cz;
        if (cnt <= LEAF_SZ) { g_nmeta[n] = make_int4(st, en, 0, 0); sh.info = -1; }
        else sh.info = 0;
    }
    __syncthreads();
    if (sh.info < 0) return;
    const float cx = sh.cc[0], cy = sh.cc[1], cz = sh.cc[2];

    int c8[8] = {0,0,0,0,0,0,0,0};
    for (int j = st + tid; j < en; j += 256) {
        float4 p = g_p4[j];
        int oct = (p.x >= cx ? 1 : 0) | (p.y >= cy ? 2 : 0) | (p.z >= cz ? 4 : 0);
        c8[oct]++;
    }
    #pragma unroll
    for (int k = 0; k < 8; ++k)
        for (int o = 1; o < 64; o <<= 1)
            c8[k] += __shfl_xor(c8[k], o);
    if (lane == 0)
        #pragma unroll
        for (int k = 0; k < 8; ++k) sh.c8[wid][k] = c8[k];
    __syncthreads();
    if (tid == 0) {
        int tot[8], nonempty = 0;
        #pragma unroll
        for (int k = 0; k < 8; ++k) {
            tot[k] = sh.c8[0][k] + sh.c8[1][k] + sh.c8[2][k] + sh.c8[3][k];
            nonempty += (tot[k] > 0) ? 1 : 0;
        }
        if (nonempty <= 1) { g_nmeta[n] = make_int4(st, en, 0, 0); sh.info = -1; }
        else {
            int base = atomicAdd(&g_ncount, nonempty);
            int acc = st, ci = base;
            #pragma unroll
            for (int k = 0; k < 8; ++k) {
                sh.cur[k] = acc;
                if (tot[k] > 0) { g_nstart[ci] = acc; g_nend[ci] = acc + tot[k]; ++ci; }
                acc += tot[k];
            }
            g_nmeta[n] = make_int4(st, en, base, nonempty);
            sh.base = base; sh.num = nonempty; sh.info = 1;
        }
    }
    __syncthreads();
    if (sh.info < 0) return;

    for (int j = st + tid; j < en; j += 256) {
        float4 p = g_p4[j];
        int id = g_perm[j];
        int oct = (p.x >= cx ? 1 : 0) | (p.y >= cy ? 2 : 0) | (p.z >= cz ? 4 : 0);
        int pdst = atomicAdd(&sh.cur[oct], 1);
        g_ptmp[pdst] = id; g_t4[pdst] = p;
    }
    __syncthreads();
    for (int j = st + tid; j < en; j += 256) {
        g_perm[j] = g_ptmp[j];
        g_p4[j]   = g_t4[j];
    }
    __syncthreads();
}

__global__ void init_kernel(const float* __restrict__ pos, const float* __restrict__ src, int N)
{
    int i = blockIdx.x * blockDim.x + threadIdx.x;
    if (i < N) {
        g_perm[i] = i;
        g_p4[i] = make_float4(pos[3*i], pos[3*i+1], pos[3*i+2], src[i]);
    }
}

__global__ __launch_bounds__(256) void roots_kernel(const int* __restrict__ batch, int N, int n_graphs)
{
    __shared__ int s_first[MAXG], s_end[MAXG];
    const int tid = threadIdx.x;
    for (int g = tid; g < MAXG; g += 256) { s_first[g] = -1; s_end[g] = 0; }
    __syncthreads();
    for (int i = tid; i < N; i += 256) {
        int b = batch[i];
        if (i == 0     || batch[i-1] != b) s_first[b] = i;
        if (i == N - 1 || batch[i+1] != b) s_end[b]   = i + 1;
    }
    __syncthreads();
    if (tid == 0) {
        int nc = 0;
        for (int g = 0; g < n_graphs && g < MAXG; ++g) {
            if (s_first[g] >= 0) {
                g_root[g] = nc;
                g_nstart[nc] = s_first[g];
                g_nend[nc]   = s_end[g];
                ++nc;
            } else g_root[g] = -1;
        }
        g_ncount = nc;
        g_lrange[0] = 0; g_lrange[1] = nc;
        g_done[0] = g_done[1] = g_done[2] = g_done[3] = 0;
    }
}

// One launch per level (4 levels): kernel boundary = free device-wide barrier.
__global__ __launch_bounds__(256) void level_kernel(int lev)
{
    __shared__ NodeSh sh;
    const int lb = g_lrange[lev], le = g_lrange[lev + 1];
    for (int n = lb + blockIdx.x; n < le; n += BGRID) {
        __syncthreads();
        process_node(sh, n);
    }
    __syncthreads();
    if (threadIdx.x == 0) {
        __threadfence();
        int d = atomicAdd(&g_done[lev], 1);
        if (d == BGRID - 1)
            g_lrange[lev + 2] = atomicAdd(&g_ncount, 0);
    }
}

// ---------------------------------------------------------------------------
// LDS-resident subtree DFS (cnt <= LCAP): load segment once, whole DFS out of
// LDS/registers, in-place ballot-rank scatter (DS pipe is in-order per wave),
// fire-and-forget node-output stores, one write-back at the end.
// ---------------------------------------------------------------------------
__device__ __forceinline__ void lds_subtree(int rootn, int st, int en, int& abase,
                                            float4* a4, int* aid,
                                            int* lid, int* la, int* lbb)
{
    const int lane = threadIdx.x & 63;
    const int cnt = en - st;
    const unsigned long long mlt = (1ull << lane) - 1ull;

    for (int j = lane; j < cnt; j += 64) {
        a4[j]  = g_p4[st + j];
        aid[j] = g_perm[st + j];
    }
    asm volatile("s_waitcnt vmcnt(0) lgkmcnt(0)" ::: "memory");
    __builtin_amdgcn_wave_barrier();

    int sp = 0;
    int cn = rootn, ca = 0, cb = cnt;
    while (true) {
        const int c = cb - ca;
        float4 pv[4]; int idv[4]; int oc[4];
        float mnx = 3.402823466e38f, mny = mnx, mnz = mnx;
        float mxx = -mnx, mxy = -mnx, mxz = -mnx;
        float sx = 0.f, sy = 0.f, sz = 0.f, sq = 0.f;
        #pragma unroll
        for (int i = 0; i < 4; ++i) {
            bool act = (i*64 + lane) < c;
            int j = act ? (ca + i*64 + lane) : ca;   // clamped addr: always in-bounds
            float4 p = a4[j];
            pv[i] = p; idv[i] = aid[j];
            if (act) {
                mnx = fminf(mnx, p.x); mny = fminf(mny, p.y); mnz = fminf(mnz, p.z);
                mxx = fmaxf(mxx, p.x); mxy = fmaxf(mxy, p.y); mxz = fmaxf(mxz, p.z);
                sx += p.x; sy += p.y; sz += p.z; sq += p.w;
            }
        }
        for (int o = 1; o < 64; o <<= 1) {
            mnx = fminf(mnx, __shfl_xor(mnx, o));
            mny = fminf(mny, __shfl_xor(mny, o));
            mnz = fminf(mnz, __shfl_xor(mnz, o));
            mxx = fmaxf(mxx, __shfl_xor(mxx, o));
            mxy = fmaxf(mxy, __shfl_xor(mxy, o));
            mxz = fmaxf(mxz, __shfl_xor(mxz, o));
            sx += __shfl_xor(sx, o);
            sy += __shfl_xor(sy, o);
            sz += __shfl_xor(sz, o);
            sq += __shfl_xor(sq, o);
        }
        const float cx = 0.5f * (mnx + mxx);
        const float cy = 0.5f * (mny + mxy);
        const float cz = 0.5f * (mnz + mxz);
        if (lane == 0) {
            g_nc4[cn] = make_float4(cx, cy, cz, 0.5f * fmaxf(fmaxf(mxx - mnx, mxy - mny), mxz - mnz));
            const float fc = (float)c;
            g_nm4[cn] = make_float4(sx / fc, sy / fc, sz / fc, sq);
        }

        int nonempty = 0;
        int c8[8] = {0,0,0,0,0,0,0,0};
        if (c > LEAF_SZ) {
            #pragma unroll
            for (int i = 0; i < 4; ++i) {
                bool act = (i*64 + lane) < c;
                int o = act ? ((pv[i].x >= cx ? 1 : 0) | (pv[i].y >= cy ? 2 : 0) | (pv[i].z >= cz ? 4 : 0)) : 8;
                oc[i] = o;
                #pragma unroll
                for (int k = 0; k < 8; ++k)
                    c8[k] += (int)__popcll(__ballot(o == k));
            }
            #pragma unroll
            for (int k = 0; k < 8; ++k) nonempty += (c8[k] > 0) ? 1 : 0;
        }

        if (c <= LEAF_SZ || nonempty <= 1) {
            if (lane == 0) g_nmeta[cn] = make_int4(st + ca, st + cb, 0, 0);
        } else {
            int off[8], acc = 0;
            #pragma unroll
            for (int k = 0; k < 8; ++k) { off[k] = acc; acc += c8[k]; }
            if (lane == 0) g_nmeta[cn] = make_int4(st + ca, st + cb, abase, nonempty);
            // in-place scatter: all values already in registers; stable rank via ballots
            int cum[8] = {0,0,0,0,0,0,0,0};
            #pragma unroll
            for (int i = 0; i < 4; ++i) {
                int o = oc[i];
                int pdst = 0;
                #pragma unroll
                for (int k = 0; k < 8; ++k) {
                    unsigned long long b = __ballot(o == k);
                    if (o == k) pdst = ca + off[k] + cum[k] + (int)__popcll(b & mlt);
                    cum[k] += (int)__popcll(b);
                }
                if (o < 8) { a4[pdst] = pv[i]; aid[pdst] = idv[i]; }
            }
            asm volatile("s_waitcnt lgkmcnt(0)" ::: "memory");
            __builtin_amdgcn_wave_barrier();
            if (lane == 0) {
                int ci = 0;
                #pragma unroll
                for (int k = 0; k < 8; ++k) {
                    if (c8[k] > 0) {
                        lid[sp + ci] = abase + ci;
                        la [sp + ci] = ca + off[k];
                        lbb[sp + ci] = ca + off[k] + c8[k];
                        ++ci;
                    }
                }
            }
            abase += nonempty; sp += nonempty;
            if (sp > LSTK) sp = LSTK;              // safety clamp (never in practice)
        }
        if (sp <= 0) break;
        --sp;
        __builtin_amdgcn_wave_barrier();
        asm volatile("s_waitcnt lgkmcnt(0)" ::: "memory");
        cn = lid[sp]; ca = la[sp]; cb = lbb[sp];
        __builtin_amdgcn_wave_barrier();
    }

    for (int j = lane; j < cnt; j += 64) {
        g_p4[st + j]  = a4[j];
        g_perm[st + j] = aid[j];
    }
    asm volatile("s_waitcnt vmcnt(0)" ::: "memory");
}

// Global-memory wave path for rare cnt > LCAP nodes (R10-proven).
__device__ __forceinline__ int proc_big(int n, int st, int en, int abase, int* cur,
                                        int* gid, int* gst, int* gen, int sp)
{
    const int lane = threadIdx.x & 63;
    const int cnt = en - st;

    float mnx = 3.402823466e38f, mny = mnx, mnz = mnx;
    float mxx = -mnx, mxy = -mnx, mxz = -mnx;
    double sx = 0.0, sy = 0.0, sz = 0.0, sq = 0.0;
    for (int j = st + lane; j < en; j += 64) {
        float4 p = g_p4[j];
        mnx = fminf(mnx, p.x); mny = fminf(mny, p.y); mnz = fminf(mnz, p.z);
        mxx = fmaxf(mxx, p.x); mxy = fmaxf(mxy, p.y); mxz = fmaxf(mxz, p.z);
        sx += (double)p.x; sy += (double)p.y; sz += (double)p.z; sq += (double)p.w;
    }
    for (int o = 1; o < 64; o <<= 1) {
        mnx = fminf(mnx, __shfl_xor(mnx, o));
        mny = fminf(mny, __shfl_xor(mny, o));
        mnz = fminf(mnz, __shfl_xor(mnz, o));
        mxx = fmaxf(mxx, __shfl_xor(mxx, o));
        mxy = fmaxf(mxy, __shfl_xor(mxy, o));
        mxz = fmaxf(mxz, __shfl_xor(mxz, o));
        sx += __shfl_xor(sx, o);
        sy += __shfl_xor(sy, o);
        sz += __shfl_xor(sz, o);
        sq += __shfl_xor(sq, o);
    }
    const float cx = 0.5f * (mnx + mxx);
    const float cy = 0.5f * (mny + mxy);
    const float cz = 0.5f * (mnz + mxz);
    if (lane == 0) {
        g_nc4[n] = make_float4(cx, cy, cz, 0.5f * fmaxf(fmaxf(mxx - mnx, mxy - mny), mxz - mnz));
        const float fc = (float)cnt;
        g_nm4[n] = make_float4((float)sx / fc, (float)sy / fc, (float)sz / fc, (float)sq);
    }
    // cnt > LCAP > LEAF_SZ: never a size-leaf

    int c8[8] = {0,0,0,0,0,0,0,0};
    for (int j = st + lane; j < en; j += 64) {
        float4 p = g_p4[j];
        int oct = (p.x >= cx ? 1 : 0) | (p.y >= cy ? 2 : 0) | (p.z >= cz ? 4 : 0);
        c8[oct]++;
    }
    #pragma unroll
    for (int k = 0; k < 8; ++k)
        for (int o = 1; o < 64; o <<= 1)
            c8[k] += __shfl_xor(c8[k], o);
    int nonempty = 0;
    #pragma unroll
    for (int k = 0; k < 8; ++k) nonempty += (c8[k] > 0) ? 1 : 0;
    if (nonempty <= 1) {
        if (lane == 0) g_nmeta[n] = make_int4(st, en, 0, 0);
        return 0;
    }

    int off[8], acc = 0;
    #pragma unroll
    for (int k = 0; k < 8; ++k) { off[k] = acc; acc += c8[k]; }
    if (lane == 0) {
        g_nmeta[n] = make_int4(st, en, abase, nonempty);
        int ci = 0;
        #pragma unroll
        for (int k = 0; k < 8; ++k) {
            if (c8[k] > 0) {
                gid[sp + ci] = abase + ci;
                gst[sp + ci] = st + off[k];
                gen[sp + ci] = st + off[k] + c8[k];
                ++ci;
            }
        }
    }
    if (lane < 8) cur[lane] = st + off[lane];
    __builtin_amdgcn_wave_barrier();
    for (int j = st + lane; j < en; j += 64) {
        float4 p = g_p4[j];
        int id = g_perm[j];
        int oct = (p.x >= cx ? 1 : 0) | (p.y >= cy ? 2 : 0) | (p.z >= cz ? 4 : 0);
        int pdst = atomicAdd(&cur[oct], 1);
        g_ptmp[pdst] = id; g_t4[pdst] = p;
    }
    asm volatile("s_waitcnt vmcnt(0)" ::: "memory");
    __builtin_amdgcn_wave_barrier();
    for (int j = st + lane; j < en; j += 64) {
        g_perm[j] = g_ptmp[j];
        g_p4[j]   = g_t4[j];
    }
    asm volatile("s_waitcnt vmcnt(0)" ::: "memory");
    return nonempty;
}

// Static task->wave mapping; arena = [le + 2*st, le + 2*en) per task (ranges
// tile the atom array -> disjoint); zero device atomics; hang-impossible.
__global__ __launch_bounds__(256) void subtree_kernel()
{
    __shared__ float4 s_a4[4][LCAP];
    __shared__ int    s_aid[4][LCAP];
    __shared__ int    s_lid[4][LSTK], s_la[4][LSTK], s_lb[4][LSTK];
    __shared__ int    s_gid[4][GSTK], s_gst[4][GSTK], s_gen[4][GSTK];
    __shared__ int    s_cur[4][8];

    const int wid = threadIdx.x >> 6;
    const int gw  = blockIdx.x * 4 + wid;
    const int lb = g_lrange[4], le = g_lrange[5];   // frontier after 4 levels
    const int ntasks = le - lb;

    float4* a4 = s_a4[wid];  int* aid = s_aid[wid];
    int* lid = s_lid[wid];   int* la = s_la[wid];  int* lbb = s_lb[wid];
    int* gid = s_gid[wid];   int* gst = s_gst[wid]; int* gen = s_gen[wid];
    int* cur = s_cur[wid];

    for (int task = gw; task < ntasks; task += BGRID * 4) {
        int cn  = lb + task;
        int cst = g_nstart[cn], cen = g_nend[cn];
        int abase = le + 2 * cst;
        int gsp = 0;
        while (true) {
            if (cen - cst <= LCAP) {
                lds_subtree(cn, cst, cen, abase, a4, aid, lid, la, lbb);
            } else {
                int num = proc_big(cn, cst, cen, abase, cur, gid, gst, gen, gsp);
                abase += num; gsp += num;
                if (gsp > GSTK) gsp = GSTK;        // safety clamp (never in practice)
            }
            if (gsp <= 0) break;
            --gsp;
            __builtin_amdgcn_wave_barrier();
            asm volatile("s_waitcnt lgkmcnt(0)" ::: "memory");
            cn = gid[gsp]; cst = gst[gsp]; cen = gen[gsp];
            __builtin_amdgcn_wave_barrier();
        }
    }
}

// ---------------------------------------------------------------------------
// One wave per target. Per batch: lanes classify nodes (monopole inline),
// leaf ranges prefix-summed into a flat LDS pair list, drained by all lanes.
// ---------------------------------------------------------------------------
__global__ __launch_bounds__(256)
void traverse_kernel(const int* __restrict__ batch,
                     const float* __restrict__ p_scr, const float* __restrict__ p_soft,
                     float* __restrict__ out, int N)
{
    __shared__ int s_q[4][NQ];
    __shared__ int s_pj[4][PCAP];
    __shared__ int s_qt[4];
    const int wid  = threadIdx.x >> 6;
    const int lane = threadIdx.x & 63;
    const int slot = blockIdx.x * 4 + wid;
    if (slot >= N) return;                 // wave-uniform; no __syncthreads used
    const int t = g_perm[slot];

    const float scr   = p_scr[0];
    const float soft  = p_soft[0];
    const float soft2 = soft * soft;
    const float cexp  = -scr * 1.4426950408889634f;  // exp(-scr*r) = exp2(cexp*r)
    const float4 tp = g_p4[slot];
    const float tx = tp.x, ty = tp.y, tz = tp.z;
    const int inv_t = slot;

    volatile int* q  = s_q[wid];
    volatile int* pj = s_pj[wid];
    if (lane == 0) { q[0] = g_root[batch[t]]; s_qt[wid] = 1; }
    __builtin_amdgcn_wave_barrier();

    float phi = 0.f;
    int qh = 0;
    while (true) {
        __builtin_amdgcn_wave_barrier();
        int qt = ((volatile int*)s_qt)[wid];
        if (qh >= qt) break;
        int take = qt - qh; if (take > 64) take = 64;
        int node = (lane < take) ? q[(qh + lane) & (NQ - 1)] : -1;
        qh += take;

        int leaf_st = 0, leaf_cnt = 0;
        if (node >= 0) {
            const int4 meta = g_nmeta[node];
            if (meta.w == 0) {
                leaf_st = meta.x; leaf_cnt = meta.y - meta.x;
            } else {
                float4 c4 = g_nc4[node];
                float dx = tx - c4.x, dy = ty - c4.y, dz = tz - c4.z;
                float dist = sqrtf(dx*dx + dy*dy + dz*dz + soft2);
                float diam = fmaxf(2.0f * c4.w, 1e-9f);
                bool inside = (inv_t >= meta.x) && (inv_t < meta.y);
                if (!inside && diam < 0.5f * dist) {
                    float4 m4 = g_nm4[node];
                    float ax = tx - m4.x, ay = ty - m4.y, az = tz - m4.z;
                    float s = ax*ax + ay*ay + az*az + soft2;
                    float rinv = rsqrtf(s);
                    phi += m4.w * exp2f(cexp * (s * rinv)) * rinv;
                } else {
                    int p = atomicAdd(&s_qt[wid], meta.w);
                    for (int c = 0; c < meta.w; ++c) q[(p + c) & (NQ - 1)] = meta.z + c;
                }
            }
        }

        // wave prefix-sum of (leaf size minus self) -> flat pair list
        bool hasself = (inv_t >= leaf_st) && (inv_t < leaf_st + leaf_cnt);
        int cnt_adj = leaf_cnt - (hasself ? 1 : 0);
        int x = cnt_adj;
        #pragma unroll
        for (int o = 1; o < 64; o <<= 1) { int y = __shfl_up(x, o); if (lane >= o) x += y; }
        int total = __shfl(x, 63);
        int off = x - cnt_adj;

        if (total > 0) {
            if (total <= PCAP) {
                int w = off;
                for (int k = 0; k < leaf_cnt; ++k) {
                    int j = leaf_st + k;
                    if (j != inv_t) pj[w++] = j;
                }
                __builtin_amdgcn_wave_barrier();
                for (int p = lane; p < total; p += 64) {
                    int j = pj[p];
                    float4 pp = g_p4[j];
                    float dx = tx - pp.x, dy = ty - pp.y, dz = tz - pp.z;
                    float s = dx*dx + dy*dy + dz*dz + soft2;
                    float rinv = rsqrtf(s);
                    phi += pp.w * exp2f(cexp * (s * rinv)) * rinv;
                }
                __builtin_amdgcn_wave_barrier();
            } else {
                for (int k = 0; k < leaf_cnt; ++k) {
                    int j = leaf_st + k;
                    if (j == inv_t) continue;
                    float4 pp = g_p4[j];
                    float dx = tx - pp.x, dy = ty - pp.y, dz = tz - pp.z;
                    float s = dx*dx + dy*dy + dz*dz + soft2;
                    float rinv = rsqrtf(s);
                    phi += pp.w * exp2f(cexp * (s * rinv)) * rinv;
                }
            }
        }
    }

    #pragma unroll
    for (int o = 1; o < 64; o <<= 1) phi += __shfl_xor(phi, o);
    if (lane == 0) out[t] = 0.5f * (tp.w * phi);
}

extern "C" void kernel_launch(void* const* d_in, const int* in_sizes, int n_in,
                              void* d_out, int out_size, void* d_ws, size_t ws_size,
                              hipStream_t stream) {
    const float* pos    = (const float*)d_in[0];
    const int*   batch  = (const int*)  d_in[1];
    const float* source = (const float*)d_in[3];
    const float* p_scr  = (const float*)d_in[4];
    const float* p_soft = (const float*)d_in[5];

    const int N        = in_sizes[0] / 3;
    const int n_graphs = in_sizes[2] / 9;

    init_kernel<<<(N + 255) / 256, 256, 0, stream>>>(pos, source, N);
    roots_kernel<<<1, 256, 0, stream>>>(batch, N, n_graphs);
    level_kernel<<<BGRID, 256, 0, stream>>>(0);
    level_kernel<<<BGRID, 256, 0, stream>>>(1);
    level_kernel<<<BGRID, 256, 0, stream>>>(2);
    level_kernel<<<BGRID, 256, 0, stream>>>(3);
    subtree_kernel<<<BGRID, 256, 0, stream>>>();

    const int blocks = (N + 3) / 4;  // 4 waves (targets) per 256-thread block
    traverse_kernel<<<blocks, 256, 0, stream>>>(batch, p_scr, p_soft, (float*)d_out, N);
}

// Round 13
// 192.854 us; speedup vs baseline: 1.9431x; 1.0670x over previous
//
#include <hip/hip_runtime.h>

#define LEAF_SZ 32
#define MAXN 16384
#define MAXNODES 65536
#define MAXG 64
#define NQ 1024
#define PCAP 224
#define BGRID 128
#define LCAP 256
#define LSTK 192
#define GSTK 64

// Static device scratch (fully rewritten each call; no cross-call state relied on).
__device__ int    g_perm[MAXN];
__device__ int    g_ptmp[MAXN];
__device__ float4 g_p4[MAXN];    // x,y,z,charge in perm order
__device__ float4 g_t4[MAXN];
__device__ int    g_nstart[MAXNODES];
__device__ int    g_nend[MAXNODES];
__device__ int4   g_nmeta[MAXNODES];  // st, en, first_child, n_children(0=leaf)
__device__ float4 g_nc4[MAXNODES];    // bbox center + half (MAC)
__device__ float4 g_nm4[MAXNODES];    // mean center + total charge (monopole)
__device__ int    g_root[MAXG];
__device__ int    g_ncount;
__device__ int    g_lrange[8];
__device__ int    g_done[4];

struct NodeSh {
    float  mn[4][3], mx[4][3];
    double sx[4], sy[4], sz[4], sq[4];
    int    c8[4][8];
    int    cur[8];
    float  cc[3];
    int    info;
    int    base, num;
};

// Block-cooperative node processing — top levels only (R2-proven).
__device__ __forceinline__ void process_node(NodeSh& sh, int n)
{
    const int tid  = threadIdx.x;
    const int wid  = tid >> 6;
    const int lane = tid & 63;
    const int st = g_nstart[n], en = g_nend[n];
    const int cnt = en - st;

    float mnx = 3.402823466e38f, mny = mnx, mnz = mnx;
    float mxx = -mnx, mxy = -mnx, mxz = -mnx;
    double sx = 0.0, sy = 0.0, sz = 0.0, sq = 0.0;
    for (int j = st + tid; j < en; j += 256) {
        float4 p = g_p4[j];
        mnx = fminf(mnx, p.x); mny = fminf(mny, p.y); mnz = fminf(mnz, p.z);
        mxx = fmaxf(mxx, p.x); mxy = fmaxf(mxy, p.y); mxz = fmaxf(mxz, p.z);
        sx += (double)p.x; sy += (double)p.y; sz += (double)p.z; sq += (double)p.w;
    }
    for (int o = 1; o < 64; o <<= 1) {
        mnx = fminf(mnx, __shfl_xor(mnx, o));
        mny = fminf(mny, __shfl_xor(mny, o));
        mnz = fminf(mnz, __shfl_xor(mnz, o));
        mxx = fmaxf(mxx, __shfl_xor(mxx, o));
        mxy = fmaxf(mxy, __shfl_xor(mxy, o));
        mxz = fmaxf(mxz, __shfl_xor(mxz, o));
        sx += __shfl_xor(sx, o);
        sy += __shfl_xor(sy, o);
        sz += __shfl_xor(sz, o);
        sq += __shfl_xor(sq, o);
    }
    if (lane == 0) {
        sh.mn[wid][0] = mnx; sh.mn[wid][1] = mny; sh.mn[wid][2] = mnz;
        sh.mx[wid][0] = mxx; sh.mx[wid][1] = mxy; sh.mx[wid][2] = mxz;
        sh.sx[wid] = sx; sh.sy[wid] = sy; sh.sz[wid] = sz; sh.sq[wid] = sq;
    }
    __syncthreads();
    if (tid == 0) {
        float a0 = sh.mn[0][0], a1 = sh.mn[0][1], a2 = sh.mn[0][2];
        float b0 = sh.mx[0][0], b1 = sh.mx[0][1], b2 = sh.mx[0][2];
        double tx = sh.sx[0], ty = sh.sy[0], tz = sh.sz[0], tq = sh.sq[0];
        for (int w = 1; w < 4; ++w) {
            a0 = fminf(a0, sh.mn[w][0]); a1 = fminf(a1, sh.mn[w][1]); a2 = fminf(a2, sh.mn[w][2]);
            b0 = fmaxf(b0, sh.mx[w][0]); b1 = fmaxf(b1, sh.mx[w][1]); b2 = fmaxf(b2, sh.mx[w][2]);
            tx += sh.sx[w]; ty += sh.sy[w]; tz += sh.sz[w]; tq += sh.sq[w];
        }
        float cx = 0.5f * (a0 + b0), cy = 0.5f * (a1 + b1), cz = 0.5f * (a2 + b2);
        g_nc4[n] = make_float4(cx, cy, cz, 0.5f * fmaxf(fmaxf(b0 - a0, b1 - a1), b2 - a2));
        const float fc = (float)cnt;
        g_nm4[n] = make_float4((float)tx / fc, (float)ty / fc, (float)tz / fc, (float)tq);
        sh.cc[0] = cx; sh.cc[1] = cy; sh.cc[2] = cz;
        if (cnt <= LEAF_SZ) { g_nmeta[n] = make_int4(st, en, 0, 0); sh.info = -1; }
        else sh.info = 0;
    }
    __syncthreads();
    if (sh.info < 0) return;
    const float cx = sh.cc[0], cy = sh.cc[1], cz = sh.cc[2];

    int c8[8] = {0,0,0,0,0,0,0,0};
    for (int j = st + tid; j < en; j += 256) {
        float4 p = g_p4[j];
        int oct = (p.x >= cx ? 1 : 0) | (p.y >= cy ? 2 : 0) | (p.z >= cz ? 4 : 0);
        c8[oct]++;
    }
    #pragma unroll
    for (int k = 0; k < 8; ++k)
        for (int o = 1; o < 64; o <<= 1)
            c8[k] += __shfl_xor(c8[k], o);
    if (lane == 0)
        #pragma unroll
        for (int k = 0; k < 8; ++k) sh.c8[wid][k] = c8[k];
    __syncthreads();
    if (tid == 0) {
        int tot[8], nonempty = 0;
        #pragma unroll
        for (int k = 0; k < 8; ++k) {
            tot[k] = sh.c8[0][k] + sh.c8[1][k] + sh.c8[2][k] + sh.c8[3][k];
            nonempty += (tot[k] > 0) ? 1 : 0;
        }
        if (nonempty <= 1) { g_nmeta[n] = make_int4(st, en, 0, 0); sh.info = -1; }
        else {
            int base = atomicAdd(&g_ncount, nonempty);
            int acc = st, ci = base;
            #pragma unroll
            for (int k = 0; k < 8; ++k) {
                sh.cur[k] = acc;
                if (tot[k] > 0) { g_nstart[ci] = acc; g_nend[ci] = acc + tot[k]; ++ci; }
                acc += tot[k];
            }
            g_nmeta[n] = make_int4(st, en, base, nonempty);
            sh.base = base; sh.num = nonempty; sh.info = 1;
        }
    }
    __syncthreads();
    if (sh.info < 0) return;

    for (int j = st + tid; j < en; j += 256) {
        float4 p = g_p4[j];
        int id = g_perm[j];
        int oct = (p.x >= cx ? 1 : 0) | (p.y >= cy ? 2 : 0) | (p.z >= cz ? 4 : 0);
        int pdst = atomicAdd(&sh.cur[oct], 1);
        g_ptmp[pdst] = id; g_t4[pdst] = p;
    }
    __syncthreads();
    for (int j = st + tid; j < en; j += 256) {
        g_perm[j] = g_ptmp[j];
        g_p4[j]   = g_t4[j];
    }
    __syncthreads();
}

// Merged init (all blocks) + roots scan (block 0 only; independent work).
__global__ __launch_bounds__(256)
void initroots_kernel(const float* __restrict__ pos, const float* __restrict__ src,
                      const int* __restrict__ batch, int N, int n_graphs)
{
    __shared__ int s_first[MAXG], s_end[MAXG];
    const int tid = threadIdx.x;
    int i = blockIdx.x * 256 + tid;
    if (i < N) {
        g_perm[i] = i;
        g_p4[i] = make_float4(pos[3*i], pos[3*i+1], pos[3*i+2], src[i]);
    }
    if (blockIdx.x != 0) return;

    for (int g = tid; g < MAXG; g += 256) { s_first[g] = -1; s_end[g] = 0; }
    __syncthreads();
    for (int j = tid; j < N; j += 256) {
        int b = batch[j];
        if (j == 0     || batch[j-1] != b) s_first[b] = j;
        if (j == N - 1 || batch[j+1] != b) s_end[b]   = j + 1;
    }
    __syncthreads();
    if (tid == 0) {
        int nc = 0;
        for (int g = 0; g < n_graphs && g < MAXG; ++g) {
            if (s_first[g] >= 0) {
                g_root[g] = nc;
                g_nstart[nc] = s_first[g];
                g_nend[nc]   = s_end[g];
                ++nc;
            } else g_root[g] = -1;
        }
        g_ncount = nc;
        g_lrange[0] = 0; g_lrange[1] = nc;
        g_done[0] = g_done[1] = g_done[2] = g_done[3] = 0;
    }
}

// One launch per level (4 levels): kernel boundary = free device-wide barrier.
__global__ __launch_bounds__(256) void level_kernel(int lev)
{
    __shared__ NodeSh sh;
    const int lb = g_lrange[lev], le = g_lrange[lev + 1];
    for (int n = lb + blockIdx.x; n < le; n += BGRID) {
        __syncthreads();
        process_node(sh, n);
    }
    __syncthreads();
    if (threadIdx.x == 0) {
        __threadfence();
        int d = atomicAdd(&g_done[lev], 1);
        if (d == BGRID - 1)
            g_lrange[lev + 2] = atomicAdd(&g_ncount, 0);
    }
}

// ---------------------------------------------------------------------------
// LDS-resident subtree DFS (cnt <= LCAP) — R11-proven.
// ---------------------------------------------------------------------------
__device__ __forceinline__ void lds_subtree(int rootn, int st, int en, int& abase,
                                            float4* a4, int* aid,
                                            int* lid, int* la, int* lbb)
{
    const int lane = threadIdx.x & 63;
    const int cnt = en - st;
    const unsigned long long mlt = (1ull << lane) - 1ull;

    for (int j = lane; j < cnt; j += 64) {
        a4[j]  = g_p4[st + j];
        aid[j] = g_perm[st + j];
    }
    asm volatile("s_waitcnt vmcnt(0) lgkmcnt(0)" ::: "memory");
    __builtin_amdgcn_wave_barrier();

    int sp = 0;
    int cn = rootn, ca = 0, cb = cnt;
    while (true) {
        const int c = cb - ca;
        float4 pv[4]; int idv[4]; int oc[4];
        float mnx = 3.402823466e38f, mny = mnx, mnz = mnx;
        float mxx = -mnx, mxy = -mnx, mxz = -mnx;
        float sx = 0.f, sy = 0.f, sz = 0.f, sq = 0.f;
        #pragma unroll
        for (int i = 0; i < 4; ++i) {
            bool act = (i*64 + lane) < c;
            int j = act ? (ca + i*64 + lane) : ca;
            float4 p = a4[j];
            pv[i] = p; idv[i] = aid[j];
            if (act) {
                mnx = fminf(mnx, p.x); mny = fminf(mny, p.y); mnz = fminf(mnz, p.z);
                mxx = fmaxf(mxx, p.x); mxy = fmaxf(mxy, p.y); mxz = fmaxf(mxz, p.z);
                sx += p.x; sy += p.y; sz += p.z; sq += p.w;
            }
        }
        for (int o = 1; o < 64; o <<= 1) {
            mnx = fminf(mnx, __shfl_xor(mnx, o));
            mny = fminf(mny, __shfl_xor(mny, o));
            mnz = fminf(mnz, __shfl_xor(mnz, o));
            mxx = fmaxf(mxx, __shfl_xor(mxx, o));
            mxy = fmaxf(mxy, __shfl_xor(mxy, o));
            mxz = fmaxf(mxz, __shfl_xor(mxz, o));
            sx += __shfl_xor(sx, o);
            sy += __shfl_xor(sy, o);
            sz += __shfl_xor(sz, o);
            sq += __shfl_xor(sq, o);
        }
        const float cx = 0.5f * (mnx + mxx);
        const float cy = 0.5f * (mny + mxy);
        const float cz = 0.5f * (mnz + mxz);
        if (lane == 0) {
            g_nc4[cn] = make_float4(cx, cy, cz, 0.5f * fmaxf(fmaxf(mxx - mnx, mxy - mny), mxz - mnz));
            const float fc = (float)c;
            g_nm4[cn] = make_float4(sx / fc, sy / fc, sz / fc, sq);
        }

        int nonempty = 0;
        int c8[8] = {0,0,0,0,0,0,0,0};
        if (c > LEAF_SZ) {
            #pragma unroll
            for (int i = 0; i < 4; ++i) {
                bool act = (i*64 + lane) < c;
                int o = act ? ((pv[i].x >= cx ? 1 : 0) | (pv[i].y >= cy ? 2 : 0) | (pv[i].z >= cz ? 4 : 0)) : 8;
                oc[i] = o;
                #pragma unroll
                for (int k = 0; k < 8; ++k)
                    c8[k] += (int)__popcll(__ballot(o == k));
            }
            #pragma unroll
            for (int k = 0; k < 8; ++k) nonempty += (c8[k] > 0) ? 1 : 0;
        }

        if (c <= LEAF_SZ || nonempty <= 1) {
            if (lane == 0) g_nmeta[cn] = make_int4(st + ca, st + cb, 0, 0);
        } else {
            int off[8], acc = 0;
            #pragma unroll
            for (int k = 0; k < 8; ++k) { off[k] = acc; acc += c8[k]; }
            if (lane == 0) g_nmeta[cn] = make_int4(st + ca, st + cb, abase, nonempty);
            int cum[8] = {0,0,0,0,0,0,0,0};
            #pragma unroll
            for (int i = 0; i < 4; ++i) {
                int o = oc[i];
                int pdst = 0;
                #pragma unroll
                for (int k = 0; k < 8; ++k) {
                    unsigned long long b = __ballot(o == k);
                    if (o == k) pdst = ca + off[k] + cum[k] + (int)__popcll(b & mlt);
                    cum[k] += (int)__popcll(b);
                }
                if (o < 8) { a4[pdst] = pv[i]; aid[pdst] = idv[i]; }
            }
            asm volatile("s_waitcnt lgkmcnt(0)" ::: "memory");
            __builtin_amdgcn_wave_barrier();
            if (lane == 0) {
                int ci = 0;
                #pragma unroll
                for (int k = 0; k < 8; ++k) {
                    if (c8[k] > 0) {
                        lid[sp + ci] = abase + ci;
                        la [sp + ci] = ca + off[k];
                        lbb[sp + ci] = ca + off[k] + c8[k];
                        ++ci;
                    }
                }
            }
            abase += nonempty; sp += nonempty;
            if (sp > LSTK) sp = LSTK;
        }
        if (sp <= 0) break;
        --sp;
        __builtin_amdgcn_wave_barrier();
        asm volatile("s_waitcnt lgkmcnt(0)" ::: "memory");
        cn = lid[sp]; ca = la[sp]; cb = lbb[sp];
        __builtin_amdgcn_wave_barrier();
    }

    for (int j = lane; j < cnt; j += 64) {
        g_p4[st + j]  = a4[j];
        g_perm[st + j] = aid[j];
    }
    asm volatile("s_waitcnt vmcnt(0)" ::: "memory");
}

// Global-memory wave path for rare cnt > LCAP nodes (R10-proven).
__device__ __forceinline__ int proc_big(int n, int st, int en, int abase, int* cur,
                                        int* gid, int* gst, int* gen, int sp)
{
    const int lane = threadIdx.x & 63;
    const int cnt = en - st;

    float mnx = 3.402823466e38f, mny = mnx, mnz = mnx;
    float mxx = -mnx, mxy = -mnx, mxz = -mnx;
    double sx = 0.0, sy = 0.0, sz = 0.0, sq = 0.0;
    for (int j = st + lane; j < en; j += 64) {
        float4 p = g_p4[j];
        mnx = fminf(mnx, p.x); mny = fminf(mny, p.y); mnz = fminf(mnz, p.z);
        mxx = fmaxf(mxx, p.x); mxy = fmaxf(mxy, p.y); mxz = fmaxf(mxz, p.z);
        sx += (double)p.x; sy += (double)p.y; sz += (double)p.z; sq += (double)p.w;
    }
    for (int o = 1; o < 64; o <<= 1) {
        mnx = fminf(mnx, __shfl_xor(mnx, o));
        mny = fminf(mny, __shfl_xor(mny, o));
        mnz = fminf(mnz, __shfl_xor(mnz, o));
        mxx = fmaxf(mxx, __shfl_xor(mxx, o));
        mxy = fmaxf(mxy, __shfl_xor(mxy, o));
        mxz = fmaxf(mxz, __shfl_xor(mxz, o));
        sx += __shfl_xor(sx, o);
        sy += __shfl_xor(sy, o);
        sz += __shfl_xor(sz, o);
        sq += __shfl_xor(sq, o);
    }
    const float cx = 0.5f * (mnx + mxx);
    const float cy = 0.5f * (mny + mxy);
    const float cz = 0.5f * (mnz + mxz);
    if (lane == 0) {
        g_nc4[n] = make_float4(cx, cy, cz, 0.5f * fmaxf(fmaxf(mxx - mnx, mxy - mny), mxz - mnz));
        const float fc = (float)cnt;
        g_nm4[n] = make_float4((float)sx / fc, (float)sy / fc, (float)sz / fc, (float)sq);
    }

    int c8[8] = {0,0,0,0,0,0,0,0};
    for (int j = st + lane; j < en; j += 64) {
        float4 p = g_p4[j];
        int oct = (p.x >= cx ? 1 : 0) | (p.y >= cy ? 2 : 0) | (p.z >= cz ? 4 : 0);
        c8[oct]++;
    }
    #pragma unroll
    for (int k = 0; k < 8; ++k)
        for (int o = 1; o < 64; o <<= 1)
            c8[k] += __shfl_xor(c8[k], o);
    int nonempty = 0;
    #pragma unroll
    for (int k = 0; k < 8; ++k) nonempty += (c8[k] > 0) ? 1 : 0;
    if (nonempty <= 1) {
        if (lane == 0) g_nmeta[n] = make_int4(st, en, 0, 0);
        return 0;
    }

    int off[8], acc = 0;
    #pragma unroll
    for (int k = 0; k < 8; ++k) { off[k] = acc; acc += c8[k]; }
    if (lane == 0) {
        g_nmeta[n] = make_int4(st, en, abase, nonempty);
        int ci = 0;
        #pragma unroll
        for (int k = 0; k < 8; ++k) {
            if (c8[k] > 0) {
                gid[sp + ci] = abase + ci;
                gst[sp + ci] = st + off[k];
                gen[sp + ci] = st + off[k] + c8[k];
                ++ci;
            }
        }
    }
    if (lane < 8) cur[lane] = st + off[lane];
    __builtin_amdgcn_wave_barrier();
    for (int j = st + lane; j < en; j += 64) {
        float4 p = g_p4[j];
        int id = g_perm[j];
        int oct = (p.x >= cx ? 1 : 0) | (p.y >= cy ? 2 : 0) | (p.z >= cz ? 4 : 0);
        int pdst = atomicAdd(&cur[oct], 1);
        g_ptmp[pdst] = id; g_t4[pdst] = p;
    }
    asm volatile("s_waitcnt vmcnt(0)" ::: "memory");
    __builtin_amdgcn_wave_barrier();
    for (int j = st + lane; j < en; j += 64) {
        g_perm[j] = g_ptmp[j];
        g_p4[j]   = g_t4[j];
    }
    asm volatile("s_waitcnt vmcnt(0)" ::: "memory");
    return nonempty;
}

// Static task->wave mapping; arena = [le + 2*st, le + 2*en) per task.
__global__ __launch_bounds__(256) void subtree_kernel()
{
    __shared__ float4 s_a4[4][LCAP];
    __shared__ int    s_aid[4][LCAP];
    __shared__ int    s_lid[4][LSTK], s_la[4][LSTK], s_lb[4][LSTK];
    __shared__ int    s_gid[4][GSTK], s_gst[4][GSTK], s_gen[4][GSTK];
    __shared__ int    s_cur[4][8];

    const int wid = threadIdx.x >> 6;
    const int gw  = blockIdx.x * 4 + wid;
    const int lb = g_lrange[4], le = g_lrange[5];   // frontier after 4 levels
    const int ntasks = le - lb;

    float4* a4 = s_a4[wid];  int* aid = s_aid[wid];
    int* lid = s_lid[wid];   int* la = s_la[wid];  int* lbb = s_lb[wid];
    int* gid = s_gid[wid];   int* gst = s_gst[wid]; int* gen = s_gen[wid];
    int* cur = s_cur[wid];

    for (int task = gw; task < ntasks; task += BGRID * 4) {
        int cn  = lb + task;
        int cst = g_nstart[cn], cen = g_nend[cn];
        int abase = le + 2 * cst;
        int gsp = 0;
        while (true) {
            if (cen - cst <= LCAP) {
                lds_subtree(cn, cst, cen, abase, a4, aid, lid, la, lbb);
            } else {
                int num = proc_big(cn, cst, cen, abase, cur, gid, gst, gen, gsp);
                abase += num; gsp += num;
                if (gsp > GSTK) gsp = GSTK;
            }
            if (gsp <= 0) break;
            --gsp;
            __builtin_amdgcn_wave_barrier();
            asm volatile("s_waitcnt lgkmcnt(0)" ::: "memory");
            cn = gid[gsp]; cst = gst[gsp]; cen = gen[gsp];
            __builtin_amdgcn_wave_barrier();
        }
    }
}

// ---------------------------------------------------------------------------
// One wave per target. Monopoles inline; leaf pair-list built+drained in
// PCAP-sized chunks (contiguous per-lane slices, O(1) self-skip; correct for
// any leaf size). 20KB LDS/block -> 8 blocks/CU -> 32-wave occupancy ceiling.
// ---------------------------------------------------------------------------
__global__ __launch_bounds__(256)
void traverse_kernel(const int* __restrict__ batch,
                     const float* __restrict__ p_scr, const float* __restrict__ p_soft,
                     float* __restrict__ out, int N)
{
    __shared__ int s_q[4][NQ];
    __shared__ int s_pj[4][PCAP];
    __shared__ int s_qt[4];
    const int wid  = threadIdx.x >> 6;
    const int lane = threadIdx.x & 63;
    const int slot = blockIdx.x * 4 + wid;
    if (slot >= N) return;                 // wave-uniform; no __syncthreads used
    const int t = g_perm[slot];

    const float scr   = p_scr[0];
    const float soft  = p_soft[0];
    const float soft2 = soft * soft;
    const float cexp  = -scr * 1.4426950408889634f;  // exp(-scr*r) = exp2(cexp*r)
    const float4 tp = g_p4[slot];
    const float tx = tp.x, ty = tp.y, tz = tp.z;
    const int inv_t = slot;

    volatile int* q  = s_q[wid];
    volatile int* pj = s_pj[wid];
    if (lane == 0) { q[0] = g_root[batch[t]]; s_qt[wid] = 1; }
    __builtin_amdgcn_wave_barrier();

    float phi = 0.f;
    int qh = 0;
    while (true) {
        __builtin_amdgcn_wave_barrier();
        int qt = ((volatile int*)s_qt)[wid];
        if (qh >= qt) break;
        int take = qt - qh; if (take > 64) take = 64;
        int node = (lane < take) ? q[(qh + lane) & (NQ - 1)] : -1;
        qh += take;

        int leaf_st = 0, leaf_cnt = 0;
        if (node >= 0) {
            const int4 meta = g_nmeta[node];
            if (meta.w == 0) {
                leaf_st = meta.x; leaf_cnt = meta.y - meta.x;
            } else {
                float4 c4 = g_nc4[node];
                float dx = tx - c4.x, dy = ty - c4.y, dz = tz - c4.z;
                float dist = sqrtf(dx*dx + dy*dy + dz*dz + soft2);
                float diam = fmaxf(2.0f * c4.w, 1e-9f);
                bool inside = (inv_t >= meta.x) && (inv_t < meta.y);
                if (!inside && diam < 0.5f * dist) {
                    float4 m4 = g_nm4[node];
                    float ax = tx - m4.x, ay = ty - m4.y, az = tz - m4.z;
                    float s = ax*ax + ay*ay + az*az + soft2;
                    float rinv = rsqrtf(s);
                    phi += m4.w * exp2f(cexp * (s * rinv)) * rinv;
                } else {
                    int p = atomicAdd(&s_qt[wid], meta.w);
                    for (int c = 0; c < meta.w; ++c) q[(p + c) & (NQ - 1)] = meta.z + c;
                }
            }
        }

        // wave prefix-sum of (leaf size minus self) -> chunked flat pair list
        bool hasself = (inv_t >= leaf_st) && (inv_t < leaf_st + leaf_cnt);
        int cnt_adj = leaf_cnt - (hasself ? 1 : 0);
        int x = cnt_adj;
        #pragma unroll
        for (int o = 1; o < 64; o <<= 1) { int y = __shfl_up(x, o); if (lane >= o) x += y; }
        int total = __shfl(x, 63);
        int off = x - cnt_adj;
        int selfpos = hasself ? (inv_t - leaf_st) : 0x7fffffff;

        for (int cb = 0; cb < total; cb += PCAP) {
            int ce = cb + PCAP; if (ce > total) ce = total;
            int ws = off > cb ? off : cb;
            int we = (off + cnt_adj) < ce ? (off + cnt_adj) : ce;
            for (int w = ws; w < we; ++w) {
                int i = w - off;
                pj[w - cb] = leaf_st + i + (i >= selfpos ? 1 : 0);
            }
            __builtin_amdgcn_wave_barrier();
            int cnum = ce - cb;
            for (int p = lane; p < cnum; p += 64) {
                int j = pj[p];
                float4 pp = g_p4[j];
                float dx = tx - pp.x, dy = ty - pp.y, dz = tz - pp.z;
                float s = dx*dx + dy*dy + dz*dz + soft2;
                float rinv = rsqrtf(s);
                phi += pp.w * exp2f(cexp * (s * rinv)) * rinv;
            }
            __builtin_amdgcn_wave_barrier();
        }
    }

    #pragma unroll
    for (int o = 1; o < 64; o <<= 1) phi += __shfl_xor(phi, o);
    if (lane == 0) out[t] = 0.5f * (tp.w * phi);
}

extern "C" void kernel_launch(void* const* d_in, const int* in_sizes, int n_in,
                              void* d_out, int out_size, void* d_ws, size_t ws_size,
                              hipStream_t stream) {
    const float* pos    = (const float*)d_in[0];
    const int*   batch  = (const int*)  d_in[1];
    const float* source = (const float*)d_in[3];
    const float* p_scr  = (const float*)d_in[4];
    const float* p_soft = (const float*)d_in[5];

    const int N        = in_sizes[0] / 3;
    const int n_graphs = in_sizes[2] / 9;

    initroots_kernel<<<(N + 255) / 256, 256, 0, stream>>>(pos, source, batch, N, n_graphs);
    level_kernel<<<BGRID, 256, 0, stream>>>(0);
    level_kernel<<<BGRID, 256, 0, stream>>>(1);
    level_kernel<<<BGRID, 256, 0, stream>>>(2);
    level_kernel<<<BGRID, 256, 0, stream>>>(3);
    subtree_kernel<<<BGRID, 256, 0, stream>>>();

    const int blocks = (N + 3) / 4;  // 4 waves (targets) per 256-thread block
    traverse_kernel<<<blocks, 256, 0, stream>>>(batch, p_scr, p_soft, (float*)d_out, N);
}

// Round 14
// 177.753 us; speedup vs baseline: 2.1082x; 1.0850x over previous
//
#include <hip/hip_runtime.h>

#define LEAF_SZ 32
#define MAXN 16384
#define MAXNODES 65536
#define ARENA_BASE 32768
#define MAXG 64
#define NQ 1024
#define PCAP 224
#define BGRID 128
#define LCAP 256
#define LSTK 192
#define BSTK 32
#define WQCAP 64

struct __align__(64) TNode { int4 meta; float4 c4; float4 m4; float4 pad; };

// Static device scratch (fully rewritten each call; no cross-call state relied on).
__device__ int    g_perm[MAXN];
__device__ int    g_ptmp[MAXN];
__device__ float4 g_p4[MAXN];    // x,y,z,charge in perm order
__device__ float4 g_t4[MAXN];
__device__ int    g_nstart[MAXNODES];
__device__ int    g_nend[MAXNODES];
__device__ TNode  g_nodes[MAXNODES];  // meta(st,en,first_child,nchild|0=leaf), bbox c4, monopole m4
__device__ int    g_root[MAXG];
__device__ int    g_ncount;
__device__ int    g_lrange[8];
__device__ int    g_done[4];

struct NodeSh {
    float  mn[4][3], mx[4][3];
    double sx[4], sy[4], sz[4], sq[4];
    int    c8[4][8];
    int    cur[8];
    float  cc[3];
    int    info;
    int    base, num;
    int    tot[8], offk[8];
};

// Block-cooperative node processing (R2-proven logic, st/en parameterized).
// Writes node outputs to g_nodes[n]; children's ranges to g_nstart/g_nend AND
// to sh.tot/offk/base/num for in-kernel consumers.
__device__ __forceinline__ void process_node2(NodeSh& sh, int n, int st, int en)
{
    const int tid  = threadIdx.x;
    const int wid  = tid >> 6;
    const int lane = tid & 63;
    const int cnt = en - st;

    float mnx = 3.402823466e38f, mny = mnx, mnz = mnx;
    float mxx = -mnx, mxy = -mnx, mxz = -mnx;
    double sx = 0.0, sy = 0.0, sz = 0.0, sq = 0.0;
    for (int j = st + tid; j < en; j += 256) {
        float4 p = g_p4[j];
        mnx = fminf(mnx, p.x); mny = fminf(mny, p.y); mnz = fminf(mnz, p.z);
        mxx = fmaxf(mxx, p.x); mxy = fmaxf(mxy, p.y); mxz = fmaxf(mxz, p.z);
        sx += (double)p.x; sy += (double)p.y; sz += (double)p.z; sq += (double)p.w;
    }
    for (int o = 1; o < 64; o <<= 1) {
        mnx = fminf(mnx, __shfl_xor(mnx, o));
        mny = fminf(mny, __shfl_xor(mny, o));
        mnz = fminf(mnz, __shfl_xor(mnz, o));
        mxx = fmaxf(mxx, __shfl_xor(mxx, o));
        mxy = fmaxf(mxy, __shfl_xor(mxy, o));
        mxz = fmaxf(mxz, __shfl_xor(mxz, o));
        sx += __shfl_xor(sx, o);
        sy += __shfl_xor(sy, o);
        sz += __shfl_xor(sz, o);
        sq += __shfl_xor(sq, o);
    }
    if (lane == 0) {
        sh.mn[wid][0] = mnx; sh.mn[wid][1] = mny; sh.mn[wid][2] = mnz;
        sh.mx[wid][0] = mxx; sh.mx[wid][1] = mxy; sh.mx[wid][2] = mxz;
        sh.sx[wid] = sx; sh.sy[wid] = sy; sh.sz[wid] = sz; sh.sq[wid] = sq;
    }
    __syncthreads();
    if (tid == 0) {
        float a0 = sh.mn[0][0], a1 = sh.mn[0][1], a2 = sh.mn[0][2];
        float b0 = sh.mx[0][0], b1 = sh.mx[0][1], b2 = sh.mx[0][2];
        double tx = sh.sx[0], ty = sh.sy[0], tz = sh.sz[0], tq = sh.sq[0];
        for (int w = 1; w < 4; ++w) {
            a0 = fminf(a0, sh.mn[w][0]); a1 = fminf(a1, sh.mn[w][1]); a2 = fminf(a2, sh.mn[w][2]);
            b0 = fmaxf(b0, sh.mx[w][0]); b1 = fmaxf(b1, sh.mx[w][1]); b2 = fmaxf(b2, sh.mx[w][2]);
            tx += sh.sx[w]; ty += sh.sy[w]; tz += sh.sz[w]; tq += sh.sq[w];
        }
        float cx = 0.5f * (a0 + b0), cy = 0.5f * (a1 + b1), cz = 0.5f * (a2 + b2);
        g_nodes[n].c4 = make_float4(cx, cy, cz, 0.5f * fmaxf(fmaxf(b0 - a0, b1 - a1), b2 - a2));
        const float fc = (float)cnt;
        g_nodes[n].m4 = make_float4((float)tx / fc, (float)ty / fc, (float)tz / fc, (float)tq);
        sh.cc[0] = cx; sh.cc[1] = cy; sh.cc[2] = cz;
        if (cnt <= LEAF_SZ) { g_nodes[n].meta = make_int4(st, en, 0, 0); sh.info = -1; }
        else sh.info = 0;
    }
    __syncthreads();
    if (sh.info < 0) return;
    const float cx = sh.cc[0], cy = sh.cc[1], cz = sh.cc[2];

    int c8[8] = {0,0,0,0,0,0,0,0};
    for (int j = st + tid; j < en; j += 256) {
        float4 p = g_p4[j];
        int oct = (p.x >= cx ? 1 : 0) | (p.y >= cy ? 2 : 0) | (p.z >= cz ? 4 : 0);
        c8[oct]++;
    }
    #pragma unroll
    for (int k = 0; k < 8; ++k)
        for (int o = 1; o < 64; o <<= 1)
            c8[k] += __shfl_xor(c8[k], o);
    if (lane == 0)
        #pragma unroll
        for (int k = 0; k < 8; ++k) sh.c8[wid][k] = c8[k];
    __syncthreads();
    if (tid == 0) {
        int tot[8], nonempty = 0;
        #pragma unroll
        for (int k = 0; k < 8; ++k) {
            tot[k] = sh.c8[0][k] + sh.c8[1][k] + sh.c8[2][k] + sh.c8[3][k];
            nonempty += (tot[k] > 0) ? 1 : 0;
        }
        if (nonempty <= 1) { g_nodes[n].meta = make_int4(st, en, 0, 0); sh.info = -1; }
        else {
            int base = atomicAdd(&g_ncount, nonempty);
            int acc = st, ci = base;
            #pragma unroll
            for (int k = 0; k < 8; ++k) {
                sh.cur[k] = acc;
                sh.offk[k] = acc - st;
                sh.tot[k] = tot[k];
                if (tot[k] > 0) { g_nstart[ci] = acc; g_nend[ci] = acc + tot[k]; ++ci; }
                acc += tot[k];
            }
            g_nodes[n].meta = make_int4(st, en, base, nonempty);
            sh.base = base; sh.num = nonempty; sh.info = 1;
        }
    }
    __syncthreads();
    if (sh.info < 0) return;

    for (int j = st + tid; j < en; j += 256) {
        float4 p = g_p4[j];
        int id = g_perm[j];
        int oct = (p.x >= cx ? 1 : 0) | (p.y >= cy ? 2 : 0) | (p.z >= cz ? 4 : 0);
        int pdst = atomicAdd(&sh.cur[oct], 1);
        g_ptmp[pdst] = id; g_t4[pdst] = p;
    }
    __syncthreads();
    for (int j = st + tid; j < en; j += 256) {
        g_perm[j] = g_ptmp[j];
        g_p4[j]   = g_t4[j];
    }
    __syncthreads();
}

// Merged init (all blocks) + roots scan (block 0 only).
__global__ __launch_bounds__(256)
void initroots_kernel(const float* __restrict__ pos, const float* __restrict__ src,
                      const int* __restrict__ batch, int N, int n_graphs)
{
    __shared__ int s_first[MAXG], s_end[MAXG];
    const int tid = threadIdx.x;
    int i = blockIdx.x * 256 + tid;
    if (i < N) {
        g_perm[i] = i;
        g_p4[i] = make_float4(pos[3*i], pos[3*i+1], pos[3*i+2], src[i]);
    }
    if (blockIdx.x != 0) return;

    for (int g = tid; g < MAXG; g += 256) { s_first[g] = -1; s_end[g] = 0; }
    __syncthreads();
    for (int j = tid; j < N; j += 256) {
        int b = batch[j];
        if (j == 0     || batch[j-1] != b) s_first[b] = j;
        if (j == N - 1 || batch[j+1] != b) s_end[b]   = j + 1;
    }
    __syncthreads();
    if (tid == 0) {
        int nc = 0;
        for (int g = 0; g < n_graphs && g < MAXG; ++g) {
            if (s_first[g] >= 0) {
                g_root[g] = nc;
                g_nstart[nc] = s_first[g];
                g_nend[nc]   = s_end[g];
                ++nc;
            } else g_root[g] = -1;
        }
        g_ncount = nc;
        g_lrange[0] = 0; g_lrange[1] = nc;
        g_done[0] = g_done[1] = g_done[2] = g_done[3] = 0;
    }
}

// One launch per level (2 levels): kernel boundary = free device-wide barrier.
__global__ __launch_bounds__(256) void level_kernel(int lev)
{
    __shared__ NodeSh sh;
    const int lb = g_lrange[lev], le = g_lrange[lev + 1];
    for (int n = lb + blockIdx.x; n < le; n += BGRID) {
        __syncthreads();
        process_node2(sh, n, g_nstart[n], g_nend[n]);
    }
    __syncthreads();
    if (threadIdx.x == 0) {
        __threadfence();
        int d = atomicAdd(&g_done[lev], 1);
        if (d == BGRID - 1)
            g_lrange[lev + 2] = atomicAdd(&g_ncount, 0);
    }
}

// ---------------------------------------------------------------------------
// LDS-resident subtree DFS (cnt <= LCAP) — R11-proven, AoS node writes.
// ---------------------------------------------------------------------------
__device__ __forceinline__ void lds_subtree(int rootn, int st, int en, int abase,
                                            float4* a4, int* aid,
                                            int* lid, int* la, int* lbb)
{
    const int lane = threadIdx.x & 63;
    const int cnt = en - st;
    const unsigned long long mlt = (1ull << lane) - 1ull;

    for (int j = lane; j < cnt; j += 64) {
        a4[j]  = g_p4[st + j];
        aid[j] = g_perm[st + j];
    }
    asm volatile("s_waitcnt vmcnt(0) lgkmcnt(0)" ::: "memory");
    __builtin_amdgcn_wave_barrier();

    int sp = 0;
    int cn = rootn, ca = 0, cb = cnt;
    while (true) {
        const int c = cb - ca;
        float4 pv[4]; int idv[4]; int oc[4];
        float mnx = 3.402823466e38f, mny = mnx, mnz = mnx;
        float mxx = -mnx, mxy = -mnx, mxz = -mnx;
        float sx = 0.f, sy = 0.f, sz = 0.f, sq = 0.f;
        #pragma unroll
        for (int i = 0; i < 4; ++i) {
            bool act = (i*64 + lane) < c;
            int j = act ? (ca + i*64 + lane) : ca;
            float4 p = a4[j];
            pv[i] = p; idv[i] = aid[j];
            if (act) {
                mnx = fminf(mnx, p.x); mny = fminf(mny, p.y); mnz = fminf(mnz, p.z);
                mxx = fmaxf(mxx, p.x); mxy = fmaxf(mxy, p.y); mxz = fmaxf(mxz, p.z);
                sx += p.x; sy += p.y; sz += p.z; sq += p.w;
            }
        }
        for (int o = 1; o < 64; o <<= 1) {
            mnx = fminf(mnx, __shfl_xor(mnx, o));
            mny = fminf(mny, __shfl_xor(mny, o));
            mnz = fminf(mnz, __shfl_xor(mnz, o));
            mxx = fmaxf(mxx, __shfl_xor(mxx, o));
            mxy = fmaxf(mxy, __shfl_xor(mxy, o));
            mxz = fmaxf(mxz, __shfl_xor(mxz, o));
            sx += __shfl_xor(sx, o);
            sy += __shfl_xor(sy, o);
            sz += __shfl_xor(sz, o);
            sq += __shfl_xor(sq, o);
        }
        const float cx = 0.5f * (mnx + mxx);
        const float cy = 0.5f * (mny + mxy);
        const float cz = 0.5f * (mnz + mxz);
        if (lane == 0) {
            g_nodes[cn].c4 = make_float4(cx, cy, cz, 0.5f * fmaxf(fmaxf(mxx - mnx, mxy - mny), mxz - mnz));
            const float fc = (float)c;
            g_nodes[cn].m4 = make_float4(sx / fc, sy / fc, sz / fc, sq);
        }

        int nonempty = 0;
        int c8[8] = {0,0,0,0,0,0,0,0};
        if (c > LEAF_SZ) {
            #pragma unroll
            for (int i = 0; i < 4; ++i) {
                bool act = (i*64 + lane) < c;
                int o = act ? ((pv[i].x >= cx ? 1 : 0) | (pv[i].y >= cy ? 2 : 0) | (pv[i].z >= cz ? 4 : 0)) : 8;
                oc[i] = o;
                #pragma unroll
                for (int k = 0; k < 8; ++k)
                    c8[k] += (int)__popcll(__ballot(o == k));
            }
            #pragma unroll
            for (int k = 0; k < 8; ++k) nonempty += (c8[k] > 0) ? 1 : 0;
        }

        if (c <= LEAF_SZ || nonempty <= 1) {
            if (lane == 0) g_nodes[cn].meta = make_int4(st + ca, st + cb, 0, 0);
        } else {
            int off[8], acc = 0;
            #pragma unroll
            for (int k = 0; k < 8; ++k) { off[k] = acc; acc += c8[k]; }
            if (lane == 0) g_nodes[cn].meta = make_int4(st + ca, st + cb, abase, nonempty);
            int cum[8] = {0,0,0,0,0,0,0,0};
            #pragma unroll
            for (int i = 0; i < 4; ++i) {
                int o = oc[i];
                int pdst = 0;
                #pragma unroll
                for (int k = 0; k < 8; ++k) {
                    unsigned long long b = __ballot(o == k);
                    if (o == k) pdst = ca + off[k] + cum[k] + (int)__popcll(b & mlt);
                    cum[k] += (int)__popcll(b);
                }
                if (o < 8) { a4[pdst] = pv[i]; aid[pdst] = idv[i]; }
            }
            asm volatile("s_waitcnt lgkmcnt(0)" ::: "memory");
            __builtin_amdgcn_wave_barrier();
            if (lane == 0) {
                int ci = 0;
                #pragma unroll
                for (int k = 0; k < 8; ++k) {
                    if (c8[k] > 0) {
                        lid[sp + ci] = abase + ci;
                        la [sp + ci] = ca + off[k];
                        lbb[sp + ci] = ca + off[k] + c8[k];
                        ++ci;
                    }
                }
            }
            abase += nonempty; sp += nonempty;
            if (sp > LSTK) sp = LSTK;
        }
        if (sp <= 0) break;
        --sp;
        __builtin_amdgcn_wave_barrier();
        asm volatile("s_waitcnt lgkmcnt(0)" ::: "memory");
        cn = lid[sp]; ca = la[sp]; cb = lbb[sp];
        __builtin_amdgcn_wave_barrier();
    }

    for (int j = lane; j < cnt; j += 64) {
        g_p4[st + j]  = a4[j];
        g_perm[st + j] = aid[j];
    }
    asm volatile("s_waitcnt vmcnt(0)" ::: "memory");
}

// ---------------------------------------------------------------------------
// Merged lvl2+lvl3+subtree: block claims a level-2 frontier task; phase 1
// block-coop DFS over >LCAP nodes (children tracked in LDS stack; no device
// barrier needed since producer==consumer block); small subtrees collected
// into wq; phase 2: the 4 waves drain wq via lds_subtree in parallel.
// Wave arena ids ARENA_BASE+2*st are disjoint from block-level g_ncount ids.
// ---------------------------------------------------------------------------
__global__ __launch_bounds__(256) void block_subtree_kernel()
{
    __shared__ NodeSh sh;
    __shared__ int bs_id[BSTK], bs_st[BSTK], bs_en[BSTK];
    __shared__ int wq_id[WQCAP], wq_st[WQCAP], wq_en[WQCAP];
    __shared__ int s_bsp, s_wq;
    __shared__ float4 s_a4[4][LCAP];
    __shared__ int    s_aid[4][LCAP];
    __shared__ int    s_lid[4][LSTK], s_la[4][LSTK], s_lb[4][LSTK];

    const int tid = threadIdx.x;
    const int wid = tid >> 6;
    const int lb = g_lrange[2], le = g_lrange[3];

    for (int task = lb + blockIdx.x; task < le; task += BGRID) {
        __syncthreads();
        if (tid == 0) {
            int st = g_nstart[task], en = g_nend[task];
            if (en - st <= LCAP) { wq_id[0] = task; wq_st[0] = st; wq_en[0] = en; s_wq = 1; s_bsp = 0; }
            else                 { bs_id[0] = task; bs_st[0] = st; bs_en[0] = en; s_bsp = 1; s_wq = 0; }
        }
        __syncthreads();

        // phase 1: block-coop DFS over big nodes
        while (true) {
            __syncthreads();
            const int bsp = s_bsp;
            if (bsp == 0) break;                     // uniform
            const int n  = bs_id[bsp-1];
            const int st = bs_st[bsp-1];
            const int en = bs_en[bsp-1];
            __syncthreads();                         // all read before tid0 pops
            if (tid == 0) s_bsp = bsp - 1;
            process_node2(sh, n, st, en);
            if (tid == 0 && sh.info == 1) {
                int ci = 0;
                #pragma unroll
                for (int k = 0; k < 8; ++k) {
                    if (sh.tot[k] > 0) {
                        int cst = st + sh.offk[k], cen = cst + sh.tot[k];
                        int cid = sh.base + ci; ++ci;
                        if (cen - cst <= LCAP) {
                            if (s_wq < WQCAP) { wq_id[s_wq] = cid; wq_st[s_wq] = cst; wq_en[s_wq] = cen; ++s_wq; }
                        } else {
                            if (s_bsp < BSTK) { bs_id[s_bsp] = cid; bs_st[s_bsp] = cst; bs_en[s_bsp] = cen; ++s_bsp; }
                        }
                    }
                }
            }
        }
        __syncthreads();

        // phase 2: waves drain wq independently (no block syncs inside)
        const int nwq = s_wq;
        float4* a4 = s_a4[wid];  int* aid = s_aid[wid];
        int* lid = s_lid[wid];   int* la = s_la[wid];  int* lbb = s_lb[wid];
        for (int i = wid; i < nwq; i += 4) {
            int cid = wq_id[i], cst = wq_st[i], cen = wq_en[i];
            lds_subtree(cid, cst, cen, ARENA_BASE + 2 * cst, a4, aid, lid, la, lbb);
        }
    }
}

// ---------------------------------------------------------------------------
// One wave per target. AoS node record: meta load pays the miss, c4/m4 are
// same-line hits. Chunked pair-list drain (R13-proven).
// ---------------------------------------------------------------------------
__global__ __launch_bounds__(256)
void traverse_kernel(const int* __restrict__ batch,
                     const float* __restrict__ p_scr, const float* __restrict__ p_soft,
                     float* __restrict__ out, int N)
{
    __shared__ int s_q[4][NQ];
    __shared__ int s_pj[4][PCAP];
    __shared__ int s_qt[4];
    const int wid  = threadIdx.x >> 6;
    const int lane = threadIdx.x & 63;
    const int slot = blockIdx.x * 4 + wid;
    if (slot >= N) return;                 // wave-uniform; no __syncthreads used
    const int t = g_perm[slot];

    const float scr   = p_scr[0];
    const float soft  = p_soft[0];
    const float soft2 = soft * soft;
    const float cexp  = -scr * 1.4426950408889634f;  // exp(-scr*r) = exp2(cexp*r)
    const float4 tp = g_p4[slot];
    const float tx = tp.x, ty = tp.y, tz = tp.z;
    const int inv_t = slot;

    volatile int* q  = s_q[wid];
    volatile int* pj = s_pj[wid];
    if (lane == 0) { q[0] = g_root[batch[t]]; s_qt[wid] = 1; }
    __builtin_amdgcn_wave_barrier();

    float phi = 0.f;
    int qh = 0;
    while (true) {
        __builtin_amdgcn_wave_barrier();
        int qt = ((volatile int*)s_qt)[wid];
        if (qh >= qt) break;
        int take = qt - qh; if (take > 64) take = 64;
        int node = (lane < take) ? q[(qh + lane) & (NQ - 1)] : -1;
        qh += take;

        int leaf_st = 0, leaf_cnt = 0;
        if (node >= 0) {
            const int4 meta = g_nodes[node].meta;
            if (meta.w == 0) {
                leaf_st = meta.x; leaf_cnt = meta.y - meta.x;
            } else {
                float4 c4 = g_nodes[node].c4;          // same 64B line as meta
                float dx = tx - c4.x, dy = ty - c4.y, dz = tz - c4.z;
                float dist = sqrtf(dx*dx + dy*dy + dz*dz + soft2);
                float diam = fmaxf(2.0f * c4.w, 1e-9f);
                bool inside = (inv_t >= meta.x) && (inv_t < meta.y);
                if (!inside && diam < 0.5f * dist) {
                    float4 m4 = g_nodes[node].m4;      // same line -> L1 hit
                    float ax = tx - m4.x, ay = ty - m4.y, az = tz - m4.z;
                    float s = ax*ax + ay*ay + az*az + soft2;
                    float rinv = rsqrtf(s);
                    phi += m4.w * exp2f(cexp * (s * rinv)) * rinv;
                } else {
                    int p = atomicAdd(&s_qt[wid], meta.w);
                    for (int c = 0; c < meta.w; ++c) q[(p + c) & (NQ - 1)] = meta.z + c;
                }
            }
        }

        // wave prefix-sum of (leaf size minus self) -> chunked flat pair list
        bool hasself = (inv_t >= leaf_st) && (inv_t < leaf_st + leaf_cnt);
        int cnt_adj = leaf_cnt - (hasself ? 1 : 0);
        int x = cnt_adj;
        #pragma unroll
        for (int o = 1; o < 64; o <<= 1) { int y = __shfl_up(x, o); if (lane >= o) x += y; }
        int total = __shfl(x, 63);
        int off = x - cnt_adj;
        int selfpos = hasself ? (inv_t - leaf_st) : 0x7fffffff;

        for (int cb = 0; cb < total; cb += PCAP) {
            int ce = cb + PCAP; if (ce > total) ce = total;
            int ws = off > cb ? off : cb;
            int we = (off + cnt_adj) < ce ? (off + cnt_adj) : ce;
            for (int w = ws; w < we; ++w) {
                int i = w - off;
                pj[w - cb] = leaf_st + i + (i >= selfpos ? 1 : 0);
            }
            __builtin_amdgcn_wave_barrier();
            int cnum = ce - cb;
            for (int p = lane; p < cnum; p += 64) {
                int j = pj[p];
                float4 pp = g_p4[j];
                float dx = tx - pp.x, dy = ty - pp.y, dz = tz - pp.z;
                float s = dx*dx + dy*dy + dz*dz + soft2;
                float rinv = rsqrtf(s);
                phi += pp.w * exp2f(cexp * (s * rinv)) * rinv;
            }
            __builtin_amdgcn_wave_barrier();
        }
    }

    #pragma unroll
    for (int o = 1; o < 64; o <<= 1) phi += __shfl_xor(phi, o);
    if (lane == 0) out[t] = 0.5f * (tp.w * phi);
}

extern "C" void kernel_launch(void* const* d_in, const int* in_sizes, int n_in,
                              void* d_out, int out_size, void* d_ws, size_t ws_size,
                              hipStream_t stream) {
    const float* pos    = (const float*)d_in[0];
    const int*   batch  = (const int*)  d_in[1];
    const float* source = (const float*)d_in[3];
    const float* p_scr  = (const float*)d_in[4];
    const float* p_soft = (const float*)d_in[5];

    const int N        = in_sizes[0] / 3;
    const int n_graphs = in_sizes[2] / 9;

    initroots_kernel<<<(N + 255) / 256, 256, 0, stream>>>(pos, source, batch, N, n_graphs);
    level_kernel<<<BGRID, 256, 0, stream>>>(0);
    level_kernel<<<BGRID, 256, 0, stream>>>(1);
    block_subtree_kernel<<<BGRID, 256, 0, stream>>>();

    const int blocks = (N + 3) / 4;  // 4 waves (targets) per 256-thread block
    traverse_kernel<<<blocks, 256, 0, stream>>>(batch, p_scr, p_soft, (float*)d_out, N);
}

// Round 15
// 151.879 us; speedup vs baseline: 2.4673x; 1.1704x over previous
//
#include <hip/hip_runtime.h>

#define LEAF_SZ 32
#define MAXN 16384
#define MAXNODES 65536
#define ARENA_BASE 32768
#define MAXG 64
#define NQ 1024
#define BGRID 128
#define LCAP 256
#define LSTK 192
#define BSTK 32
#define WQCAP 64
#define NW0 16

struct __align__(64) TNode { int4 meta; float4 c4; float4 m4; float4 pad; };

// Static device scratch (fully rewritten each call; no cross-call state relied on).
__device__ int    g_perm[MAXN];
__device__ int    g_ptmp[MAXN];
__device__ float4 g_p4[MAXN];    // x,y,z,charge in perm order
__device__ float4 g_t4[MAXN];
__device__ int    g_nstart[MAXNODES];
__device__ int    g_nend[MAXNODES];
__device__ TNode  g_nodes[MAXNODES];
__device__ int    g_root[MAXG];
__device__ int    g_ncount;
__device__ int    g_lrange[4];
__device__ int    g_done[2];

struct NodeSh {
    float  mn[4][3], mx[4][3];
    double sx[4], sy[4], sz[4], sq[4];
    int    c8[4][8];
    int    cur[8];
    float  cc[3];
    int    info;
    int    base, num;
    int    tot[8], offk[8];
};

// Block-cooperative node processing (R2-proven logic, 256 threads).
__device__ __forceinline__ void process_node2(NodeSh& sh, int n, int st, int en)
{
    const int tid  = threadIdx.x;
    const int wid  = tid >> 6;
    const int lane = tid & 63;
    const int cnt = en - st;

    float mnx = 3.402823466e38f, mny = mnx, mnz = mnx;
    float mxx = -mnx, mxy = -mnx, mxz = -mnx;
    double sx = 0.0, sy = 0.0, sz = 0.0, sq = 0.0;
    for (int j = st + tid; j < en; j += 256) {
        float4 p = g_p4[j];
        mnx = fminf(mnx, p.x); mny = fminf(mny, p.y); mnz = fminf(mnz, p.z);
        mxx = fmaxf(mxx, p.x); mxy = fmaxf(mxy, p.y); mxz = fmaxf(mxz, p.z);
        sx += (double)p.x; sy += (double)p.y; sz += (double)p.z; sq += (double)p.w;
    }
    for (int o = 1; o < 64; o <<= 1) {
        mnx = fminf(mnx, __shfl_xor(mnx, o));
        mny = fminf(mny, __shfl_xor(mny, o));
        mnz = fminf(mnz, __shfl_xor(mnz, o));
        mxx = fmaxf(mxx, __shfl_xor(mxx, o));
        mxy = fmaxf(mxy, __shfl_xor(mxy, o));
        mxz = fmaxf(mxz, __shfl_xor(mxz, o));
        sx += __shfl_xor(sx, o);
        sy += __shfl_xor(sy, o);
        sz += __shfl_xor(sz, o);
        sq += __shfl_xor(sq, o);
    }
    if (lane == 0) {
        sh.mn[wid][0] = mnx; sh.mn[wid][1] = mny; sh.mn[wid][2] = mnz;
        sh.mx[wid][0] = mxx; sh.mx[wid][1] = mxy; sh.mx[wid][2] = mxz;
        sh.sx[wid] = sx; sh.sy[wid] = sy; sh.sz[wid] = sz; sh.sq[wid] = sq;
    }
    __syncthreads();
    if (tid == 0) {
        float a0 = sh.mn[0][0], a1 = sh.mn[0][1], a2 = sh.mn[0][2];
        float b0 = sh.mx[0][0], b1 = sh.mx[0][1], b2 = sh.mx[0][2];
        double tx = sh.sx[0], ty = sh.sy[0], tz = sh.sz[0], tq = sh.sq[0];
        for (int w = 1; w < 4; ++w) {
            a0 = fminf(a0, sh.mn[w][0]); a1 = fminf(a1, sh.mn[w][1]); a2 = fminf(a2, sh.mn[w][2]);
            b0 = fmaxf(b0, sh.mx[w][0]); b1 = fmaxf(b1, sh.mx[w][1]); b2 = fmaxf(b2, sh.mx[w][2]);
            tx += sh.sx[w]; ty += sh.sy[w]; tz += sh.sz[w]; tq += sh.sq[w];
        }
        float cx = 0.5f * (a0 + b0), cy = 0.5f * (a1 + b1), cz = 0.5f * (a2 + b2);
        g_nodes[n].c4 = make_float4(cx, cy, cz, 0.5f * fmaxf(fmaxf(b0 - a0, b1 - a1), b2 - a2));
        const float fc = (float)cnt;
        g_nodes[n].m4 = make_float4((float)tx / fc, (float)ty / fc, (float)tz / fc, (float)tq);
        sh.cc[0] = cx; sh.cc[1] = cy; sh.cc[2] = cz;
        if (cnt <= LEAF_SZ) { g_nodes[n].meta = make_int4(st, en, 0, 0); sh.info = -1; }
        else sh.info = 0;
    }
    __syncthreads();
    if (sh.info < 0) return;
    const float cx = sh.cc[0], cy = sh.cc[1], cz = sh.cc[2];

    int c8[8] = {0,0,0,0,0,0,0,0};
    for (int j = st + tid; j < en; j += 256) {
        float4 p = g_p4[j];
        int oct = (p.x >= cx ? 1 : 0) | (p.y >= cy ? 2 : 0) | (p.z >= cz ? 4 : 0);
        c8[oct]++;
    }
    #pragma unroll
    for (int k = 0; k < 8; ++k)
        for (int o = 1; o < 64; o <<= 1)
            c8[k] += __shfl_xor(c8[k], o);
    if (lane == 0)
        #pragma unroll
        for (int k = 0; k < 8; ++k) sh.c8[wid][k] = c8[k];
    __syncthreads();
    if (tid == 0) {
        int tot[8], nonempty = 0;
        #pragma unroll
        for (int k = 0; k < 8; ++k) {
            tot[k] = sh.c8[0][k] + sh.c8[1][k] + sh.c8[2][k] + sh.c8[3][k];
            nonempty += (tot[k] > 0) ? 1 : 0;
        }
        if (nonempty <= 1) { g_nodes[n].meta = make_int4(st, en, 0, 0); sh.info = -1; }
        else {
            int base = atomicAdd(&g_ncount, nonempty);
            int acc = st, ci = base;
            #pragma unroll
            for (int k = 0; k < 8; ++k) {
                sh.cur[k] = acc;
                sh.offk[k] = acc - st;
                sh.tot[k] = tot[k];
                if (tot[k] > 0) { g_nstart[ci] = acc; g_nend[ci] = acc + tot[k]; ++ci; }
                acc += tot[k];
            }
            g_nodes[n].meta = make_int4(st, en, base, nonempty);
            sh.base = base; sh.num = nonempty; sh.info = 1;
        }
    }
    __syncthreads();
    if (sh.info < 0) return;

    for (int j = st + tid; j < en; j += 256) {
        float4 p = g_p4[j];
        int id = g_perm[j];
        int oct = (p.x >= cx ? 1 : 0) | (p.y >= cy ? 2 : 0) | (p.z >= cz ? 4 : 0);
        int pdst = atomicAdd(&sh.cur[oct], 1);
        g_ptmp[pdst] = id; g_t4[pdst] = p;
    }
    __syncthreads();
    for (int j = st + tid; j < en; j += 256) {
        g_perm[j] = g_ptmp[j];
        g_p4[j]   = g_t4[j];
    }
    __syncthreads();
}

// ---------------------------------------------------------------------------
// Fused init + level-0: one 1024-thread block per graph, reading pos/src/batch
// directly (no pre-gather). Graph ranges computed redundantly per block.
// Children use a FIXED arena (nc + g*8, rank-consecutive; unused slots -1),
// so no cross-block counters at level 0. Scatter writes g_p4/g_perm directly.
// ---------------------------------------------------------------------------
__global__ __launch_bounds__(1024)
void level0_kernel(const float* __restrict__ pos, const float* __restrict__ src,
                   const int* __restrict__ batch, int N, int n_graphs)
{
    __shared__ int    s_first[MAXG], s_end[MAXG];
    __shared__ float  s_mn[NW0][3], s_mx[NW0][3];
    __shared__ double s_sx[NW0], s_sy[NW0], s_sz[NW0], s_sq[NW0];
    __shared__ int    s_c8[NW0][8];
    __shared__ int    s_cur[8];
    __shared__ float  s_cc[3];
    __shared__ int    s_info;
    const int tid = threadIdx.x, wid = tid >> 6, lane = tid & 63;
    const int ng = (n_graphs < MAXG) ? n_graphs : MAXG;

    for (int g = tid; g < MAXG; g += 1024) { s_first[g] = -1; s_end[g] = 0; }
    __syncthreads();
    for (int i = tid; i < N; i += 1024) {
        int b = batch[i];
        if (i == 0     || batch[i-1] != b) s_first[b] = i;
        if (i == N - 1 || batch[i+1] != b) s_end[b]   = i + 1;
    }
    __syncthreads();

    const int g = blockIdx.x;
    int nc = 0, myroot = -1;
    for (int q = 0; q < ng; ++q)
        if (s_first[q] >= 0) { if (q == g) myroot = nc; ++nc; }
    const int nb = nc + 8 * ng;

    if (g == 0 && tid == 0) {
        int r = 0;
        for (int q = 0; q < ng; ++q) {
            if (s_first[q] >= 0) g_root[q] = r++;
            else {
                g_root[q] = -1;
                for (int c = 0; c < 8; ++c) g_nstart[nc + q*8 + c] = -1;  // dead arena
            }
        }
        g_ncount = nb;          // alloc base for level-2+
        g_lrange[0] = nc;       // level-1 id range [nc, nb)
        g_lrange[1] = nb;
        g_done[1] = 0;
    }
    if (g >= ng || myroot < 0) return;          // block-uniform

    const int st = s_first[g], en = s_end[g];
    const int cnt = en - st;
    const int n = myroot;
    const int cbase = nc + g * 8;

    // pass 1: bbox + monopole
    float mnx = 3.402823466e38f, mny = mnx, mnz = mnx;
    float mxx = -mnx, mxy = -mnx, mxz = -mnx;
    double sx = 0.0, sy = 0.0, sz = 0.0, sq = 0.0;
    for (int j = st + tid; j < en; j += 1024) {
        float x = pos[3*j], y = pos[3*j+1], z = pos[3*j+2], s = src[j];
        mnx = fminf(mnx, x); mny = fminf(mny, y); mnz = fminf(mnz, z);
        mxx = fmaxf(mxx, x); mxy = fmaxf(mxy, y); mxz = fmaxf(mxz, z);
        sx += (double)x; sy += (double)y; sz += (double)z; sq += (double)s;
    }
    for (int o = 1; o < 64; o <<= 1) {
        mnx = fminf(mnx, __shfl_xor(mnx, o));
        mny = fminf(mny, __shfl_xor(mny, o));
        mnz = fminf(mnz, __shfl_xor(mnz, o));
        mxx = fmaxf(mxx, __shfl_xor(mxx, o));
        mxy = fmaxf(mxy, __shfl_xor(mxy, o));
        mxz = fmaxf(mxz, __shfl_xor(mxz, o));
        sx += __shfl_xor(sx, o);
        sy += __shfl_xor(sy, o);
        sz += __shfl_xor(sz, o);
        sq += __shfl_xor(sq, o);
    }
    if (lane == 0) {
        s_mn[wid][0] = mnx; s_mn[wid][1] = mny; s_mn[wid][2] = mnz;
        s_mx[wid][0] = mxx; s_mx[wid][1] = mxy; s_mx[wid][2] = mxz;
        s_sx[wid] = sx; s_sy[wid] = sy; s_sz[wid] = sz; s_sq[wid] = sq;
    }
    __syncthreads();
    if (tid == 0) {
        float a0 = s_mn[0][0], a1 = s_mn[0][1], a2 = s_mn[0][2];
        float b0 = s_mx[0][0], b1 = s_mx[0][1], b2 = s_mx[0][2];
        double tx = s_sx[0], ty = s_sy[0], tz = s_sz[0], tq = s_sq[0];
        for (int w = 1; w < NW0; ++w) {
            a0 = fminf(a0, s_mn[w][0]); a1 = fminf(a1, s_mn[w][1]); a2 = fminf(a2, s_mn[w][2]);
            b0 = fmaxf(b0, s_mx[w][0]); b1 = fmaxf(b1, s_mx[w][1]); b2 = fmaxf(b2, s_mx[w][2]);
            tx += s_sx[w]; ty += s_sy[w]; tz += s_sz[w]; tq += s_sq[w];
        }
        float cx = 0.5f * (a0 + b0), cy = 0.5f * (a1 + b1), cz = 0.5f * (a2 + b2);
        g_nodes[n].c4 = make_float4(cx, cy, cz, 0.5f * fmaxf(fmaxf(b0 - a0, b1 - a1), b2 - a2));
        const float fc = (float)cnt;
        g_nodes[n].m4 = make_float4((float)tx / fc, (float)ty / fc, (float)tz / fc, (float)tq);
        s_cc[0] = cx; s_cc[1] = cy; s_cc[2] = cz;
        s_info = (cnt <= LEAF_SZ) ? -1 : 0;
        if (s_info < 0) g_nodes[n].meta = make_int4(st, en, 0, 0);
    }
    __syncthreads();

    if (s_info == 0) {
        // pass 2: octant counts
        const float cx = s_cc[0], cy = s_cc[1], cz = s_cc[2];
        int c8[8] = {0,0,0,0,0,0,0,0};
        for (int j = st + tid; j < en; j += 1024) {
            int oct = (pos[3*j] >= cx ? 1 : 0) | (pos[3*j+1] >= cy ? 2 : 0) | (pos[3*j+2] >= cz ? 4 : 0);
            c8[oct]++;
        }
        #pragma unroll
        for (int k = 0; k < 8; ++k)
            for (int o = 1; o < 64; o <<= 1)
                c8[k] += __shfl_xor(c8[k], o);
        if (lane == 0)
            #pragma unroll
            for (int k = 0; k < 8; ++k) s_c8[wid][k] = c8[k];
        __syncthreads();
        if (tid == 0) {
            int tot[8], nonempty = 0;
            #pragma unroll
            for (int k = 0; k < 8; ++k) {
                int tk = 0;
                for (int w = 0; w < NW0; ++w) tk += s_c8[w][k];
                tot[k] = tk;
                nonempty += (tk > 0) ? 1 : 0;
            }
            if (nonempty <= 1) {
                g_nodes[n].meta = make_int4(st, en, 0, 0);
                for (int c = 0; c < 8; ++c) g_nstart[cbase + c] = -1;
                s_info = -1;
            } else {
                int acc = st, ci = cbase;
                #pragma unroll
                for (int k = 0; k < 8; ++k) {
                    s_cur[k] = acc;
                    if (tot[k] > 0) { g_nstart[ci] = acc; g_nend[ci] = acc + tot[k]; ++ci; }
                    acc += tot[k];
                }
                for (int c = ci; c < cbase + 8; ++c) g_nstart[c] = -1;
                g_nodes[n].meta = make_int4(st, en, cbase, nonempty);
                s_info = 1;
            }
        }
        __syncthreads();
    } else if (tid == 0) {
        for (int c = 0; c < 8; ++c) g_nstart[cbase + c] = -1;
    }

    if (s_info == 1) {
        // pass 3: scatter directly from inputs into permuted g_p4/g_perm
        const float cx = s_cc[0], cy = s_cc[1], cz = s_cc[2];
        for (int j = st + tid; j < en; j += 1024) {
            float x = pos[3*j], y = pos[3*j+1], z = pos[3*j+2], s = src[j];
            int oct = (x >= cx ? 1 : 0) | (y >= cy ? 2 : 0) | (z >= cz ? 4 : 0);
            int pdst = atomicAdd(&s_cur[oct], 1);
            g_p4[pdst] = make_float4(x, y, z, s);
            g_perm[pdst] = j;
        }
    } else {
        // leaf root: identity gather
        for (int j = st + tid; j < en; j += 1024) {
            g_p4[j] = make_float4(pos[3*j], pos[3*j+1], pos[3*j+2], src[j]);
            g_perm[j] = j;
        }
    }
}

// Level 1 (256 threads): iterate fixed arena [nc, nb), skip invalid slots.
__global__ __launch_bounds__(256) void level1_kernel()
{
    __shared__ NodeSh sh;
    const int lb = g_lrange[0], le = g_lrange[1];
    for (int n = lb + blockIdx.x; n < le; n += BGRID) {
        __syncthreads();
        int st = g_nstart[n];
        if (st < 0) continue;                      // block-uniform
        process_node2(sh, n, st, g_nend[n]);
    }
    __syncthreads();
    if (threadIdx.x == 0) {
        __threadfence();
        int d = atomicAdd(&g_done[1], 1);
        if (d == BGRID - 1)
            g_lrange[2] = atomicAdd(&g_ncount, 0);  // snapshot level-2 frontier end
    }
}

// ---------------------------------------------------------------------------
// LDS-resident subtree DFS (cnt <= LCAP) — R11-proven, AoS node writes.
// ---------------------------------------------------------------------------
__device__ __forceinline__ void lds_subtree(int rootn, int st, int en, int abase,
                                            float4* a4, int* aid,
                                            int* lid, int* la, int* lbb)
{
    const int lane = threadIdx.x & 63;
    const int cnt = en - st;
    const unsigned long long mlt = (1ull << lane) - 1ull;

    for (int j = lane; j < cnt; j += 64) {
        a4[j]  = g_p4[st + j];
        aid[j] = g_perm[st + j];
    }
    asm volatile("s_waitcnt vmcnt(0) lgkmcnt(0)" ::: "memory");
    __builtin_amdgcn_wave_barrier();

    int sp = 0;
    int cn = rootn, ca = 0, cb = cnt;
    while (true) {
        const int c = cb - ca;
        float4 pv[4]; int idv[4]; int oc[4];
        float mnx = 3.402823466e38f, mny = mnx, mnz = mnx;
        float mxx = -mnx, mxy = -mnx, mxz = -mnx;
        float sx = 0.f, sy = 0.f, sz = 0.f, sq = 0.f;
        #pragma unroll
        for (int i = 0; i < 4; ++i) {
            bool act = (i*64 + lane) < c;
            int j = act ? (ca + i*64 + lane) : ca;
            float4 p = a4[j];
            pv[i] = p; idv[i] = aid[j];
            if (act) {
                mnx = fminf(mnx, p.x); mny = fminf(mny, p.y); mnz = fminf(mnz, p.z);
                mxx = fmaxf(mxx, p.x); mxy = fmaxf(mxy, p.y); mxz = fmaxf(mxz, p.z);
                sx += p.x; sy += p.y; sz += p.z; sq += p.w;
            }
        }
        for (int o = 1; o < 64; o <<= 1) {
            mnx = fminf(mnx, __shfl_xor(mnx, o));
            mny = fminf(mny, __shfl_xor(mny, o));
            mnz = fminf(mnz, __shfl_xor(mnz, o));
            mxx = fmaxf(mxx, __shfl_xor(mxx, o));
            mxy = fmaxf(mxy, __shfl_xor(mxy, o));
            mxz = fmaxf(mxz, __shfl_xor(mxz, o));
            sx += __shfl_xor(sx, o);
            sy += __shfl_xor(sy, o);
            sz += __shfl_xor(sz, o);
            sq += __shfl_xor(sq, o);
        }
        const float cx = 0.5f * (mnx + mxx);
        const float cy = 0.5f * (mny + mxy);
        const float cz = 0.5f * (mnz + mxz);
        if (lane == 0) {
            g_nodes[cn].c4 = make_float4(cx, cy, cz, 0.5f * fmaxf(fmaxf(mxx - mnx, mxy - mny), mxz - mnz));
            const float fc = (float)c;
            g_nodes[cn].m4 = make_float4(sx / fc, sy / fc, sz / fc, sq);
        }

        int nonempty = 0;
        int c8[8] = {0,0,0,0,0,0,0,0};
        if (c > LEAF_SZ) {
            #pragma unroll
            for (int i = 0; i < 4; ++i) {
                bool act = (i*64 + lane) < c;
                int o = act ? ((pv[i].x >= cx ? 1 : 0) | (pv[i].y >= cy ? 2 : 0) | (pv[i].z >= cz ? 4 : 0)) : 8;
                oc[i] = o;
                #pragma unroll
                for (int k = 0; k < 8; ++k)
                    c8[k] += (int)__popcll(__ballot(o == k));
            }
            #pragma unroll
            for (int k = 0; k < 8; ++k) nonempty += (c8[k] > 0) ? 1 : 0;
        }

        if (c <= LEAF_SZ || nonempty <= 1) {
            if (lane == 0) g_nodes[cn].meta = make_int4(st + ca, st + cb, 0, 0);
        } else {
            int off[8], acc = 0;
            #pragma unroll
            for (int k = 0; k < 8; ++k) { off[k] = acc; acc += c8[k]; }
            if (lane == 0) g_nodes[cn].meta = make_int4(st + ca, st + cb, abase, nonempty);
            int cum[8] = {0,0,0,0,0,0,0,0};
            #pragma unroll
            for (int i = 0; i < 4; ++i) {
                int o = oc[i];
                int pdst = 0;
                #pragma unroll
                for (int k = 0; k < 8; ++k) {
                    unsigned long long b = __ballot(o == k);
                    if (o == k) pdst = ca + off[k] + cum[k] + (int)__popcll(b & mlt);
                    cum[k] += (int)__popcll(b);
                }
                if (o < 8) { a4[pdst] = pv[i]; aid[pdst] = idv[i]; }
            }
            asm volatile("s_waitcnt lgkmcnt(0)" ::: "memory");
            __builtin_amdgcn_wave_barrier();
            if (lane == 0) {
                int ci = 0;
                #pragma unroll
                for (int k = 0; k < 8; ++k) {
                    if (c8[k] > 0) {
                        lid[sp + ci] = abase + ci;
                        la [sp + ci] = ca + off[k];
                        lbb[sp + ci] = ca + off[k] + c8[k];
                        ++ci;
                    }
                }
            }
            abase += nonempty; sp += nonempty;
            if (sp > LSTK) sp = LSTK;
        }
        if (sp <= 0) break;
        --sp;
        __builtin_amdgcn_wave_barrier();
        asm volatile("s_waitcnt lgkmcnt(0)" ::: "memory");
        cn = lid[sp]; ca = la[sp]; cb = lbb[sp];
        __builtin_amdgcn_wave_barrier();
    }

    for (int j = lane; j < cnt; j += 64) {
        g_p4[st + j]  = a4[j];
        g_perm[st + j] = aid[j];
    }
    asm volatile("s_waitcnt vmcnt(0)" ::: "memory");
}

// ---------------------------------------------------------------------------
// Merged level-2+ build (R14-proven): block claims a frontier task; phase 1
// block-coop DFS over >LCAP nodes; phase 2 waves drain small subtrees.
// ---------------------------------------------------------------------------
__global__ __launch_bounds__(256) void block_subtree_kernel()
{
    __shared__ NodeSh sh;
    __shared__ int bs_id[BSTK], bs_st[BSTK], bs_en[BSTK];
    __shared__ int wq_id[WQCAP], wq_st[WQCAP], wq_en[WQCAP];
    __shared__ int s_bsp, s_wq;
    __shared__ float4 s_a4[4][LCAP];
    __shared__ int    s_aid[4][LCAP];
    __shared__ int    s_lid[4][LSTK], s_la[4][LSTK], s_lb[4][LSTK];

    const int tid = threadIdx.x;
    const int wid = tid >> 6;
    const int lb = g_lrange[1], le = g_lrange[2];

    for (int task = lb + blockIdx.x; task < le; task += BGRID) {
        __syncthreads();
        if (tid == 0) {
            int st = g_nstart[task], en = g_nend[task];
            if (en - st <= LCAP) { wq_id[0] = task; wq_st[0] = st; wq_en[0] = en; s_wq = 1; s_bsp = 0; }
            else                 { bs_id[0] = task; bs_st[0] = st; bs_en[0] = en; s_bsp = 1; s_wq = 0; }
        }
        __syncthreads();

        while (true) {
            __syncthreads();
            const int bsp = s_bsp;
            if (bsp == 0) break;
            const int n  = bs_id[bsp-1];
            const int st = bs_st[bsp-1];
            const int en = bs_en[bsp-1];
            __syncthreads();
            if (tid == 0) s_bsp = bsp - 1;
            process_node2(sh, n, st, en);
            if (tid == 0 && sh.info == 1) {
                int ci = 0;
                #pragma unroll
                for (int k = 0; k < 8; ++k) {
                    if (sh.tot[k] > 0) {
                        int cst = st + sh.offk[k], cen = cst + sh.tot[k];
                        int cid = sh.base + ci; ++ci;
                        if (cen - cst <= LCAP) {
                            if (s_wq < WQCAP) { wq_id[s_wq] = cid; wq_st[s_wq] = cst; wq_en[s_wq] = cen; ++s_wq; }
                        } else {
                            if (s_bsp < BSTK) { bs_id[s_bsp] = cid; bs_st[s_bsp] = cst; bs_en[s_bsp] = cen; ++s_bsp; }
                        }
                    }
                }
            }
        }
        __syncthreads();

        const int nwq = s_wq;
        float4* a4 = s_a4[wid];  int* aid = s_aid[wid];
        int* lid = s_lid[wid];   int* la = s_la[wid];  int* lbb = s_lb[wid];
        for (int i = wid; i < nwq; i += 4) {
            int cid = wq_id[i], cst = wq_st[i], cen = wq_en[i];
            lds_subtree(cid, cst, cen, ARENA_BASE + 2 * cst, a4, aid, lid, la, lbb);
        }
    }
}

// ---------------------------------------------------------------------------
// One wave per target. Leaf pairs distributed by a 64-pair-chunk owner scan:
// lanes publish (base,selfskip) once; drain lanes find their owning leaf via
// mark + shfl-max inclusive scan (carry across chunks), then index directly.
// ---------------------------------------------------------------------------
__global__ __launch_bounds__(256)
void traverse_kernel(const int* __restrict__ batch,
                     const float* __restrict__ p_scr, const float* __restrict__ p_soft,
                     float* __restrict__ out, int N)
{
    __shared__ int s_q[4][NQ];
    __shared__ int s_sb[4][64], s_ss[4][64], s_mk[4][64];
    __shared__ int s_qt[4];
    const int wid  = threadIdx.x >> 6;
    const int lane = threadIdx.x & 63;
    const int slot = blockIdx.x * 4 + wid;
    if (slot >= N) return;                 // wave-uniform; no __syncthreads used
    const int t = g_perm[slot];

    const float scr   = p_scr[0];
    const float soft  = p_soft[0];
    const float soft2 = soft * soft;
    const float cexp  = -scr * 1.4426950408889634f;  // exp(-scr*r) = exp2(cexp*r)
    const float4 tp = g_p4[slot];
    const float tx = tp.x, ty = tp.y, tz = tp.z;
    const int inv_t = slot;

    volatile int* q = s_q[wid];
    int* sb = s_sb[wid];
    int* ss = s_ss[wid];
    int* mk = s_mk[wid];
    if (lane == 0) { q[0] = g_root[batch[t]]; s_qt[wid] = 1; }
    __builtin_amdgcn_wave_barrier();

    float phi = 0.f;
    int qh = 0;
    while (true) {
        __builtin_amdgcn_wave_barrier();
        int qt = ((volatile int*)s_qt)[wid];
        if (qh >= qt) break;
        int take = qt - qh; if (take > 64) take = 64;
        int node = (lane < take) ? q[(qh + lane) & (NQ - 1)] : -1;
        qh += take;

        int leaf_st = 0, leaf_cnt = 0;
        if (node >= 0) {
            const int4 meta = g_nodes[node].meta;
            if (meta.w == 0) {
                leaf_st = meta.x; leaf_cnt = meta.y - meta.x;
            } else {
                float4 c4 = g_nodes[node].c4;
                float dx = tx - c4.x, dy = ty - c4.y, dz = tz - c4.z;
                float dist = sqrtf(dx*dx + dy*dy + dz*dz + soft2);
                float diam = fmaxf(2.0f * c4.w, 1e-9f);
                bool inside = (inv_t >= meta.x) && (inv_t < meta.y);
                if (!inside && diam < 0.5f * dist) {
                    float4 m4 = g_nodes[node].m4;
                    float ax = tx - m4.x, ay = ty - m4.y, az = tz - m4.z;
                    float s = ax*ax + ay*ay + az*az + soft2;
                    float rinv = rsqrtf(s);
                    phi += m4.w * exp2f(cexp * (s * rinv)) * rinv;
                } else {
                    int p = atomicAdd(&s_qt[wid], meta.w);
                    for (int c = 0; c < meta.w; ++c) q[(p + c) & (NQ - 1)] = meta.z + c;
                }
            }
        }

        // prefix-sum of (leaf size minus self)
        bool hasself = (inv_t >= leaf_st) && (inv_t < leaf_st + leaf_cnt);
        int cnt_adj = leaf_cnt - (hasself ? 1 : 0);
        int x = cnt_adj;
        #pragma unroll
        for (int o = 1; o < 64; o <<= 1) { int y = __shfl_up(x, o); if (lane >= o) x += y; }
        int total = __shfl(x, 63);
        int off = x - cnt_adj;

        if (total > 0) {
            sb[lane] = leaf_st - off;
            ss[lane] = hasself ? (off + (inv_t - leaf_st)) : 0x7fffffff;
            asm volatile("s_waitcnt lgkmcnt(0)" ::: "memory");
            __builtin_amdgcn_wave_barrier();
            int carry = -1;
            for (int cb = 0; cb < total; cb += 64) {
                mk[lane] = -1;
                asm volatile("s_waitcnt lgkmcnt(0)" ::: "memory");
                __builtin_amdgcn_wave_barrier();
                if (cnt_adj > 0 && off >= cb && off < cb + 64) mk[off - cb] = lane;
                asm volatile("s_waitcnt lgkmcnt(0)" ::: "memory");
                __builtin_amdgcn_wave_barrier();
                int own = mk[lane];
                if (lane == 0) own = own > carry ? own : carry;
                #pragma unroll
                for (int o = 1; o < 64; o <<= 1) {
                    int y = __shfl_up(own, o);
                    if (lane >= o) own = own > y ? own : y;
                }
                carry = __shfl(own, 63);
                int p = cb + lane;
                if (p < total) {
                    int j = sb[own] + p + ((p >= ss[own]) ? 1 : 0);
                    float4 pp = g_p4[j];
                    float dx = tx - pp.x, dy = ty - pp.y, dz = tz - pp.z;
                    float s = dx*dx + dy*dy + dz*dz + soft2;
                    float rinv = rsqrtf(s);
                    phi += pp.w * exp2f(cexp * (s * rinv)) * rinv;
                }
                __builtin_amdgcn_wave_barrier();
            }
        }
    }

    #pragma unroll
    for (int o = 1; o < 64; o <<= 1) phi += __shfl_xor(phi, o);
    if (lane == 0) out[t] = 0.5f * (tp.w * phi);
}

extern "C" void kernel_launch(void* const* d_in, const int* in_sizes, int n_in,
                              void* d_out, int out_size, void* d_ws, size_t ws_size,
                              hipStream_t stream) {
    const float* pos    = (const float*)d_in[0];
    const int*   batch  = (const int*)  d_in[1];
    const float* source = (const float*)d_in[3];
    const float* p_scr  = (const float*)d_in[4];
    const float* p_soft = (const float*)d_in[5];

    const int N        = in_sizes[0] / 3;
    const int n_graphs = in_sizes[2] / 9;

    int g0 = n_graphs > 0 ? n_graphs : 1;
    if (g0 > MAXG) g0 = MAXG;
    level0_kernel<<<g0, 1024, 0, stream>>>(pos, source, batch, N, n_graphs);
    level1_kernel<<<BGRID, 256, 0, stream>>>();
    block_subtree_kernel<<<BGRID, 256, 0, stream>>>();

    const int blocks = (N + 3) / 4;  // 4 waves (targets) per 256-thread block
    traverse_kernel<<<blocks, 256, 0, stream>>>(batch, p_scr, p_soft, (float*)d_out, N);
}